// Round 1
// baseline (983.459 us; speedup 1.0000x reference)
//
#include <hip/hip_runtime.h>
#include <math.h>

// Problem constants
#define F_DIM 256
#define N_DIM 400
#define C_DIM 128
#define H_DIM 8
#define E_DIM 16
#define ROWS  (F_DIM * N_DIM)          // 102400
#define SBUF  (N_DIM * H_DIM * F_DIM * E_DIM)  // 13107200 floats per q/k/v region

typedef _Float16 half2_t __attribute__((ext_vector_type(2)));
typedef _Float16 f16x8   __attribute__((ext_vector_type(8)));
typedef float    f32x16  __attribute__((ext_vector_type(16)));
typedef float    f32x4   __attribute__((ext_vector_type(4)));

struct H2x4 { half2_t h[4]; };

// pack 8 consecutive fp32 (two float4) into an f16x8 fragment (RTZ)
__device__ inline f16x8 pack8(float4 a, float4 b) {
    H2x4 t;
    t.h[0] = __builtin_bit_cast(half2_t, __builtin_amdgcn_cvt_pkrtz(a.x, a.y));
    t.h[1] = __builtin_bit_cast(half2_t, __builtin_amdgcn_cvt_pkrtz(a.z, a.w));
    t.h[2] = __builtin_bit_cast(half2_t, __builtin_amdgcn_cvt_pkrtz(b.x, b.y));
    t.h[3] = __builtin_bit_cast(half2_t, __builtin_amdgcn_cvt_pkrtz(b.z, b.w));
    return __builtin_bit_cast(f16x8, t);
}

// scalar fp32 -> fp16 with RTZ (matches pack8 rounding)
__device__ inline _Float16 h_rtz(float v) {
    half2_t p = __builtin_bit_cast(half2_t, __builtin_amdgcn_cvt_pkrtz(v, v));
    return p[0];
}

__device__ inline int iclamp256(int v) { return v < 0 ? 0 : (v > 256 ? 256 : v); }

// ---------------------------------------------------------------------------
// K0: tree_k / tree_v projections (unchanged)
// ---------------------------------------------------------------------------
__global__ __launch_bounds__(256) void tree_proj(
    const float* __restrict__ te, const float* __restrict__ Wtk,
    const float* __restrict__ Wtv, float* __restrict__ tk, float* __restrict__ tv)
{
    int n = blockIdx.x;
    int t = threadIdx.x;
    const float* W = (t < 128) ? Wtk : Wtv;
    float* outp    = (t < 128) ? tk : tv;
    int j = t & 127;
    float acc = 0.f;
    #pragma unroll 4
    for (int c = 0; c < 128; ++c)
        acc += te[n * 128 + c] * W[c * 128 + j];
    outp[n * 128 + j] = acc;
}

// ---------------------------------------------------------------------------
// K0b: pack emb (257 x 16 fp32) into fp16 (RTZ) for direct fragment loads
// ---------------------------------------------------------------------------
__global__ __launch_bounds__(256) void emb_pack(
    const float* __restrict__ emb, _Float16* __restrict__ embh)
{
    int r = blockIdx.x * 256 + threadIdx.x;
    if (r > 256) return;
    const float4* er = (const float4*)(emb + r * 16);
    float4 e0 = er[0], e1 = er[1], e2 = er[2], e3 = er[3];
    *(uint4*)(embh + r * 16)     = __builtin_bit_cast(uint4, pack8(e0, e1));
    *(uint4*)(embh + r * 16 + 8) = __builtin_bit_cast(uint4, pack8(e2, e3));
}

// ---------------------------------------------------------------------------
// K1: qkv GEMM via fp16 MFMA.
// CHANGE r7->r8: outputs are now _Float16 (RTZ for q/k as before via pack8
// path; RTN for v, matching the old VshT staging cast). v is written
// PRE-TRANSPOSED in (n,h,e,f) layout so attn can load V^T fragments directly
// from global. Halves qkv write traffic and attn fetch traffic, and lets
// attn drop its Ksh/Esh/VshT staging LDS entirely.
// ---------------------------------------------------------------------------
__global__ __launch_bounds__(256) void qkv_gemm(
    const float* __restrict__ x, const float* __restrict__ Wq,
    const float* __restrict__ tk, const float* __restrict__ tv,
    _Float16* __restrict__ qb, _Float16* __restrict__ kb, _Float16* __restrict__ vb)
{
    int tid  = threadIdx.x;
    int wave = tid >> 6, lane = tid & 63;
    int m32  = lane & 31, khalf = lane >> 5;
    int row0 = blockIdx.y * 64 + (wave & 1) * 32;
    int col0 = blockIdx.x * 64 + (wave >> 1) * 32;

    const float* xp = x  + (row0 + m32) * 128 + khalf * 8;
    const float* wp = Wq + (col0 + m32) * 128 + khalf * 8;

    f32x16 acc;
    #pragma unroll
    for (int i = 0; i < 16; ++i) acc[i] = 0.f;

    #pragma unroll
    for (int k0 = 0; k0 < 128; k0 += 16) {
        float4 xa = *(const float4*)(xp + k0);
        float4 xb = *(const float4*)(xp + k0 + 4);
        float4 wa = *(const float4*)(wp + k0);
        float4 wb = *(const float4*)(wp + k0 + 4);
        acc = __builtin_amdgcn_mfma_f32_32x32x16_f16(pack8(xa, xb), pack8(wa, wb), acc, 0, 0, 0);
    }

    int o   = col0 + m32;
    int sec = o >> 7;
    int rem = o & 127;
    int h = rem >> 4, e = rem & 15;
    #pragma unroll
    for (int reg = 0; reg < 16; ++reg) {
        int r = row0 + (reg & 3) + 8 * (reg >> 2) + 4 * khalf;  // r = f*400+n
        int f = r / 400;
        int n = r - f * 400;
        float val = acc[reg];
        if (sec == 0) {
            qb[((n * 8 + h) * 256 + f) * 16 + e] = h_rtz(val);
        } else if (sec == 1) {
            val += tk[n * 128 + rem];
            kb[((n * 8 + h) * 256 + f) * 16 + e] = h_rtz(val);
        } else {
            val += tv[n * 128 + rem];
            vb[((n * 8 + h) * 16 + e) * 256 + f] = (_Float16)val;  // V^T, RTN like old staging
        }
    }
}

// ---------------------------------------------------------------------------
// K2: MFMA flash attention per (n,h). 4 waves; wave w owns l in [64w,64w+64).
// S = QK^T (32x32x16 MFMA). bias1 = Q.emb[d] via window-GEMM + ds_bpermute.
// bias2 = K.emb[d] via shared R2 table (K_tile @ emb^T, MFMA, LDS gather).
// PV via 16x16x32 MFMA after wave-private LDS roundtrip of P.
// CHANGE r7->r8: q/k/v/emb arrive as fp16 in fragment-ready layouts
// (v pre-transposed), so Ksh/Esh/VshT staging is gone. LDS 62.4KB -> 29.2KB
// => 5 blocks/CU instead of 2 (occupancy 21% -> ~55%+). Fragments load as
// single 16B global reads (L1-hot: K/V tiles 8KB each, emb 12KB shared).
// LDS ~28.5 KB. grid 3200, block 256.
// ---------------------------------------------------------------------------
#define R2_STRIDE 296   // halves per R2 row (288 cols + pad)
#define PS_STRIDE 40    // halves per P row (80B, b128-aligned, odd-dword)

__global__ __launch_bounds__(256, 5) void attn_kernel(
    const _Float16* __restrict__ qb, const _Float16* __restrict__ kb,
    const _Float16* __restrict__ vb, const _Float16* __restrict__ embh,
    float* __restrict__ y)
{
    __shared__ __align__(16) _Float16 R2sh[32 * R2_STRIDE];   // 18.9 KB
    __shared__ __align__(16) _Float16 Psh[4 * 32 * PS_STRIDE];// 10.2 KB

    int tid  = threadIdx.x;
    int wave = tid >> 6, lane = tid & 63;
    int bn   = blockIdx.x;            // n*8 + h
    int n    = bn >> 3, h = bn & 7;
    int base = bn * 4096;             // halves

    int nn  = lane & 31;            // score col / s-local / frag m-or-n index
    int kh  = lane >> 5;            // wave half (frag k split for 32-shapes)
    int khb = (lane & 32) << 2;     // bpermute addr offset into own half
    int cbase = 31 + 4 * kh - nn;   // window col base per lane
    int dbase = 4 * kh - nn;        // d offset per lane
    int q16 = (lane >> 4) & 3;      // quad for 16x16 shapes

    // Q fragments for this wave's two l-tiles (direct 16B loads from global)
    f16x8 aq[2];
    #pragma unroll
    for (int lt = 0; lt < 2; ++lt)
        aq[lt] = __builtin_bit_cast(f16x8,
            *(const uint4*)(qb + base + (64 * wave + 32 * lt + nn) * 16 + kh * 8));

    f32x4 O[2][2];
    #pragma unroll
    for (int i = 0; i < 2; ++i)
        #pragma unroll
        for (int j = 0; j < 2; ++j)
            #pragma unroll
            for (int r = 0; r < 4; ++r) O[i][j][r] = 0.f;
    float denom = 0.f;

    _Float16* psw = Psh + wave * 32 * PS_STRIDE;

    for (int st = 0; st < 8; ++st) {
        // K-tile fragment (A for R2, B for QK): row = 32*st + nn
        f16x8 bk = __builtin_bit_cast(f16x8,
            *(const uint4*)(kb + base + (32 * st + nn) * 16 + kh * 8));

        // ---- shared R2 table: R2[s_local][d] = K[32st+s_local] . emb[d] ----
        for (int ct = wave; ct < 9; ct += 4) {
            int erow = 32 * ct + nn; if (erow > 256) erow = 256;
            f16x8 be = __builtin_bit_cast(f16x8,
                *(const uint4*)(embh + erow * 16 + kh * 8));
            f32x16 c2;
            #pragma unroll
            for (int i = 0; i < 16; ++i) c2[i] = 0.f;
            c2 = __builtin_amdgcn_mfma_f32_32x32x16_f16(bk, be, c2, 0, 0, 0);
            #pragma unroll
            for (int r = 0; r < 16; ++r) {
                int srow = (r & 3) + 8 * (r >> 2) + 4 * kh;
                R2sh[srow * R2_STRIDE + 32 * ct + nn] = (_Float16)c2[r];
            }
        }
        __syncthreads();   // R2 ready for all waves

        // PV B-fragment: V^T[e = lane&15][k = s-local = q16*8+j], direct global
        f16x8 bv = __builtin_bit_cast(f16x8,
            *(const uint4*)(vb + base + (lane & 15) * 256 + 32 * st + q16 * 8));

        #pragma unroll
        for (int lt = 0; lt < 2; ++lt) {
            int U0 = 64 * wave + 32 * lt - 32 * st + 128;

            // scores
            f32x16 S;
            #pragma unroll
            for (int i = 0; i < 16; ++i) S[i] = 0.f;
            S = __builtin_amdgcn_mfma_f32_32x32x16_f16(aq[lt], bk, S, 0, 0, 0);

            // bias1 windows: W[m][c] = Q[l0+m] . emb[clamp(U0-31+c)]
            int br0 = iclamp256(U0 - 31 + nn);
            int br1 = iclamp256(U0 + 1 + nn);
            f16x8 be0 = __builtin_bit_cast(f16x8,
                *(const uint4*)(embh + br0 * 16 + kh * 8));
            f16x8 be1 = __builtin_bit_cast(f16x8,
                *(const uint4*)(embh + br1 * 16 + kh * 8));
            f32x16 W0, W1;
            #pragma unroll
            for (int i = 0; i < 16; ++i) { W0[i] = 0.f; W1[i] = 0.f; }
            W0 = __builtin_amdgcn_mfma_f32_32x32x16_f16(aq[lt], be0, W0, 0, 0, 0);
            W1 = __builtin_amdgcn_mfma_f32_32x32x16_f16(aq[lt], be1, W1, 0, 0, 0);

            #pragma unroll
            for (int r = 0; r < 16; ++r) {
                int rmr = (r & 3) + 8 * (r >> 2);
                int c   = rmr + cbase;                 // [0,62]
                int addr = ((c & 31) << 2) + khb;
                float b1a = __builtin_bit_cast(float,
                    __builtin_amdgcn_ds_bpermute(addr, __builtin_bit_cast(int, W0[r])));
                float b1b = __builtin_bit_cast(float,
                    __builtin_amdgcn_ds_bpermute(addr, __builtin_bit_cast(int, W1[r])));
                float b1 = (c < 32) ? b1a : b1b;
                int d = iclamp256(U0 + rmr + dbase);
                float b2 = (float)R2sh[nn * R2_STRIDE + d];
                float p = __expf((S[r] + b1 + b2) * 0.25f);
                int mloc = rmr + 4 * kh;
                psw[mloc * PS_STRIDE + nn] = (_Float16)p;
            }

            // denom: lane j (with j>>5==lt) sums its own row — ALL 32 values
            if ((lane >> 5) == lt) {
                const uint4* rp = (const uint4*)(psw + (lane & 31) * PS_STRIDE);
                uint4 u0 = rp[0], u1 = rp[1], u2 = rp[2], u3 = rp[3];
                half2_t hs0 =
                    (__builtin_bit_cast(half2_t, u0.x) + __builtin_bit_cast(half2_t, u0.y)) +
                    (__builtin_bit_cast(half2_t, u0.z) + __builtin_bit_cast(half2_t, u0.w));
                half2_t hs1 =
                    (__builtin_bit_cast(half2_t, u1.x) + __builtin_bit_cast(half2_t, u1.y)) +
                    (__builtin_bit_cast(half2_t, u1.z) + __builtin_bit_cast(half2_t, u1.w));
                half2_t hs2 =
                    (__builtin_bit_cast(half2_t, u2.x) + __builtin_bit_cast(half2_t, u2.y)) +
                    (__builtin_bit_cast(half2_t, u2.z) + __builtin_bit_cast(half2_t, u2.w));
                half2_t hs3 =
                    (__builtin_bit_cast(half2_t, u3.x) + __builtin_bit_cast(half2_t, u3.y)) +
                    (__builtin_bit_cast(half2_t, u3.z) + __builtin_bit_cast(half2_t, u3.w));
                half2_t hsum = (hs0 + hs1) + (hs2 + hs3);
                denom += (float)hsum.x + (float)hsum.y;
            }

            // PV: 2 sub-tiles of 16 l-rows each, K = 32 (this s-tile)
            #pragma unroll
            for (int a = 0; a < 2; ++a) {
                f16x8 ap = __builtin_bit_cast(f16x8,
                    *(const uint4*)(psw + (16 * a + (lane & 15)) * PS_STRIDE + q16 * 8));
                O[lt][a] = __builtin_amdgcn_mfma_f32_16x16x32_f16(ap, bv, O[lt][a], 0, 0, 0);
            }
        }
        __syncthreads();   // all reads of R2sh done before next st overwrites
    }

    // ---- epilogue: normalize + write ----
    float inv = 1.0f / denom;   // lane owns l = 64*wave + lane
    int iinv = __builtin_bit_cast(int, inv);
    #pragma unroll
    for (int lt = 0; lt < 2; ++lt) {
        #pragma unroll
        for (int a = 0; a < 2; ++a) {
            #pragma unroll
            for (int r = 0; r < 4; ++r) {
                int row  = q16 * 4 + r;
                int lloc = 32 * lt + 16 * a + row;
                float dv = __builtin_bit_cast(float,
                    __builtin_amdgcn_ds_bpermute(lloc << 2, iinv));
                int lg = 64 * wave + lloc;
                y[(lg * 400 + n) * 128 + h * 16 + (lane & 15)] = O[lt][a][r] * dv;
            }
        }
    }
}

// ---------------------------------------------------------------------------
// K3: gate+LN1 (unchanged)
// ---------------------------------------------------------------------------
__global__ __launch_bounds__(256) void gate_ln1(
    const float* __restrict__ x, const float* __restrict__ y,
    const float* __restrict__ Wb, const float* __restrict__ g,
    const float* __restrict__ b, float* __restrict__ h1)
{
    int tid  = threadIdx.x;
    int r    = blockIdx.x * 4 + (tid >> 6);
    int lane = tid & 63;
    int c    = lane * 2;

    float2 xv = *(const float2*)(x + r * 128 + c);
    float2 yv = *(const float2*)(y + r * 128 + c);
    float2 w0 = *(const float2*)(Wb + c);
    float2 w1 = *(const float2*)(Wb + 128 + c);
    float2 w2 = *(const float2*)(Wb + 256 + c);

    float sv = yv.x * w0.x + yv.y * w0.y
             + xv.x * w1.x + xv.y * w1.y
             + (yv.x - xv.x) * w2.x + (yv.y - xv.y) * w2.y;
    #pragma unroll
    for (int off = 32; off > 0; off >>= 1) sv += __shfl_xor(sv, off);
    float gate = 1.0f / (1.0f + __expf(-sv));

    float z0 = gate * xv.x + (1.0f - gate) * yv.x;
    float z1 = gate * xv.y + (1.0f - gate) * yv.y;
    float s1 = z0 + z1, s2 = z0 * z0 + z1 * z1;
    #pragma unroll
    for (int off = 32; off > 0; off >>= 1) {
        s1 += __shfl_xor(s1, off);
        s2 += __shfl_xor(s2, off);
    }
    float mu  = s1 * (1.0f / 128.0f);
    float var = s2 * (1.0f / 128.0f) - mu * mu;
    float rs  = rsqrtf(var + 1e-5f);

    float2 gv = *(const float2*)(g + c);
    float2 bv = *(const float2*)(b + c);
    float2 ov;
    ov.x = (z0 - mu) * rs * gv.x + bv.x;
    ov.y = (z1 - mu) * rs * gv.y + bv.y;
    *(float2*)(h1 + r * 128 + c) = ov;
}

// ---------------------------------------------------------------------------
// K4: ff1 fp16 MFMA + exact GELU (unchanged)
// ---------------------------------------------------------------------------
__global__ __launch_bounds__(256) void ff1_gemm(
    const float* __restrict__ A, const float* __restrict__ W,
    const float* __restrict__ bias, float* __restrict__ outp)
{
    int tid  = threadIdx.x;
    int wave = tid >> 6, lane = tid & 63;
    int m32  = lane & 31, khalf = lane >> 5;
    int row0 = blockIdx.y * 64 + (wave & 1) * 32;
    int col0 = blockIdx.x * 64 + (wave >> 1) * 32;

    const float* ap = A + (row0 + m32) * 128 + khalf * 8;
    const float* wp = W + (col0 + m32) * 128 + khalf * 8;

    f32x16 acc;
    #pragma unroll
    for (int i = 0; i < 16; ++i) acc[i] = 0.f;

    #pragma unroll
    for (int k0 = 0; k0 < 128; k0 += 16) {
        float4 aa = *(const float4*)(ap + k0);
        float4 ab = *(const float4*)(ap + k0 + 4);
        float4 wa = *(const float4*)(wp + k0);
        float4 wb = *(const float4*)(wp + k0 + 4);
        acc = __builtin_amdgcn_mfma_f32_32x32x16_f16(pack8(aa, ab), pack8(wa, wb), acc, 0, 0, 0);
    }

    int   c  = col0 + m32;
    float bi = bias[c];
    #pragma unroll
    for (int reg = 0; reg < 16; ++reg) {
        int r = row0 + (reg & 3) + 8 * (reg >> 2) + 4 * khalf;
        float v = acc[reg] + bi;
        v = 0.5f * v * (1.0f + erff(v * 0.70710678118654752f));  // exact GELU
        outp[r * 128 + c] = v;
    }
}

// ---------------------------------------------------------------------------
// K5: ff2 + LN2 fp16 MFMA (unchanged)
// ---------------------------------------------------------------------------
__global__ __launch_bounds__(256) void ff2_ln2(
    const float* __restrict__ A, const float* __restrict__ W2,
    const float* __restrict__ b2, const float* __restrict__ h1,
    const float* __restrict__ g, const float* __restrict__ bb,
    float* __restrict__ outp)
{
    __shared__ float Cs[32 * 132];
    int tid  = threadIdx.x;
    int wave = tid >> 6, lane = tid & 63;
    int m32  = lane & 31, khalf = lane >> 5;
    int row0 = blockIdx.x * 32;
    int col0 = wave * 32;

    const float* ap = A  + (row0 + m32) * 128 + khalf * 8;
    const float* wp = W2 + (col0 + m32) * 128 + khalf * 8;

    f32x16 acc;
    #pragma unroll
    for (int i = 0; i < 16; ++i) acc[i] = 0.f;

    #pragma unroll
    for (int k0 = 0; k0 < 128; k0 += 16) {
        float4 aa = *(const float4*)(ap + k0);
        float4 ab = *(const float4*)(ap + k0 + 4);
        float4 wa = *(const float4*)(wp + k0);
        float4 wb = *(const float4*)(wp + k0 + 4);
        acc = __builtin_amdgcn_mfma_f32_32x32x16_f16(pack8(aa, ab), pack8(wa, wb), acc, 0, 0, 0);
    }

    #pragma unroll
    for (int reg = 0; reg < 16; ++reg) {
        int rloc = (reg & 3) + 8 * (reg >> 2) + 4 * khalf;
        Cs[rloc * 132 + col0 + m32] = acc[reg];
    }
    __syncthreads();

    int rloc = tid >> 3, seg = (tid & 7) * 16;
    int r = row0 + rloc;
    float z[16];
    float s1 = 0.f, s2 = 0.f;
    #pragma unroll
    for (int j4 = 0; j4 < 4; ++j4) {
        float4 cv = *(const float4*)(Cs + rloc * 132 + seg + j4 * 4);
        float4 hv = *(const float4*)(h1 + r * 128 + seg + j4 * 4);
        float4 bv = *(const float4*)(b2 + seg + j4 * 4);
        z[j4*4+0] = cv.x + bv.x + hv.x;
        z[j4*4+1] = cv.y + bv.y + hv.y;
        z[j4*4+2] = cv.z + bv.z + hv.z;
        z[j4*4+3] = cv.w + bv.w + hv.w;
        s1 += z[j4*4+0] + z[j4*4+1] + z[j4*4+2] + z[j4*4+3];
        s2 += z[j4*4+0]*z[j4*4+0] + z[j4*4+1]*z[j4*4+1]
            + z[j4*4+2]*z[j4*4+2] + z[j4*4+3]*z[j4*4+3];
    }
    #pragma unroll
    for (int off = 4; off > 0; off >>= 1) {
        s1 += __shfl_xor(s1, off);
        s2 += __shfl_xor(s2, off);
    }
    float mu  = s1 * (1.0f / 128.0f);
    float var = s2 * (1.0f / 128.0f) - mu * mu;
    float rs  = rsqrtf(var + 1e-5f);
    #pragma unroll
    for (int j4 = 0; j4 < 4; ++j4) {
        float4 gv = *(const float4*)(g  + seg + j4 * 4);
        float4 bv = *(const float4*)(bb + seg + j4 * 4);
        float4 ov;
        ov.x = (z[j4*4+0] - mu) * rs * gv.x + bv.x;
        ov.y = (z[j4*4+1] - mu) * rs * gv.y + bv.y;
        ov.z = (z[j4*4+2] - mu) * rs * gv.z + bv.z;
        ov.w = (z[j4*4+3] - mu) * rs * gv.w + bv.w;
        *(float4*)(outp + r * 128 + seg + j4 * 4) = ov;
    }
}

// ---------------------------------------------------------------------------
extern "C" void kernel_launch(void* const* d_in, const int* in_sizes, int n_in,
                              void* d_out, int out_size, void* d_ws, size_t ws_size,
                              hipStream_t stream)
{
    const float* x     = (const float*)d_in[0];
    const float* te    = (const float*)d_in[1];
    const float* Wqkv  = (const float*)d_in[2];
    const float* Wtk   = (const float*)d_in[3];
    const float* Wtv   = (const float*)d_in[4];
    const float* emb   = (const float*)d_in[5];
    const float* Wbeta = (const float*)d_in[6];
    const float* ln1g  = (const float*)d_in[7];
    const float* ln1b  = (const float*)d_in[8];
    const float* ln2g  = (const float*)d_in[9];
    const float* ln2b  = (const float*)d_in[10];
    const float* W1    = (const float*)d_in[11];
    const float* b1    = (const float*)d_in[12];
    const float* W2    = (const float*)d_in[13];
    const float* b2    = (const float*)d_in[14];
    float* outp = (float*)d_out;

    float* ws = (float*)d_ws;
    float* tk = ws;                        // 51200
    float* tv = ws + 51200;                // 51200
    float* qb_region = ws + 102400;        // SBUF floats (q uses first half as f16)
    float* kb_region = qb_region + SBUF;   // SBUF floats (k uses first half as f16)
    float* vb_region = kb_region + SBUF;   // SBUF floats (v^T uses first half as f16)
    float* yb        = vb_region + SBUF;   // SBUF floats (f,n,c) fp32

    _Float16* qh   = (_Float16*)qb_region;
    _Float16* khb  = (_Float16*)kb_region;
    _Float16* vhb  = (_Float16*)vb_region;
    _Float16* embh = (_Float16*)(vb_region + SBUF / 2);  // spare half of v region

    float* h1  = kb_region;               // reuse: k dead after attention
    float* ff1 = qb_region;               // reuse: q dead after attention

    tree_proj<<<400, 256, 0, stream>>>(te, Wtk, Wtv, tk, tv);
    emb_pack<<<2, 256, 0, stream>>>(emb, embh);
    qkv_gemm<<<dim3(6, 1600), 256, 0, stream>>>(x, Wqkv, tk, tv, qh, khb, vhb);
    attn_kernel<<<3200, 256, 0, stream>>>(qh, khb, vhb, embh, yb);
    gate_ln1<<<ROWS / 4, 256, 0, stream>>>(x, yb, Wbeta, ln1g, ln1b, h1);
    ff1_gemm<<<dim3(2, 1600), 256, 0, stream>>>(h1, W1, b1, ff1);
    ff2_ln2<<<3200, 256, 0, stream>>>(ff1, W2, b2, h1, ln2g, ln2b, outp);
}

// Round 2
// 742.395 us; speedup vs baseline: 1.3247x; 1.3247x over previous
//
#include <hip/hip_runtime.h>
#include <math.h>

// Problem constants
#define F_DIM 256
#define N_DIM 400
#define C_DIM 128
#define H_DIM 8
#define E_DIM 16
#define ROWS  (F_DIM * N_DIM)          // 102400
#define SBUF  (N_DIM * H_DIM * F_DIM * E_DIM)  // 13107200 floats per q/k/v region

typedef _Float16 half2_t __attribute__((ext_vector_type(2)));
typedef _Float16 f16x8   __attribute__((ext_vector_type(8)));
typedef float    f32x16  __attribute__((ext_vector_type(16)));
typedef float    f32x4   __attribute__((ext_vector_type(4)));

struct H2x4 { half2_t h[4]; };

// pack 8 consecutive fp32 (two float4) into an f16x8 fragment (RTZ)
__device__ inline f16x8 pack8(float4 a, float4 b) {
    H2x4 t;
    t.h[0] = __builtin_bit_cast(half2_t, __builtin_amdgcn_cvt_pkrtz(a.x, a.y));
    t.h[1] = __builtin_bit_cast(half2_t, __builtin_amdgcn_cvt_pkrtz(a.z, a.w));
    t.h[2] = __builtin_bit_cast(half2_t, __builtin_amdgcn_cvt_pkrtz(b.x, b.y));
    t.h[3] = __builtin_bit_cast(half2_t, __builtin_amdgcn_cvt_pkrtz(b.z, b.w));
    return __builtin_bit_cast(f16x8, t);
}

// scalar fp32 -> fp16 with RTZ (matches pack8 rounding)
__device__ inline _Float16 h_rtz(float v) {
    half2_t p = __builtin_bit_cast(half2_t, __builtin_amdgcn_cvt_pkrtz(v, v));
    return p[0];
}

__device__ inline int iclamp256(int v) { return v < 0 ? 0 : (v > 256 ? 256 : v); }

// ---------------------------------------------------------------------------
// K0: tree_k / tree_v projections (unchanged)
// ---------------------------------------------------------------------------
__global__ __launch_bounds__(256) void tree_proj(
    const float* __restrict__ te, const float* __restrict__ Wtk,
    const float* __restrict__ Wtv, float* __restrict__ tk, float* __restrict__ tv)
{
    int n = blockIdx.x;
    int t = threadIdx.x;
    const float* W = (t < 128) ? Wtk : Wtv;
    float* outp    = (t < 128) ? tk : tv;
    int j = t & 127;
    float acc = 0.f;
    #pragma unroll 4
    for (int c = 0; c < 128; ++c)
        acc += te[n * 128 + c] * W[c * 128 + j];
    outp[n * 128 + j] = acc;
}

// ---------------------------------------------------------------------------
// K0b: pack emb (257 x 16 fp32) into fp16 (RTZ) for direct fragment loads
// ---------------------------------------------------------------------------
__global__ __launch_bounds__(256) void emb_pack(
    const float* __restrict__ emb, _Float16* __restrict__ embh)
{
    int r = blockIdx.x * 256 + threadIdx.x;
    if (r > 256) return;
    const float4* er = (const float4*)(emb + r * 16);
    float4 e0 = er[0], e1 = er[1], e2 = er[2], e3 = er[3];
    *(uint4*)(embh + r * 16)     = __builtin_bit_cast(uint4, pack8(e0, e1));
    *(uint4*)(embh + r * 16 + 8) = __builtin_bit_cast(uint4, pack8(e2, e3));
}

// ---------------------------------------------------------------------------
// K1: qkv GEMM via fp16 MFMA. Outputs _Float16, v pre-transposed (n,h,e,f).
// ---------------------------------------------------------------------------
__global__ __launch_bounds__(256) void qkv_gemm(
    const float* __restrict__ x, const float* __restrict__ Wq,
    const float* __restrict__ tk, const float* __restrict__ tv,
    _Float16* __restrict__ qb, _Float16* __restrict__ kb, _Float16* __restrict__ vb)
{
    int tid  = threadIdx.x;
    int wave = tid >> 6, lane = tid & 63;
    int m32  = lane & 31, khalf = lane >> 5;
    int row0 = blockIdx.y * 64 + (wave & 1) * 32;
    int col0 = blockIdx.x * 64 + (wave >> 1) * 32;

    const float* xp = x  + (row0 + m32) * 128 + khalf * 8;
    const float* wp = Wq + (col0 + m32) * 128 + khalf * 8;

    f32x16 acc;
    #pragma unroll
    for (int i = 0; i < 16; ++i) acc[i] = 0.f;

    #pragma unroll
    for (int k0 = 0; k0 < 128; k0 += 16) {
        float4 xa = *(const float4*)(xp + k0);
        float4 xb = *(const float4*)(xp + k0 + 4);
        float4 wa = *(const float4*)(wp + k0);
        float4 wb = *(const float4*)(wp + k0 + 4);
        acc = __builtin_amdgcn_mfma_f32_32x32x16_f16(pack8(xa, xb), pack8(wa, wb), acc, 0, 0, 0);
    }

    int o   = col0 + m32;
    int sec = o >> 7;
    int rem = o & 127;
    int h = rem >> 4, e = rem & 15;
    #pragma unroll
    for (int reg = 0; reg < 16; ++reg) {
        int r = row0 + (reg & 3) + 8 * (reg >> 2) + 4 * khalf;  // r = f*400+n
        int f = r / 400;
        int n = r - f * 400;
        float val = acc[reg];
        if (sec == 0) {
            qb[((n * 8 + h) * 256 + f) * 16 + e] = h_rtz(val);
        } else if (sec == 1) {
            val += tk[n * 128 + rem];
            kb[((n * 8 + h) * 256 + f) * 16 + e] = h_rtz(val);
        } else {
            val += tv[n * 128 + rem];
            vb[((n * 8 + h) * 16 + e) * 256 + f] = (_Float16)val;  // V^T, RTN like old staging
        }
    }
}

// ---------------------------------------------------------------------------
// K2: MFMA flash attention per (n,h). 4 waves; wave w owns l in [64w,64w+64).
// S = QK^T (32x32x16 MFMA). bias1 = Q.emb[d] via window-GEMM + ds_bpermute.
// bias2 = K.emb[d] via shared R2 table (K_tile @ emb^T, MFMA, LDS gather).
// PV via 16x16x32 MFMA after wave-private LDS roundtrip of P.
// r8: q/k/v/emb arrive as fp16 fragment-ready (v pre-transposed); no staging
// LDS. LDS 29.2KB => 5 blocks/CU.
// FIX r8->r9: __launch_bounds__(256,5) forced VGPR_Count=48 -> massive
// scratch spills (FETCH 608MB, WRITE 393MB vs ~79/52 ideal) -> 428us.
// Relax to (256,4): VGPR cap 128 (r7 needed 88 with MORE live state), LDS
// still allows 5 blocks/CU; no spill expected.
// ---------------------------------------------------------------------------
#define R2_STRIDE 296   // halves per R2 row (288 cols + pad)
#define PS_STRIDE 40    // halves per P row (80B, b128-aligned, odd-dword)

__global__ __launch_bounds__(256, 4) void attn_kernel(
    const _Float16* __restrict__ qb, const _Float16* __restrict__ kb,
    const _Float16* __restrict__ vb, const _Float16* __restrict__ embh,
    float* __restrict__ y)
{
    __shared__ __align__(16) _Float16 R2sh[32 * R2_STRIDE];   // 18.9 KB
    __shared__ __align__(16) _Float16 Psh[4 * 32 * PS_STRIDE];// 10.2 KB

    int tid  = threadIdx.x;
    int wave = tid >> 6, lane = tid & 63;
    int bn   = blockIdx.x;            // n*8 + h
    int n    = bn >> 3, h = bn & 7;
    int base = bn * 4096;             // halves

    int nn  = lane & 31;            // score col / s-local / frag m-or-n index
    int kh  = lane >> 5;            // wave half (frag k split for 32-shapes)
    int khb = (lane & 32) << 2;     // bpermute addr offset into own half
    int cbase = 31 + 4 * kh - nn;   // window col base per lane
    int dbase = 4 * kh - nn;        // d offset per lane
    int q16 = (lane >> 4) & 3;      // quad for 16x16 shapes

    // Q fragments for this wave's two l-tiles (direct 16B loads from global)
    f16x8 aq[2];
    #pragma unroll
    for (int lt = 0; lt < 2; ++lt)
        aq[lt] = __builtin_bit_cast(f16x8,
            *(const uint4*)(qb + base + (64 * wave + 32 * lt + nn) * 16 + kh * 8));

    f32x4 O[2][2];
    #pragma unroll
    for (int i = 0; i < 2; ++i)
        #pragma unroll
        for (int j = 0; j < 2; ++j)
            #pragma unroll
            for (int r = 0; r < 4; ++r) O[i][j][r] = 0.f;
    float denom = 0.f;

    _Float16* psw = Psh + wave * 32 * PS_STRIDE;

    for (int st = 0; st < 8; ++st) {
        // K-tile fragment (A for R2, B for QK): row = 32*st + nn
        f16x8 bk = __builtin_bit_cast(f16x8,
            *(const uint4*)(kb + base + (32 * st + nn) * 16 + kh * 8));

        // ---- shared R2 table: R2[s_local][d] = K[32st+s_local] . emb[d] ----
        for (int ct = wave; ct < 9; ct += 4) {
            int erow = 32 * ct + nn; if (erow > 256) erow = 256;
            f16x8 be = __builtin_bit_cast(f16x8,
                *(const uint4*)(embh + erow * 16 + kh * 8));
            f32x16 c2;
            #pragma unroll
            for (int i = 0; i < 16; ++i) c2[i] = 0.f;
            c2 = __builtin_amdgcn_mfma_f32_32x32x16_f16(bk, be, c2, 0, 0, 0);
            #pragma unroll
            for (int r = 0; r < 16; ++r) {
                int srow = (r & 3) + 8 * (r >> 2) + 4 * kh;
                R2sh[srow * R2_STRIDE + 32 * ct + nn] = (_Float16)c2[r];
            }
        }
        __syncthreads();   // R2 ready for all waves

        // PV B-fragment: V^T[e = lane&15][k = s-local = q16*8+j], direct global
        f16x8 bv = __builtin_bit_cast(f16x8,
            *(const uint4*)(vb + base + (lane & 15) * 256 + 32 * st + q16 * 8));

        #pragma unroll
        for (int lt = 0; lt < 2; ++lt) {
            int U0 = 64 * wave + 32 * lt - 32 * st + 128;

            // scores
            f32x16 S;
            #pragma unroll
            for (int i = 0; i < 16; ++i) S[i] = 0.f;
            S = __builtin_amdgcn_mfma_f32_32x32x16_f16(aq[lt], bk, S, 0, 0, 0);

            // bias1 windows: W[m][c] = Q[l0+m] . emb[clamp(U0-31+c)]
            int br0 = iclamp256(U0 - 31 + nn);
            int br1 = iclamp256(U0 + 1 + nn);
            f16x8 be0 = __builtin_bit_cast(f16x8,
                *(const uint4*)(embh + br0 * 16 + kh * 8));
            f16x8 be1 = __builtin_bit_cast(f16x8,
                *(const uint4*)(embh + br1 * 16 + kh * 8));
            f32x16 W0, W1;
            #pragma unroll
            for (int i = 0; i < 16; ++i) { W0[i] = 0.f; W1[i] = 0.f; }
            W0 = __builtin_amdgcn_mfma_f32_32x32x16_f16(aq[lt], be0, W0, 0, 0, 0);
            W1 = __builtin_amdgcn_mfma_f32_32x32x16_f16(aq[lt], be1, W1, 0, 0, 0);

            #pragma unroll
            for (int r = 0; r < 16; ++r) {
                int rmr = (r & 3) + 8 * (r >> 2);
                int c   = rmr + cbase;                 // [0,62]
                int addr = ((c & 31) << 2) + khb;
                float b1a = __builtin_bit_cast(float,
                    __builtin_amdgcn_ds_bpermute(addr, __builtin_bit_cast(int, W0[r])));
                float b1b = __builtin_bit_cast(float,
                    __builtin_amdgcn_ds_bpermute(addr, __builtin_bit_cast(int, W1[r])));
                float b1 = (c < 32) ? b1a : b1b;
                int d = iclamp256(U0 + rmr + dbase);
                float b2 = (float)R2sh[nn * R2_STRIDE + d];
                float p = __expf((S[r] + b1 + b2) * 0.25f);
                int mloc = rmr + 4 * kh;
                psw[mloc * PS_STRIDE + nn] = (_Float16)p;
            }

            // denom: lane j (with j>>5==lt) sums its own row — ALL 32 values
            if ((lane >> 5) == lt) {
                const uint4* rp = (const uint4*)(psw + (lane & 31) * PS_STRIDE);
                uint4 u0 = rp[0], u1 = rp[1], u2 = rp[2], u3 = rp[3];
                half2_t hs0 =
                    (__builtin_bit_cast(half2_t, u0.x) + __builtin_bit_cast(half2_t, u0.y)) +
                    (__builtin_bit_cast(half2_t, u0.z) + __builtin_bit_cast(half2_t, u0.w));
                half2_t hs1 =
                    (__builtin_bit_cast(half2_t, u1.x) + __builtin_bit_cast(half2_t, u1.y)) +
                    (__builtin_bit_cast(half2_t, u1.z) + __builtin_bit_cast(half2_t, u1.w));
                half2_t hs2 =
                    (__builtin_bit_cast(half2_t, u2.x) + __builtin_bit_cast(half2_t, u2.y)) +
                    (__builtin_bit_cast(half2_t, u2.z) + __builtin_bit_cast(half2_t, u2.w));
                half2_t hs3 =
                    (__builtin_bit_cast(half2_t, u3.x) + __builtin_bit_cast(half2_t, u3.y)) +
                    (__builtin_bit_cast(half2_t, u3.z) + __builtin_bit_cast(half2_t, u3.w));
                half2_t hsum = (hs0 + hs1) + (hs2 + hs3);
                denom += (float)hsum.x + (float)hsum.y;
            }

            // PV: 2 sub-tiles of 16 l-rows each, K = 32 (this s-tile)
            #pragma unroll
            for (int a = 0; a < 2; ++a) {
                f16x8 ap = __builtin_bit_cast(f16x8,
                    *(const uint4*)(psw + (16 * a + (lane & 15)) * PS_STRIDE + q16 * 8));
                O[lt][a] = __builtin_amdgcn_mfma_f32_16x16x32_f16(ap, bv, O[lt][a], 0, 0, 0);
            }
        }
        __syncthreads();   // all reads of R2sh done before next st overwrites
    }

    // ---- epilogue: normalize + write ----
    float inv = 1.0f / denom;   // lane owns l = 64*wave + lane
    int iinv = __builtin_bit_cast(int, inv);
    #pragma unroll
    for (int lt = 0; lt < 2; ++lt) {
        #pragma unroll
        for (int a = 0; a < 2; ++a) {
            #pragma unroll
            for (int r = 0; r < 4; ++r) {
                int row  = q16 * 4 + r;
                int lloc = 32 * lt + 16 * a + row;
                float dv = __builtin_bit_cast(float,
                    __builtin_amdgcn_ds_bpermute(lloc << 2, iinv));
                int lg = 64 * wave + lloc;
                y[(lg * 400 + n) * 128 + h * 16 + (lane & 15)] = O[lt][a][r] * dv;
            }
        }
    }
}

// ---------------------------------------------------------------------------
// K3: gate+LN1 (unchanged)
// ---------------------------------------------------------------------------
__global__ __launch_bounds__(256) void gate_ln1(
    const float* __restrict__ x, const float* __restrict__ y,
    const float* __restrict__ Wb, const float* __restrict__ g,
    const float* __restrict__ b, float* __restrict__ h1)
{
    int tid  = threadIdx.x;
    int r    = blockIdx.x * 4 + (tid >> 6);
    int lane = tid & 63;
    int c    = lane * 2;

    float2 xv = *(const float2*)(x + r * 128 + c);
    float2 yv = *(const float2*)(y + r * 128 + c);
    float2 w0 = *(const float2*)(Wb + c);
    float2 w1 = *(const float2*)(Wb + 128 + c);
    float2 w2 = *(const float2*)(Wb + 256 + c);

    float sv = yv.x * w0.x + yv.y * w0.y
             + xv.x * w1.x + xv.y * w1.y
             + (yv.x - xv.x) * w2.x + (yv.y - xv.y) * w2.y;
    #pragma unroll
    for (int off = 32; off > 0; off >>= 1) sv += __shfl_xor(sv, off);
    float gate = 1.0f / (1.0f + __expf(-sv));

    float z0 = gate * xv.x + (1.0f - gate) * yv.x;
    float z1 = gate * xv.y + (1.0f - gate) * yv.y;
    float s1 = z0 + z1, s2 = z0 * z0 + z1 * z1;
    #pragma unroll
    for (int off = 32; off > 0; off >>= 1) {
        s1 += __shfl_xor(s1, off);
        s2 += __shfl_xor(s2, off);
    }
    float mu  = s1 * (1.0f / 128.0f);
    float var = s2 * (1.0f / 128.0f) - mu * mu;
    float rs  = rsqrtf(var + 1e-5f);

    float2 gv = *(const float2*)(g + c);
    float2 bv = *(const float2*)(b + c);
    float2 ov;
    ov.x = (z0 - mu) * rs * gv.x + bv.x;
    ov.y = (z1 - mu) * rs * gv.y + bv.y;
    *(float2*)(h1 + r * 128 + c) = ov;
}

// ---------------------------------------------------------------------------
// K4: ff1 fp16 MFMA + exact GELU (unchanged)
// ---------------------------------------------------------------------------
__global__ __launch_bounds__(256) void ff1_gemm(
    const float* __restrict__ A, const float* __restrict__ W,
    const float* __restrict__ bias, float* __restrict__ outp)
{
    int tid  = threadIdx.x;
    int wave = tid >> 6, lane = tid & 63;
    int m32  = lane & 31, khalf = lane >> 5;
    int row0 = blockIdx.y * 64 + (wave & 1) * 32;
    int col0 = blockIdx.x * 64 + (wave >> 1) * 32;

    const float* ap = A + (row0 + m32) * 128 + khalf * 8;
    const float* wp = W + (col0 + m32) * 128 + khalf * 8;

    f32x16 acc;
    #pragma unroll
    for (int i = 0; i < 16; ++i) acc[i] = 0.f;

    #pragma unroll
    for (int k0 = 0; k0 < 128; k0 += 16) {
        float4 aa = *(const float4*)(ap + k0);
        float4 ab = *(const float4*)(ap + k0 + 4);
        float4 wa = *(const float4*)(wp + k0);
        float4 wb = *(const float4*)(wp + k0 + 4);
        acc = __builtin_amdgcn_mfma_f32_32x32x16_f16(pack8(aa, ab), pack8(wa, wb), acc, 0, 0, 0);
    }

    int   c  = col0 + m32;
    float bi = bias[c];
    #pragma unroll
    for (int reg = 0; reg < 16; ++reg) {
        int r = row0 + (reg & 3) + 8 * (reg >> 2) + 4 * khalf;
        float v = acc[reg] + bi;
        v = 0.5f * v * (1.0f + erff(v * 0.70710678118654752f));  // exact GELU
        outp[r * 128 + c] = v;
    }
}

// ---------------------------------------------------------------------------
// K5: ff2 + LN2 fp16 MFMA (unchanged)
// ---------------------------------------------------------------------------
__global__ __launch_bounds__(256) void ff2_ln2(
    const float* __restrict__ A, const float* __restrict__ W2,
    const float* __restrict__ b2, const float* __restrict__ h1,
    const float* __restrict__ g, const float* __restrict__ bb,
    float* __restrict__ outp)
{
    __shared__ float Cs[32 * 132];
    int tid  = threadIdx.x;
    int wave = tid >> 6, lane = tid & 63;
    int m32  = lane & 31, khalf = lane >> 5;
    int row0 = blockIdx.x * 32;
    int col0 = wave * 32;

    const float* ap = A  + (row0 + m32) * 128 + khalf * 8;
    const float* wp = W2 + (col0 + m32) * 128 + khalf * 8;

    f32x16 acc;
    #pragma unroll
    for (int i = 0; i < 16; ++i) acc[i] = 0.f;

    #pragma unroll
    for (int k0 = 0; k0 < 128; k0 += 16) {
        float4 aa = *(const float4*)(ap + k0);
        float4 ab = *(const float4*)(ap + k0 + 4);
        float4 wa = *(const float4*)(wp + k0);
        float4 wb = *(const float4*)(wp + k0 + 4);
        acc = __builtin_amdgcn_mfma_f32_32x32x16_f16(pack8(aa, ab), pack8(wa, wb), acc, 0, 0, 0);
    }

    #pragma unroll
    for (int reg = 0; reg < 16; ++reg) {
        int rloc = (reg & 3) + 8 * (reg >> 2) + 4 * khalf;
        Cs[rloc * 132 + col0 + m32] = acc[reg];
    }
    __syncthreads();

    int rloc = tid >> 3, seg = (tid & 7) * 16;
    int r = row0 + rloc;
    float z[16];
    float s1 = 0.f, s2 = 0.f;
    #pragma unroll
    for (int j4 = 0; j4 < 4; ++j4) {
        float4 cv = *(const float4*)(Cs + rloc * 132 + seg + j4 * 4);
        float4 hv = *(const float4*)(h1 + r * 128 + seg + j4 * 4);
        float4 bv = *(const float4*)(b2 + seg + j4 * 4);
        z[j4*4+0] = cv.x + bv.x + hv.x;
        z[j4*4+1] = cv.y + bv.y + hv.y;
        z[j4*4+2] = cv.z + bv.z + hv.z;
        z[j4*4+3] = cv.w + bv.w + hv.w;
        s1 += z[j4*4+0] + z[j4*4+1] + z[j4*4+2] + z[j4*4+3];
        s2 += z[j4*4+0]*z[j4*4+0] + z[j4*4+1]*z[j4*4+1]
            + z[j4*4+2]*z[j4*4+2] + z[j4*4+3]*z[j4*4+3];
    }
    #pragma unroll
    for (int off = 4; off > 0; off >>= 1) {
        s1 += __shfl_xor(s1, off);
        s2 += __shfl_xor(s2, off);
    }
    float mu  = s1 * (1.0f / 128.0f);
    float var = s2 * (1.0f / 128.0f) - mu * mu;
    float rs  = rsqrtf(var + 1e-5f);
    #pragma unroll
    for (int j4 = 0; j4 < 4; ++j4) {
        float4 gv = *(const float4*)(g  + seg + j4 * 4);
        float4 bv = *(const float4*)(bb + seg + j4 * 4);
        float4 ov;
        ov.x = (z[j4*4+0] - mu) * rs * gv.x + bv.x;
        ov.y = (z[j4*4+1] - mu) * rs * gv.y + bv.y;
        ov.z = (z[j4*4+2] - mu) * rs * gv.z + bv.z;
        ov.w = (z[j4*4+3] - mu) * rs * gv.w + bv.w;
        *(float4*)(outp + r * 128 + seg + j4 * 4) = ov;
    }
}

// ---------------------------------------------------------------------------
extern "C" void kernel_launch(void* const* d_in, const int* in_sizes, int n_in,
                              void* d_out, int out_size, void* d_ws, size_t ws_size,
                              hipStream_t stream)
{
    const float* x     = (const float*)d_in[0];
    const float* te    = (const float*)d_in[1];
    const float* Wqkv  = (const float*)d_in[2];
    const float* Wtk   = (const float*)d_in[3];
    const float* Wtv   = (const float*)d_in[4];
    const float* emb   = (const float*)d_in[5];
    const float* Wbeta = (const float*)d_in[6];
    const float* ln1g  = (const float*)d_in[7];
    const float* ln1b  = (const float*)d_in[8];
    const float* ln2g  = (const float*)d_in[9];
    const float* ln2b  = (const float*)d_in[10];
    const float* W1    = (const float*)d_in[11];
    const float* b1    = (const float*)d_in[12];
    const float* W2    = (const float*)d_in[13];
    const float* b2    = (const float*)d_in[14];
    float* outp = (float*)d_out;

    float* ws = (float*)d_ws;
    float* tk = ws;                        // 51200
    float* tv = ws + 51200;                // 51200
    float* qb_region = ws + 102400;        // SBUF floats (q uses first half as f16)
    float* kb_region = qb_region + SBUF;   // SBUF floats (k uses first half as f16)
    float* vb_region = kb_region + SBUF;   // SBUF floats (v^T uses first half as f16)
    float* yb        = vb_region + SBUF;   // SBUF floats (f,n,c) fp32

    _Float16* qh   = (_Float16*)qb_region;
    _Float16* khb  = (_Float16*)kb_region;
    _Float16* vhb  = (_Float16*)vb_region;
    _Float16* embh = (_Float16*)(vb_region + SBUF / 2);  // spare half of v region

    float* h1  = kb_region;               // reuse: k dead after attention
    float* ff1 = qb_region;               // reuse: q dead after attention

    tree_proj<<<400, 256, 0, stream>>>(te, Wtk, Wtv, tk, tv);
    emb_pack<<<2, 256, 0, stream>>>(emb, embh);
    qkv_gemm<<<dim3(6, 1600), 256, 0, stream>>>(x, Wqkv, tk, tv, qh, khb, vhb);
    attn_kernel<<<3200, 256, 0, stream>>>(qh, khb, vhb, embh, yb);
    gate_ln1<<<ROWS / 4, 256, 0, stream>>>(x, yb, Wbeta, ln1g, ln1b, h1);
    ff1_gemm<<<dim3(2, 1600), 256, 0, stream>>>(h1, W1, b1, ff1);
    ff2_ln2<<<3200, 256, 0, stream>>>(ff1, W2, b2, h1, ln2g, ln2b, outp);
}

// Round 5
// 630.088 us; speedup vs baseline: 1.5608x; 1.1782x over previous
//
#include <hip/hip_runtime.h>
#include <math.h>

// Problem constants
#define F_DIM 256
#define N_DIM 400
#define C_DIM 128
#define H_DIM 8
#define E_DIM 16
#define ROWS  (F_DIM * N_DIM)          // 102400
#define SBUF  (N_DIM * H_DIM * F_DIM * E_DIM)  // 13107200 floats per q/k/v region

// r12 == r10 resubmitted (3rd attempt): rounds 3+4 failed with "MI355X
// container failed twice" (acquire/run-level infra error, not a test
// verdict; session has documented federation pathology, e.g. 1145s npz
// push in round 1). Static re-audit found no OOB/misalignment/divergent-
// barrier/hang mechanism. Fallback if this fails again: revert to r9
// structure and bisect the r10 changes one at a time.

typedef _Float16 half2_t __attribute__((ext_vector_type(2)));
typedef _Float16 f16x8   __attribute__((ext_vector_type(8)));
typedef float    f32x16  __attribute__((ext_vector_type(16)));
typedef float    f32x4   __attribute__((ext_vector_type(4)));

struct H2x4 { half2_t h[4]; };

// pack 8 consecutive fp32 (two float4) into an f16x8 fragment (RTZ)
__device__ inline f16x8 pack8(float4 a, float4 b) {
    H2x4 t;
    t.h[0] = __builtin_bit_cast(half2_t, __builtin_amdgcn_cvt_pkrtz(a.x, a.y));
    t.h[1] = __builtin_bit_cast(half2_t, __builtin_amdgcn_cvt_pkrtz(a.z, a.w));
    t.h[2] = __builtin_bit_cast(half2_t, __builtin_amdgcn_cvt_pkrtz(b.x, b.y));
    t.h[3] = __builtin_bit_cast(half2_t, __builtin_amdgcn_cvt_pkrtz(b.z, b.w));
    return __builtin_bit_cast(f16x8, t);
}

// scalar fp32 -> fp16 with RTZ (matches pack8 rounding)
__device__ inline _Float16 h_rtz(float v) {
    half2_t p = __builtin_bit_cast(half2_t, __builtin_amdgcn_cvt_pkrtz(v, v));
    return p[0];
}

__device__ inline int iclamp256(int v) { return v < 0 ? 0 : (v > 256 ? 256 : v); }

// ---------------------------------------------------------------------------
// K0: tree_k / tree_v projections (unchanged)
// ---------------------------------------------------------------------------
__global__ __launch_bounds__(256) void tree_proj(
    const float* __restrict__ te, const float* __restrict__ Wtk,
    const float* __restrict__ Wtv, float* __restrict__ tk, float* __restrict__ tv)
{
    int n = blockIdx.x;
    int t = threadIdx.x;
    const float* W = (t < 128) ? Wtk : Wtv;
    float* outp    = (t < 128) ? tk : tv;
    int j = t & 127;
    float acc = 0.f;
    #pragma unroll 4
    for (int c = 0; c < 128; ++c)
        acc += te[n * 128 + c] * W[c * 128 + j];
    outp[n * 128 + j] = acc;
}

// ---------------------------------------------------------------------------
// K0b: pack emb (257 x 16 fp32) into fp16 (RTZ) for direct fragment loads
// ---------------------------------------------------------------------------
__global__ __launch_bounds__(256) void emb_pack(
    const float* __restrict__ emb, _Float16* __restrict__ embh)
{
    int r = blockIdx.x * 256 + threadIdx.x;
    if (r > 256) return;
    const float4* er = (const float4*)(emb + r * 16);
    float4 e0 = er[0], e1 = er[1], e2 = er[2], e3 = er[3];
    *(uint4*)(embh + r * 16)     = __builtin_bit_cast(uint4, pack8(e0, e1));
    *(uint4*)(embh + r * 16 + 8) = __builtin_bit_cast(uint4, pack8(e2, e3));
}

// ---------------------------------------------------------------------------
// K1: qkv GEMM via fp16 MFMA.
// FIX r9->r10: r8/r9 wrote fp16 into (n,h,f,e)/(n,h,e,f) layouts -> 32B
// partial-line runs (q/k) and 2B scatters at 512B stride (V^T). Partial
// lines evicted before the sibling half arrived (different XCD) -> HBM
// read-modify-write: FETCH 225MB / WRITE 460MB vs ~55/79 ideal -> 320us.
// Now: write q/k/v NATURAL (r,c) fp16 - per reg a half-wave stores 64B full
// lines. attn reads q/k fragments directly from natural layout (16B
// contiguous); V is transposed by the tiny v_pack kernel below.
// ---------------------------------------------------------------------------
__global__ __launch_bounds__(256) void qkv_gemm(
    const float* __restrict__ x, const float* __restrict__ Wq,
    const float* __restrict__ tk, const float* __restrict__ tv,
    _Float16* __restrict__ qn, _Float16* __restrict__ kn, _Float16* __restrict__ vn)
{
    int tid  = threadIdx.x;
    int wave = tid >> 6, lane = tid & 63;
    int m32  = lane & 31, khalf = lane >> 5;
    int row0 = blockIdx.y * 64 + (wave & 1) * 32;
    int col0 = blockIdx.x * 64 + (wave >> 1) * 32;

    const float* xp = x  + (row0 + m32) * 128 + khalf * 8;
    const float* wp = Wq + (col0 + m32) * 128 + khalf * 8;

    f32x16 acc;
    #pragma unroll
    for (int i = 0; i < 16; ++i) acc[i] = 0.f;

    #pragma unroll
    for (int k0 = 0; k0 < 128; k0 += 16) {
        float4 xa = *(const float4*)(xp + k0);
        float4 xb = *(const float4*)(xp + k0 + 4);
        float4 wa = *(const float4*)(wp + k0);
        float4 wb = *(const float4*)(wp + k0 + 4);
        acc = __builtin_amdgcn_mfma_f32_32x32x16_f16(pack8(xa, xb), pack8(wa, wb), acc, 0, 0, 0);
    }

    int o   = col0 + m32;
    int sec = o >> 7;
    int rem = o & 127;
    #pragma unroll
    for (int reg = 0; reg < 16; ++reg) {
        int r = row0 + (reg & 3) + 8 * (reg >> 2) + 4 * khalf;  // r = f*400+n
        float val = acc[reg];
        if (sec == 0) {
            qn[r * 128 + rem] = h_rtz(val);
        } else {
            int f = r / 400;
            int n = r - f * 400;
            if (sec == 1) {
                kn[r * 128 + rem] = h_rtz(val + tk[n * 128 + rem]);
            } else {
                vn[r * 128 + rem] = (_Float16)(val + tv[n * 128 + rem]);  // RTN like old staging
            }
        }
    }
}

// ---------------------------------------------------------------------------
// K1b: V transpose per (n,h): natural (f, e) -> vT (n,h,e,f).
// Coalesced-in (2x uint4 per thread, strided lanes), LDS transpose
// (scalar 2B writes, 2-way-free banks), coalesced-out (uint4 full lines).
// ~52 MB traffic total => ~10us.
// ---------------------------------------------------------------------------
__global__ __launch_bounds__(256) void v_pack(
    const _Float16* __restrict__ vn, _Float16* __restrict__ vT)
{
    __shared__ _Float16 sm[16 * 264];
    int bn = blockIdx.x;             // n*8 + h
    int n  = bn >> 3, h = bn & 7;
    int t  = threadIdx.x;            // f = t

    const uint4* src = (const uint4*)(vn + (t * 400 + n) * 128 + h * 16);
    uint4 a = src[0], b = src[1];
    union { uint4 u; _Float16 hv[8]; } ua, ub;
    ua.u = a; ub.u = b;
    #pragma unroll
    for (int e = 0; e < 8; ++e) sm[e * 264 + t]       = ua.hv[e];
    #pragma unroll
    for (int e = 0; e < 8; ++e) sm[(e + 8) * 264 + t] = ub.hv[e];
    __syncthreads();

    #pragma unroll
    for (int k = 0; k < 2; ++k) {
        int idx = (k * 256 + t) * 8;         // halves into (e,f) plane
        int e = idx >> 8, f0 = idx & 255;
        uint4 o = *(const uint4*)(sm + e * 264 + f0);
        *(uint4*)(vT + bn * 4096 + idx) = o;
    }
}

// ---------------------------------------------------------------------------
// K2: MFMA flash attention per (n,h). 4 waves; wave w owns l in [64w,64w+64).
// S = QK^T (32x32x16 MFMA). bias1 = Q.emb[d] via window-GEMM + ds_bpermute.
// bias2 = K.emb[d] via shared R2 table (K_tile @ emb^T, MFMA, LDS gather).
// PV via 16x16x32 MFMA after wave-private LDS roundtrip of P.
// r10: q/k fragments load directly from NATURAL fp16 layout (16B contiguous
// at (f*400+n)*128 + h*16 + kh*8); V from vT (v_pack). LDS 29.2KB.
// (256,4): VGPR cap 128 - (256,5)'s cap 48 caused catastrophic spills in r8.
// ---------------------------------------------------------------------------
#define R2_STRIDE 296   // halves per R2 row (288 cols + pad)
#define PS_STRIDE 40    // halves per P row (80B, b128-aligned, odd-dword)

__global__ __launch_bounds__(256, 4) void attn_kernel(
    const _Float16* __restrict__ qb, const _Float16* __restrict__ kb,
    const _Float16* __restrict__ vb, const _Float16* __restrict__ embh,
    float* __restrict__ y)
{
    __shared__ __align__(16) _Float16 R2sh[32 * R2_STRIDE];   // 18.9 KB
    __shared__ __align__(16) _Float16 Psh[4 * 32 * PS_STRIDE];// 10.2 KB

    int tid  = threadIdx.x;
    int wave = tid >> 6, lane = tid & 63;
    int bn   = blockIdx.x;            // n*8 + h
    int n    = bn >> 3, h = bn & 7;
    int base = bn * 4096;             // halves (vT only)

    int nn  = lane & 31;            // score col / s-local / frag m-or-n index
    int kh  = lane >> 5;            // wave half (frag k split for 32-shapes)
    int khb = (lane & 32) << 2;     // bpermute addr offset into own half
    int cbase = 31 + 4 * kh - nn;   // window col base per lane
    int dbase = 4 * kh - nn;        // d offset per lane
    int q16 = (lane >> 4) & 3;      // quad for 16x16 shapes

    // natural-layout fragment offset for this (n,h,kh)
    int nat_off = n * 128 + h * 16 + kh * 8;

    // Q fragments for this wave's two l-tiles (direct 16B loads from global)
    f16x8 aq[2];
    #pragma unroll
    for (int lt = 0; lt < 2; ++lt)
        aq[lt] = __builtin_bit_cast(f16x8,
            *(const uint4*)(qb + (64 * wave + 32 * lt + nn) * 51200 + nat_off));

    f32x4 O[2][2];
    #pragma unroll
    for (int i = 0; i < 2; ++i)
        #pragma unroll
        for (int j = 0; j < 2; ++j)
            #pragma unroll
            for (int r = 0; r < 4; ++r) O[i][j][r] = 0.f;
    float denom = 0.f;

    _Float16* psw = Psh + wave * 32 * PS_STRIDE;

    for (int st = 0; st < 8; ++st) {
        // K-tile fragment (A for R2, B for QK): row f = 32*st + nn
        f16x8 bk = __builtin_bit_cast(f16x8,
            *(const uint4*)(kb + (32 * st + nn) * 51200 + nat_off));

        // ---- shared R2 table: R2[s_local][d] = K[32st+s_local] . emb[d] ----
        for (int ct = wave; ct < 9; ct += 4) {
            int erow = 32 * ct + nn; if (erow > 256) erow = 256;
            f16x8 be = __builtin_bit_cast(f16x8,
                *(const uint4*)(embh + erow * 16 + kh * 8));
            f32x16 c2;
            #pragma unroll
            for (int i = 0; i < 16; ++i) c2[i] = 0.f;
            c2 = __builtin_amdgcn_mfma_f32_32x32x16_f16(bk, be, c2, 0, 0, 0);
            #pragma unroll
            for (int r = 0; r < 16; ++r) {
                int srow = (r & 3) + 8 * (r >> 2) + 4 * kh;
                R2sh[srow * R2_STRIDE + 32 * ct + nn] = (_Float16)c2[r];
            }
        }
        __syncthreads();   // R2 ready for all waves

        // PV B-fragment: V^T[e = lane&15][k = s-local = q16*8+j], direct global
        f16x8 bv = __builtin_bit_cast(f16x8,
            *(const uint4*)(vb + base + (lane & 15) * 256 + 32 * st + q16 * 8));

        #pragma unroll
        for (int lt = 0; lt < 2; ++lt) {
            int U0 = 64 * wave + 32 * lt - 32 * st + 128;

            // scores
            f32x16 S;
            #pragma unroll
            for (int i = 0; i < 16; ++i) S[i] = 0.f;
            S = __builtin_amdgcn_mfma_f32_32x32x16_f16(aq[lt], bk, S, 0, 0, 0);

            // bias1 windows: W[m][c] = Q[l0+m] . emb[clamp(U0-31+c)]
            int br0 = iclamp256(U0 - 31 + nn);
            int br1 = iclamp256(U0 + 1 + nn);
            f16x8 be0 = __builtin_bit_cast(f16x8,
                *(const uint4*)(embh + br0 * 16 + kh * 8));
            f16x8 be1 = __builtin_bit_cast(f16x8,
                *(const uint4*)(embh + br1 * 16 + kh * 8));
            f32x16 W0, W1;
            #pragma unroll
            for (int i = 0; i < 16; ++i) { W0[i] = 0.f; W1[i] = 0.f; }
            W0 = __builtin_amdgcn_mfma_f32_32x32x16_f16(aq[lt], be0, W0, 0, 0, 0);
            W1 = __builtin_amdgcn_mfma_f32_32x32x16_f16(aq[lt], be1, W1, 0, 0, 0);

            #pragma unroll
            for (int r = 0; r < 16; ++r) {
                int rmr = (r & 3) + 8 * (r >> 2);
                int c   = rmr + cbase;                 // [0,62]
                int addr = ((c & 31) << 2) + khb;
                float b1a = __builtin_bit_cast(float,
                    __builtin_amdgcn_ds_bpermute(addr, __builtin_bit_cast(int, W0[r])));
                float b1b = __builtin_bit_cast(float,
                    __builtin_amdgcn_ds_bpermute(addr, __builtin_bit_cast(int, W1[r])));
                float b1 = (c < 32) ? b1a : b1b;
                int d = iclamp256(U0 + rmr + dbase);
                float b2 = (float)R2sh[nn * R2_STRIDE + d];
                float p = __expf((S[r] + b1 + b2) * 0.25f);
                int mloc = rmr + 4 * kh;
                psw[mloc * PS_STRIDE + nn] = (_Float16)p;
            }

            // denom: lane j (with j>>5==lt) sums its own row — ALL 32 values
            if ((lane >> 5) == lt) {
                const uint4* rp = (const uint4*)(psw + (lane & 31) * PS_STRIDE);
                uint4 u0 = rp[0], u1 = rp[1], u2 = rp[2], u3 = rp[3];
                half2_t hs0 =
                    (__builtin_bit_cast(half2_t, u0.x) + __builtin_bit_cast(half2_t, u0.y)) +
                    (__builtin_bit_cast(half2_t, u0.z) + __builtin_bit_cast(half2_t, u0.w));
                half2_t hs1 =
                    (__builtin_bit_cast(half2_t, u1.x) + __builtin_bit_cast(half2_t, u1.y)) +
                    (__builtin_bit_cast(half2_t, u1.z) + __builtin_bit_cast(half2_t, u1.w));
                half2_t hs2 =
                    (__builtin_bit_cast(half2_t, u2.x) + __builtin_bit_cast(half2_t, u2.y)) +
                    (__builtin_bit_cast(half2_t, u2.z) + __builtin_bit_cast(half2_t, u2.w));
                half2_t hs3 =
                    (__builtin_bit_cast(half2_t, u3.x) + __builtin_bit_cast(half2_t, u3.y)) +
                    (__builtin_bit_cast(half2_t, u3.z) + __builtin_bit_cast(half2_t, u3.w));
                half2_t hsum = (hs0 + hs1) + (hs2 + hs3);
                denom += (float)hsum.x + (float)hsum.y;
            }

            // PV: 2 sub-tiles of 16 l-rows each, K = 32 (this s-tile)
            #pragma unroll
            for (int a = 0; a < 2; ++a) {
                f16x8 ap = __builtin_bit_cast(f16x8,
                    *(const uint4*)(psw + (16 * a + (lane & 15)) * PS_STRIDE + q16 * 8));
                O[lt][a] = __builtin_amdgcn_mfma_f32_16x16x32_f16(ap, bv, O[lt][a], 0, 0, 0);
            }
        }
        __syncthreads();   // all reads of R2sh done before next st overwrites
    }

    // ---- epilogue: normalize + write ----
    float inv = 1.0f / denom;   // lane owns l = 64*wave + lane
    int iinv = __builtin_bit_cast(int, inv);
    #pragma unroll
    for (int lt = 0; lt < 2; ++lt) {
        #pragma unroll
        for (int a = 0; a < 2; ++a) {
            #pragma unroll
            for (int r = 0; r < 4; ++r) {
                int row  = q16 * 4 + r;
                int lloc = 32 * lt + 16 * a + row;
                float dv = __builtin_bit_cast(float,
                    __builtin_amdgcn_ds_bpermute(lloc << 2, iinv));
                int lg = 64 * wave + lloc;
                y[(lg * 400 + n) * 128 + h * 16 + (lane & 15)] = O[lt][a][r] * dv;
            }
        }
    }
}

// ---------------------------------------------------------------------------
// K3: gate+LN1 (unchanged)
// ---------------------------------------------------------------------------
__global__ __launch_bounds__(256) void gate_ln1(
    const float* __restrict__ x, const float* __restrict__ y,
    const float* __restrict__ Wb, const float* __restrict__ g,
    const float* __restrict__ b, float* __restrict__ h1)
{
    int tid  = threadIdx.x;
    int r    = blockIdx.x * 4 + (tid >> 6);
    int lane = tid & 63;
    int c    = lane * 2;

    float2 xv = *(const float2*)(x + r * 128 + c);
    float2 yv = *(const float2*)(y + r * 128 + c);
    float2 w0 = *(const float2*)(Wb + c);
    float2 w1 = *(const float2*)(Wb + 128 + c);
    float2 w2 = *(const float2*)(Wb + 256 + c);

    float sv = yv.x * w0.x + yv.y * w0.y
             + xv.x * w1.x + xv.y * w1.y
             + (yv.x - xv.x) * w2.x + (yv.y - xv.y) * w2.y;
    #pragma unroll
    for (int off = 32; off > 0; off >>= 1) sv += __shfl_xor(sv, off);
    float gate = 1.0f / (1.0f + __expf(-sv));

    float z0 = gate * xv.x + (1.0f - gate) * yv.x;
    float z1 = gate * xv.y + (1.0f - gate) * yv.y;
    float s1 = z0 + z1, s2 = z0 * z0 + z1 * z1;
    #pragma unroll
    for (int off = 32; off > 0; off >>= 1) {
        s1 += __shfl_xor(s1, off);
        s2 += __shfl_xor(s2, off);
    }
    float mu  = s1 * (1.0f / 128.0f);
    float var = s2 * (1.0f / 128.0f) - mu * mu;
    float rs  = rsqrtf(var + 1e-5f);

    float2 gv = *(const float2*)(g + c);
    float2 bv = *(const float2*)(b + c);
    float2 ov;
    ov.x = (z0 - mu) * rs * gv.x + bv.x;
    ov.y = (z1 - mu) * rs * gv.y + bv.y;
    *(float2*)(h1 + r * 128 + c) = ov;
}

// ---------------------------------------------------------------------------
// K4: ff1 fp16 MFMA + exact GELU (unchanged)
// ---------------------------------------------------------------------------
__global__ __launch_bounds__(256) void ff1_gemm(
    const float* __restrict__ A, const float* __restrict__ W,
    const float* __restrict__ bias, float* __restrict__ outp)
{
    int tid  = threadIdx.x;
    int wave = tid >> 6, lane = tid & 63;
    int m32  = lane & 31, khalf = lane >> 5;
    int row0 = blockIdx.y * 64 + (wave & 1) * 32;
    int col0 = blockIdx.x * 64 + (wave >> 1) * 32;

    const float* ap = A + (row0 + m32) * 128 + khalf * 8;
    const float* wp = W + (col0 + m32) * 128 + khalf * 8;

    f32x16 acc;
    #pragma unroll
    for (int i = 0; i < 16; ++i) acc[i] = 0.f;

    #pragma unroll
    for (int k0 = 0; k0 < 128; k0 += 16) {
        float4 aa = *(const float4*)(ap + k0);
        float4 ab = *(const float4*)(ap + k0 + 4);
        float4 wa = *(const float4*)(wp + k0);
        float4 wb = *(const float4*)(wp + k0 + 4);
        acc = __builtin_amdgcn_mfma_f32_32x32x16_f16(pack8(aa, ab), pack8(wa, wb), acc, 0, 0, 0);
    }

    int   c  = col0 + m32;
    float bi = bias[c];
    #pragma unroll
    for (int reg = 0; reg < 16; ++reg) {
        int r = row0 + (reg & 3) + 8 * (reg >> 2) + 4 * khalf;
        float v = acc[reg] + bi;
        v = 0.5f * v * (1.0f + erff(v * 0.70710678118654752f));  // exact GELU
        outp[r * 128 + c] = v;
    }
}

// ---------------------------------------------------------------------------
// K5: ff2 + LN2 fp16 MFMA (unchanged)
// ---------------------------------------------------------------------------
__global__ __launch_bounds__(256) void ff2_ln2(
    const float* __restrict__ A, const float* __restrict__ W2,
    const float* __restrict__ b2, const float* __restrict__ h1,
    const float* __restrict__ g, const float* __restrict__ bb,
    float* __restrict__ outp)
{
    __shared__ float Cs[32 * 132];
    int tid  = threadIdx.x;
    int wave = tid >> 6, lane = tid & 63;
    int m32  = lane & 31, khalf = lane >> 5;
    int row0 = blockIdx.x * 32;
    int col0 = wave * 32;

    const float* ap = A  + (row0 + m32) * 128 + khalf * 8;
    const float* wp = W2 + (col0 + m32) * 128 + khalf * 8;

    f32x16 acc;
    #pragma unroll
    for (int i = 0; i < 16; ++i) acc[i] = 0.f;

    #pragma unroll
    for (int k0 = 0; k0 < 128; k0 += 16) {
        float4 aa = *(const float4*)(ap + k0);
        float4 ab = *(const float4*)(ap + k0 + 4);
        float4 wa = *(const float4*)(wp + k0);
        float4 wb = *(const float4*)(wp + k0 + 4);
        acc = __builtin_amdgcn_mfma_f32_32x32x16_f16(pack8(aa, ab), pack8(wa, wb), acc, 0, 0, 0);
    }

    #pragma unroll
    for (int reg = 0; reg < 16; ++reg) {
        int rloc = (reg & 3) + 8 * (reg >> 2) + 4 * khalf;
        Cs[rloc * 132 + col0 + m32] = acc[reg];
    }
    __syncthreads();

    int rloc = tid >> 3, seg = (tid & 7) * 16;
    int r = row0 + rloc;
    float z[16];
    float s1 = 0.f, s2 = 0.f;
    #pragma unroll
    for (int j4 = 0; j4 < 4; ++j4) {
        float4 cv = *(const float4*)(Cs + rloc * 132 + seg + j4 * 4);
        float4 hv = *(const float4*)(h1 + r * 128 + seg + j4 * 4);
        float4 bv = *(const float4*)(b2 + seg + j4 * 4);
        z[j4*4+0] = cv.x + bv.x + hv.x;
        z[j4*4+1] = cv.y + bv.y + hv.y;
        z[j4*4+2] = cv.z + bv.z + hv.z;
        z[j4*4+3] = cv.w + bv.w + hv.w;
        s1 += z[j4*4+0] + z[j4*4+1] + z[j4*4+2] + z[j4*4+3];
        s2 += z[j4*4+0]*z[j4*4+0] + z[j4*4+1]*z[j4*4+1]
            + z[j4*4+2]*z[j4*4+2] + z[j4*4+3]*z[j4*4+3];
    }
    #pragma unroll
    for (int off = 4; off > 0; off >>= 1) {
        s1 += __shfl_xor(s1, off);
        s2 += __shfl_xor(s2, off);
    }
    float mu  = s1 * (1.0f / 128.0f);
    float var = s2 * (1.0f / 128.0f) - mu * mu;
    float rs  = rsqrtf(var + 1e-5f);
    #pragma unroll
    for (int j4 = 0; j4 < 4; ++j4) {
        float4 gv = *(const float4*)(g  + seg + j4 * 4);
        float4 bv = *(const float4*)(bb + seg + j4 * 4);
        float4 ov;
        ov.x = (z[j4*4+0] - mu) * rs * gv.x + bv.x;
        ov.y = (z[j4*4+1] - mu) * rs * gv.y + bv.y;
        ov.z = (z[j4*4+2] - mu) * rs * gv.z + bv.z;
        ov.w = (z[j4*4+3] - mu) * rs * gv.w + bv.w;
        *(float4*)(outp + r * 128 + seg + j4 * 4) = ov;
    }
}

// ---------------------------------------------------------------------------
extern "C" void kernel_launch(void* const* d_in, const int* in_sizes, int n_in,
                              void* d_out, int out_size, void* d_ws, size_t ws_size,
                              hipStream_t stream)
{
    const float* x     = (const float*)d_in[0];
    const float* te    = (const float*)d_in[1];
    const float* Wqkv  = (const float*)d_in[2];
    const float* Wtk   = (const float*)d_in[3];
    const float* Wtv   = (const float*)d_in[4];
    const float* emb   = (const float*)d_in[5];
    const float* Wbeta = (const float*)d_in[6];
    const float* ln1g  = (const float*)d_in[7];
    const float* ln1b  = (const float*)d_in[8];
    const float* ln2g  = (const float*)d_in[9];
    const float* ln2b  = (const float*)d_in[10];
    const float* W1    = (const float*)d_in[11];
    const float* b1    = (const float*)d_in[12];
    const float* W2    = (const float*)d_in[13];
    const float* b2    = (const float*)d_in[14];
    float* outp = (float*)d_out;

    float* ws = (float*)d_ws;
    float* tk = ws;                        // 51200
    float* tv = ws + 51200;                // 51200
    float* qb_region = ws + 102400;        // SBUF floats
    float* kb_region = qb_region + SBUF;   // SBUF floats
    float* vb_region = kb_region + SBUF;   // SBUF floats
    float* yb        = vb_region + SBUF;   // SBUF floats (f,n,c) fp32

    _Float16* qnat = (_Float16*)qb_region;                   // natural (r,c) fp16
    _Float16* knat = (_Float16*)kb_region;                   // natural (r,c) fp16
    _Float16* vnat = (_Float16*)vb_region;                   // natural (r,c) fp16
    _Float16* vT   = (_Float16*)(vb_region + SBUF / 2);      // (n,h,e,f) fp16
    _Float16* embh = (_Float16*)(qb_region + SBUF / 2);      // spare half of q region

    float* h1  = kb_region;               // reuse: k dead after attention
    float* ff1 = qb_region;               // reuse: q dead after attention

    tree_proj<<<400, 256, 0, stream>>>(te, Wtk, Wtv, tk, tv);
    emb_pack<<<2, 256, 0, stream>>>(emb, embh);
    qkv_gemm<<<dim3(6, 1600), 256, 0, stream>>>(x, Wqkv, tk, tv, qnat, knat, vnat);
    v_pack<<<3200, 256, 0, stream>>>(vnat, vT);
    attn_kernel<<<3200, 256, 0, stream>>>(qnat, knat, vT, embh, yb);
    gate_ln1<<<ROWS / 4, 256, 0, stream>>>(x, yb, Wbeta, ln1g, ln1b, h1);
    ff1_gemm<<<dim3(2, 1600), 256, 0, stream>>>(h1, W1, b1, ff1);
    ff2_ln2<<<3200, 256, 0, stream>>>(ff1, W2, b2, h1, ln2g, ln2b, outp);
}

// Round 6
// 606.843 us; speedup vs baseline: 1.6206x; 1.0383x over previous
//
#include <hip/hip_runtime.h>
#include <math.h>

// Problem constants
#define F_DIM 256
#define N_DIM 400
#define C_DIM 128
#define H_DIM 8
#define E_DIM 16
#define ROWS  (F_DIM * N_DIM)          // 102400
#define SBUF  (N_DIM * H_DIM * F_DIM * E_DIM)  // 13107200 floats per q/k/v region

// r13: r10 verified at 630us (attn 212us, VALUBusy 49%, MfmaUtil 6.8%,
// bank-conflict 11.5M). attn is LDS-pipe/latency bound in the softmax
// element loop. This round: (1) packed single-bpermute for bias1 (32->16
// bpermutes/iter via cvt_pkrtz pair), (2) R2_STRIDE 296->298 (odd dword
// stride -> conflict-free gather), (3) y and ff1-out stored fp16 (halve
// those streams; ff2 loads f16x8 directly).

typedef _Float16 half2_t __attribute__((ext_vector_type(2)));
typedef _Float16 f16x8   __attribute__((ext_vector_type(8)));
typedef float    f32x16  __attribute__((ext_vector_type(16)));
typedef float    f32x4   __attribute__((ext_vector_type(4)));

struct H2x4 { half2_t h[4]; };

// pack 8 consecutive fp32 (two float4) into an f16x8 fragment (RTZ)
__device__ inline f16x8 pack8(float4 a, float4 b) {
    H2x4 t;
    t.h[0] = __builtin_bit_cast(half2_t, __builtin_amdgcn_cvt_pkrtz(a.x, a.y));
    t.h[1] = __builtin_bit_cast(half2_t, __builtin_amdgcn_cvt_pkrtz(a.z, a.w));
    t.h[2] = __builtin_bit_cast(half2_t, __builtin_amdgcn_cvt_pkrtz(b.x, b.y));
    t.h[3] = __builtin_bit_cast(half2_t, __builtin_amdgcn_cvt_pkrtz(b.z, b.w));
    return __builtin_bit_cast(f16x8, t);
}

// scalar fp32 -> fp16 with RTZ (matches pack8 rounding)
__device__ inline _Float16 h_rtz(float v) {
    half2_t p = __builtin_bit_cast(half2_t, __builtin_amdgcn_cvt_pkrtz(v, v));
    return p[0];
}

__device__ inline int iclamp256(int v) { return v < 0 ? 0 : (v > 256 ? 256 : v); }

// ---------------------------------------------------------------------------
// K0: tree_k / tree_v projections (unchanged)
// ---------------------------------------------------------------------------
__global__ __launch_bounds__(256) void tree_proj(
    const float* __restrict__ te, const float* __restrict__ Wtk,
    const float* __restrict__ Wtv, float* __restrict__ tk, float* __restrict__ tv)
{
    int n = blockIdx.x;
    int t = threadIdx.x;
    const float* W = (t < 128) ? Wtk : Wtv;
    float* outp    = (t < 128) ? tk : tv;
    int j = t & 127;
    float acc = 0.f;
    #pragma unroll 4
    for (int c = 0; c < 128; ++c)
        acc += te[n * 128 + c] * W[c * 128 + j];
    outp[n * 128 + j] = acc;
}

// ---------------------------------------------------------------------------
// K0b: pack emb (257 x 16 fp32) into fp16 (RTZ) for direct fragment loads
// ---------------------------------------------------------------------------
__global__ __launch_bounds__(256) void emb_pack(
    const float* __restrict__ emb, _Float16* __restrict__ embh)
{
    int r = blockIdx.x * 256 + threadIdx.x;
    if (r > 256) return;
    const float4* er = (const float4*)(emb + r * 16);
    float4 e0 = er[0], e1 = er[1], e2 = er[2], e3 = er[3];
    *(uint4*)(embh + r * 16)     = __builtin_bit_cast(uint4, pack8(e0, e1));
    *(uint4*)(embh + r * 16 + 8) = __builtin_bit_cast(uint4, pack8(e2, e3));
}

// ---------------------------------------------------------------------------
// K1: qkv GEMM via fp16 MFMA. Writes q/k/v NATURAL (r,c) fp16 (full-line
// stores); attn reads q/k fragments directly, V transposed by v_pack.
// ---------------------------------------------------------------------------
__global__ __launch_bounds__(256) void qkv_gemm(
    const float* __restrict__ x, const float* __restrict__ Wq,
    const float* __restrict__ tk, const float* __restrict__ tv,
    _Float16* __restrict__ qn, _Float16* __restrict__ kn, _Float16* __restrict__ vn)
{
    int tid  = threadIdx.x;
    int wave = tid >> 6, lane = tid & 63;
    int m32  = lane & 31, khalf = lane >> 5;
    int row0 = blockIdx.y * 64 + (wave & 1) * 32;
    int col0 = blockIdx.x * 64 + (wave >> 1) * 32;

    const float* xp = x  + (row0 + m32) * 128 + khalf * 8;
    const float* wp = Wq + (col0 + m32) * 128 + khalf * 8;

    f32x16 acc;
    #pragma unroll
    for (int i = 0; i < 16; ++i) acc[i] = 0.f;

    #pragma unroll
    for (int k0 = 0; k0 < 128; k0 += 16) {
        float4 xa = *(const float4*)(xp + k0);
        float4 xb = *(const float4*)(xp + k0 + 4);
        float4 wa = *(const float4*)(wp + k0);
        float4 wb = *(const float4*)(wp + k0 + 4);
        acc = __builtin_amdgcn_mfma_f32_32x32x16_f16(pack8(xa, xb), pack8(wa, wb), acc, 0, 0, 0);
    }

    int o   = col0 + m32;
    int sec = o >> 7;
    int rem = o & 127;
    #pragma unroll
    for (int reg = 0; reg < 16; ++reg) {
        int r = row0 + (reg & 3) + 8 * (reg >> 2) + 4 * khalf;  // r = f*400+n
        float val = acc[reg];
        if (sec == 0) {
            qn[r * 128 + rem] = h_rtz(val);
        } else {
            int f = r / 400;
            int n = r - f * 400;
            if (sec == 1) {
                kn[r * 128 + rem] = h_rtz(val + tk[n * 128 + rem]);
            } else {
                vn[r * 128 + rem] = (_Float16)(val + tv[n * 128 + rem]);  // RTN like old staging
            }
        }
    }
}

// ---------------------------------------------------------------------------
// K1b: V transpose per (n,h): natural (f, e) -> vT (n,h,e,f).
// ---------------------------------------------------------------------------
__global__ __launch_bounds__(256) void v_pack(
    const _Float16* __restrict__ vn, _Float16* __restrict__ vT)
{
    __shared__ _Float16 sm[16 * 264];
    int bn = blockIdx.x;             // n*8 + h
    int n  = bn >> 3, h = bn & 7;
    int t  = threadIdx.x;            // f = t

    const uint4* src = (const uint4*)(vn + (t * 400 + n) * 128 + h * 16);
    uint4 a = src[0], b = src[1];
    union { uint4 u; _Float16 hv[8]; } ua, ub;
    ua.u = a; ub.u = b;
    #pragma unroll
    for (int e = 0; e < 8; ++e) sm[e * 264 + t]       = ua.hv[e];
    #pragma unroll
    for (int e = 0; e < 8; ++e) sm[(e + 8) * 264 + t] = ub.hv[e];
    __syncthreads();

    #pragma unroll
    for (int k = 0; k < 2; ++k) {
        int idx = (k * 256 + t) * 8;         // halves into (e,f) plane
        int e = idx >> 8, f0 = idx & 255;
        uint4 o = *(const uint4*)(sm + e * 264 + f0);
        *(uint4*)(vT + bn * 4096 + idx) = o;
    }
}

// ---------------------------------------------------------------------------
// K2: MFMA flash attention per (n,h). 4 waves; wave w owns l in [64w,64w+64).
// r13 changes: (a) bias1 via SINGLE packed bpermute (W0,W1 as fp16 pair in
// one dword); (b) R2_STRIDE 298 (odd dword stride -> conflict-free gather);
// (c) y written fp16. LDS 29312B -> still 5 blocks/CU. (256,4) cap.
// ---------------------------------------------------------------------------
#define R2_STRIDE 298   // halves per R2 row; dword stride 149 (odd) = no bank conflict
#define PS_STRIDE 40    // halves per P row (80B, b128-aligned, odd-dword)

__global__ __launch_bounds__(256, 4) void attn_kernel(
    const _Float16* __restrict__ qb, const _Float16* __restrict__ kb,
    const _Float16* __restrict__ vb, const _Float16* __restrict__ embh,
    _Float16* __restrict__ y)
{
    __shared__ __align__(16) _Float16 R2sh[32 * R2_STRIDE];   // 19.1 KB
    __shared__ __align__(16) _Float16 Psh[4 * 32 * PS_STRIDE];// 10.2 KB

    int tid  = threadIdx.x;
    int wave = tid >> 6, lane = tid & 63;
    int bn   = blockIdx.x;            // n*8 + h
    int n    = bn >> 3, h = bn & 7;
    int base = bn * 4096;             // halves (vT only)

    int nn  = lane & 31;            // score col / s-local / frag m-or-n index
    int kh  = lane >> 5;            // wave half (frag k split for 32-shapes)
    int khb = (lane & 32) << 2;     // bpermute addr offset into own half
    int cbase = 31 + 4 * kh - nn;   // window col base per lane
    int dbase = 4 * kh - nn;        // d offset per lane
    int q16 = (lane >> 4) & 3;      // quad for 16x16 shapes

    // natural-layout fragment offset for this (n,h,kh)
    int nat_off = n * 128 + h * 16 + kh * 8;

    // Q fragments for this wave's two l-tiles (direct 16B loads from global)
    f16x8 aq[2];
    #pragma unroll
    for (int lt = 0; lt < 2; ++lt)
        aq[lt] = __builtin_bit_cast(f16x8,
            *(const uint4*)(qb + (64 * wave + 32 * lt + nn) * 51200 + nat_off));

    f32x4 O[2][2];
    #pragma unroll
    for (int i = 0; i < 2; ++i)
        #pragma unroll
        for (int j = 0; j < 2; ++j)
            #pragma unroll
            for (int r = 0; r < 4; ++r) O[i][j][r] = 0.f;
    float denom = 0.f;

    _Float16* psw = Psh + wave * 32 * PS_STRIDE;

    for (int st = 0; st < 8; ++st) {
        // K-tile fragment (A for R2, B for QK): row f = 32*st + nn
        f16x8 bk = __builtin_bit_cast(f16x8,
            *(const uint4*)(kb + (32 * st + nn) * 51200 + nat_off));

        // ---- shared R2 table: R2[s_local][d] = K[32st+s_local] . emb[d] ----
        for (int ct = wave; ct < 9; ct += 4) {
            int erow = 32 * ct + nn; if (erow > 256) erow = 256;
            f16x8 be = __builtin_bit_cast(f16x8,
                *(const uint4*)(embh + erow * 16 + kh * 8));
            f32x16 c2;
            #pragma unroll
            for (int i = 0; i < 16; ++i) c2[i] = 0.f;
            c2 = __builtin_amdgcn_mfma_f32_32x32x16_f16(bk, be, c2, 0, 0, 0);
            #pragma unroll
            for (int r = 0; r < 16; ++r) {
                int srow = (r & 3) + 8 * (r >> 2) + 4 * kh;
                R2sh[srow * R2_STRIDE + 32 * ct + nn] = (_Float16)c2[r];
            }
        }
        __syncthreads();   // R2 ready for all waves

        // PV B-fragment: V^T[e = lane&15][k = s-local = q16*8+j], direct global
        f16x8 bv = __builtin_bit_cast(f16x8,
            *(const uint4*)(vb + base + (lane & 15) * 256 + 32 * st + q16 * 8));

        #pragma unroll
        for (int lt = 0; lt < 2; ++lt) {
            int U0 = 64 * wave + 32 * lt - 32 * st + 128;

            // scores
            f32x16 S;
            #pragma unroll
            for (int i = 0; i < 16; ++i) S[i] = 0.f;
            S = __builtin_amdgcn_mfma_f32_32x32x16_f16(aq[lt], bk, S, 0, 0, 0);

            // bias1 windows: W[m][c] = Q[l0+m] . emb[clamp(U0-31+c)]
            int br0 = iclamp256(U0 - 31 + nn);
            int br1 = iclamp256(U0 + 1 + nn);
            f16x8 be0 = __builtin_bit_cast(f16x8,
                *(const uint4*)(embh + br0 * 16 + kh * 8));
            f16x8 be1 = __builtin_bit_cast(f16x8,
                *(const uint4*)(embh + br1 * 16 + kh * 8));
            f32x16 W0, W1;
            #pragma unroll
            for (int i = 0; i < 16; ++i) { W0[i] = 0.f; W1[i] = 0.f; }
            W0 = __builtin_amdgcn_mfma_f32_32x32x16_f16(aq[lt], be0, W0, 0, 0, 0);
            W1 = __builtin_amdgcn_mfma_f32_32x32x16_f16(aq[lt], be1, W1, 0, 0, 0);

            #pragma unroll
            for (int r = 0; r < 16; ++r) {
                int rmr = (r & 3) + 8 * (r >> 2);
                int c   = rmr + cbase;                 // [0,62]
                int addr = ((c & 31) << 2) + khb;
                // pack (W0[r], W1[r]) as fp16 pair -> ONE bpermute, select half
                int w01 = __builtin_bit_cast(int,
                    __builtin_amdgcn_cvt_pkrtz(W0[r], W1[r]));
                half2_t hh = __builtin_bit_cast(half2_t,
                    __builtin_amdgcn_ds_bpermute(addr, w01));
                float b1 = (float)((c < 32) ? hh[0] : hh[1]);
                int d = iclamp256(U0 + rmr + dbase);
                float b2 = (float)R2sh[nn * R2_STRIDE + d];
                float p = __expf((S[r] + b1 + b2) * 0.25f);
                int mloc = rmr + 4 * kh;
                psw[mloc * PS_STRIDE + nn] = (_Float16)p;
            }

            // denom: lane j (with j>>5==lt) sums its own row — ALL 32 values
            if ((lane >> 5) == lt) {
                const uint4* rp = (const uint4*)(psw + (lane & 31) * PS_STRIDE);
                uint4 u0 = rp[0], u1 = rp[1], u2 = rp[2], u3 = rp[3];
                half2_t hs0 =
                    (__builtin_bit_cast(half2_t, u0.x) + __builtin_bit_cast(half2_t, u0.y)) +
                    (__builtin_bit_cast(half2_t, u0.z) + __builtin_bit_cast(half2_t, u0.w));
                half2_t hs1 =
                    (__builtin_bit_cast(half2_t, u1.x) + __builtin_bit_cast(half2_t, u1.y)) +
                    (__builtin_bit_cast(half2_t, u1.z) + __builtin_bit_cast(half2_t, u1.w));
                half2_t hs2 =
                    (__builtin_bit_cast(half2_t, u2.x) + __builtin_bit_cast(half2_t, u2.y)) +
                    (__builtin_bit_cast(half2_t, u2.z) + __builtin_bit_cast(half2_t, u2.w));
                half2_t hs3 =
                    (__builtin_bit_cast(half2_t, u3.x) + __builtin_bit_cast(half2_t, u3.y)) +
                    (__builtin_bit_cast(half2_t, u3.z) + __builtin_bit_cast(half2_t, u3.w));
                half2_t hsum = (hs0 + hs1) + (hs2 + hs3);
                denom += (float)hsum.x + (float)hsum.y;
            }

            // PV: 2 sub-tiles of 16 l-rows each, K = 32 (this s-tile)
            #pragma unroll
            for (int a = 0; a < 2; ++a) {
                f16x8 ap = __builtin_bit_cast(f16x8,
                    *(const uint4*)(psw + (16 * a + (lane & 15)) * PS_STRIDE + q16 * 8));
                O[lt][a] = __builtin_amdgcn_mfma_f32_16x16x32_f16(ap, bv, O[lt][a], 0, 0, 0);
            }
        }
        __syncthreads();   // all reads of R2sh done before next st overwrites
    }

    // ---- epilogue: normalize + write (fp16 y) ----
    float inv = 1.0f / denom;   // lane owns l = 64*wave + lane
    int iinv = __builtin_bit_cast(int, inv);
    #pragma unroll
    for (int lt = 0; lt < 2; ++lt) {
        #pragma unroll
        for (int a = 0; a < 2; ++a) {
            #pragma unroll
            for (int r = 0; r < 4; ++r) {
                int row  = q16 * 4 + r;
                int lloc = 32 * lt + 16 * a + row;
                float dv = __builtin_bit_cast(float,
                    __builtin_amdgcn_ds_bpermute(lloc << 2, iinv));
                int lg = 64 * wave + lloc;
                y[(lg * 400 + n) * 128 + h * 16 + (lane & 15)] =
                    (_Float16)(O[lt][a][r] * dv);
            }
        }
    }
}

// ---------------------------------------------------------------------------
// K3: gate+LN1 (y now fp16)
// ---------------------------------------------------------------------------
__global__ __launch_bounds__(256) void gate_ln1(
    const float* __restrict__ x, const _Float16* __restrict__ yh,
    const float* __restrict__ Wb, const float* __restrict__ g,
    const float* __restrict__ b, float* __restrict__ h1)
{
    int tid  = threadIdx.x;
    int r    = blockIdx.x * 4 + (tid >> 6);
    int lane = tid & 63;
    int c    = lane * 2;

    float2 xv = *(const float2*)(x + r * 128 + c);
    half2_t yv2 = *(const half2_t*)(yh + r * 128 + c);
    float yvx = (float)yv2[0], yvy = (float)yv2[1];
    float2 w0 = *(const float2*)(Wb + c);
    float2 w1 = *(const float2*)(Wb + 128 + c);
    float2 w2 = *(const float2*)(Wb + 256 + c);

    float sv = yvx * w0.x + yvy * w0.y
             + xv.x * w1.x + xv.y * w1.y
             + (yvx - xv.x) * w2.x + (yvy - xv.y) * w2.y;
    #pragma unroll
    for (int off = 32; off > 0; off >>= 1) sv += __shfl_xor(sv, off);
    float gate = 1.0f / (1.0f + __expf(-sv));

    float z0 = gate * xv.x + (1.0f - gate) * yvx;
    float z1 = gate * xv.y + (1.0f - gate) * yvy;
    float s1 = z0 + z1, s2 = z0 * z0 + z1 * z1;
    #pragma unroll
    for (int off = 32; off > 0; off >>= 1) {
        s1 += __shfl_xor(s1, off);
        s2 += __shfl_xor(s2, off);
    }
    float mu  = s1 * (1.0f / 128.0f);
    float var = s2 * (1.0f / 128.0f) - mu * mu;
    float rs  = rsqrtf(var + 1e-5f);

    float2 gv = *(const float2*)(g + c);
    float2 bv = *(const float2*)(b + c);
    float2 ov;
    ov.x = (z0 - mu) * rs * gv.x + bv.x;
    ov.y = (z1 - mu) * rs * gv.y + bv.y;
    *(float2*)(h1 + r * 128 + c) = ov;
}

// ---------------------------------------------------------------------------
// K4: ff1 fp16 MFMA + exact GELU; output stored fp16
// ---------------------------------------------------------------------------
__global__ __launch_bounds__(256) void ff1_gemm(
    const float* __restrict__ A, const float* __restrict__ W,
    const float* __restrict__ bias, _Float16* __restrict__ outp)
{
    int tid  = threadIdx.x;
    int wave = tid >> 6, lane = tid & 63;
    int m32  = lane & 31, khalf = lane >> 5;
    int row0 = blockIdx.y * 64 + (wave & 1) * 32;
    int col0 = blockIdx.x * 64 + (wave >> 1) * 32;

    const float* ap = A + (row0 + m32) * 128 + khalf * 8;
    const float* wp = W + (col0 + m32) * 128 + khalf * 8;

    f32x16 acc;
    #pragma unroll
    for (int i = 0; i < 16; ++i) acc[i] = 0.f;

    #pragma unroll
    for (int k0 = 0; k0 < 128; k0 += 16) {
        float4 aa = *(const float4*)(ap + k0);
        float4 ab = *(const float4*)(ap + k0 + 4);
        float4 wa = *(const float4*)(wp + k0);
        float4 wb = *(const float4*)(wp + k0 + 4);
        acc = __builtin_amdgcn_mfma_f32_32x32x16_f16(pack8(aa, ab), pack8(wa, wb), acc, 0, 0, 0);
    }

    int   c  = col0 + m32;
    float bi = bias[c];
    #pragma unroll
    for (int reg = 0; reg < 16; ++reg) {
        int r = row0 + (reg & 3) + 8 * (reg >> 2) + 4 * khalf;
        float v = acc[reg] + bi;
        v = 0.5f * v * (1.0f + erff(v * 0.70710678118654752f));  // exact GELU
        outp[r * 128 + c] = (_Float16)v;
    }
}

// ---------------------------------------------------------------------------
// K5: ff2 + LN2 fp16 MFMA (A arrives fp16 -> direct f16x8 fragment loads)
// ---------------------------------------------------------------------------
__global__ __launch_bounds__(256) void ff2_ln2(
    const _Float16* __restrict__ A, const float* __restrict__ W2,
    const float* __restrict__ b2, const float* __restrict__ h1,
    const float* __restrict__ g, const float* __restrict__ bb,
    float* __restrict__ outp)
{
    __shared__ float Cs[32 * 132];
    int tid  = threadIdx.x;
    int wave = tid >> 6, lane = tid & 63;
    int m32  = lane & 31, khalf = lane >> 5;
    int row0 = blockIdx.x * 32;
    int col0 = wave * 32;

    const _Float16* ap = A  + (row0 + m32) * 128 + khalf * 8;
    const float*    wp = W2 + (col0 + m32) * 128 + khalf * 8;

    f32x16 acc;
    #pragma unroll
    for (int i = 0; i < 16; ++i) acc[i] = 0.f;

    #pragma unroll
    for (int k0 = 0; k0 < 128; k0 += 16) {
        f16x8 aa16 = __builtin_bit_cast(f16x8, *(const uint4*)(ap + k0));
        float4 wa = *(const float4*)(wp + k0);
        float4 wb = *(const float4*)(wp + k0 + 4);
        acc = __builtin_amdgcn_mfma_f32_32x32x16_f16(aa16, pack8(wa, wb), acc, 0, 0, 0);
    }

    #pragma unroll
    for (int reg = 0; reg < 16; ++reg) {
        int rloc = (reg & 3) + 8 * (reg >> 2) + 4 * khalf;
        Cs[rloc * 132 + col0 + m32] = acc[reg];
    }
    __syncthreads();

    int rloc = tid >> 3, seg = (tid & 7) * 16;
    int r = row0 + rloc;
    float z[16];
    float s1 = 0.f, s2 = 0.f;
    #pragma unroll
    for (int j4 = 0; j4 < 4; ++j4) {
        float4 cv = *(const float4*)(Cs + rloc * 132 + seg + j4 * 4);
        float4 hv = *(const float4*)(h1 + r * 128 + seg + j4 * 4);
        float4 bv = *(const float4*)(b2 + seg + j4 * 4);
        z[j4*4+0] = cv.x + bv.x + hv.x;
        z[j4*4+1] = cv.y + bv.y + hv.y;
        z[j4*4+2] = cv.z + bv.z + hv.z;
        z[j4*4+3] = cv.w + bv.w + hv.w;
        s1 += z[j4*4+0] + z[j4*4+1] + z[j4*4+2] + z[j4*4+3];
        s2 += z[j4*4+0]*z[j4*4+0] + z[j4*4+1]*z[j4*4+1]
            + z[j4*4+2]*z[j4*4+2] + z[j4*4+3]*z[j4*4+3];
    }
    #pragma unroll
    for (int off = 4; off > 0; off >>= 1) {
        s1 += __shfl_xor(s1, off);
        s2 += __shfl_xor(s2, off);
    }
    float mu  = s1 * (1.0f / 128.0f);
    float var = s2 * (1.0f / 128.0f) - mu * mu;
    float rs  = rsqrtf(var + 1e-5f);
    #pragma unroll
    for (int j4 = 0; j4 < 4; ++j4) {
        float4 gv = *(const float4*)(g  + seg + j4 * 4);
        float4 bv = *(const float4*)(bb + seg + j4 * 4);
        float4 ov;
        ov.x = (z[j4*4+0] - mu) * rs * gv.x + bv.x;
        ov.y = (z[j4*4+1] - mu) * rs * gv.y + bv.y;
        ov.z = (z[j4*4+2] - mu) * rs * gv.z + bv.z;
        ov.w = (z[j4*4+3] - mu) * rs * gv.w + bv.w;
        *(float4*)(outp + r * 128 + seg + j4 * 4) = ov;
    }
}

// ---------------------------------------------------------------------------
extern "C" void kernel_launch(void* const* d_in, const int* in_sizes, int n_in,
                              void* d_out, int out_size, void* d_ws, size_t ws_size,
                              hipStream_t stream)
{
    const float* x     = (const float*)d_in[0];
    const float* te    = (const float*)d_in[1];
    const float* Wqkv  = (const float*)d_in[2];
    const float* Wtk   = (const float*)d_in[3];
    const float* Wtv   = (const float*)d_in[4];
    const float* emb   = (const float*)d_in[5];
    const float* Wbeta = (const float*)d_in[6];
    const float* ln1g  = (const float*)d_in[7];
    const float* ln1b  = (const float*)d_in[8];
    const float* ln2g  = (const float*)d_in[9];
    const float* ln2b  = (const float*)d_in[10];
    const float* W1    = (const float*)d_in[11];
    const float* b1    = (const float*)d_in[12];
    const float* W2    = (const float*)d_in[13];
    const float* b2    = (const float*)d_in[14];
    float* outp = (float*)d_out;

    float* ws = (float*)d_ws;
    float* tk = ws;                        // 51200
    float* tv = ws + 51200;                // 51200
    float* qb_region = ws + 102400;        // SBUF floats
    float* kb_region = qb_region + SBUF;   // SBUF floats
    float* vb_region = kb_region + SBUF;   // SBUF floats
    float* yb        = vb_region + SBUF;   // SBUF floats

    _Float16* qnat = (_Float16*)qb_region;                   // natural (r,c) fp16
    _Float16* knat = (_Float16*)kb_region;                   // natural (r,c) fp16
    _Float16* vnat = (_Float16*)vb_region;                   // natural (r,c) fp16
    _Float16* vT   = (_Float16*)(vb_region + SBUF / 2);      // (n,h,e,f) fp16
    _Float16* embh = (_Float16*)(qb_region + SBUF / 2);      // spare half of q region
    _Float16* yh   = (_Float16*)yb;                          // y fp16 (f,n,c)

    float*    h1   = kb_region;            // reuse: k dead after attention
    _Float16* ff1h = (_Float16*)qb_region; // reuse: q dead after attention

    tree_proj<<<400, 256, 0, stream>>>(te, Wtk, Wtv, tk, tv);
    emb_pack<<<2, 256, 0, stream>>>(emb, embh);
    qkv_gemm<<<dim3(6, 1600), 256, 0, stream>>>(x, Wqkv, tk, tv, qnat, knat, vnat);
    v_pack<<<3200, 256, 0, stream>>>(vnat, vT);
    attn_kernel<<<3200, 256, 0, stream>>>(qnat, knat, vT, embh, yh);
    gate_ln1<<<ROWS / 4, 256, 0, stream>>>(x, yh, Wbeta, ln1g, ln1b, h1);
    ff1_gemm<<<dim3(2, 1600), 256, 0, stream>>>(h1, W1, b1, ff1h);
    ff2_ln2<<<3200, 256, 0, stream>>>(ff1h, W2, b2, h1, ln2g, ln2b, outp);
}

// Round 7
// 547.867 us; speedup vs baseline: 1.7951x; 1.1076x over previous
//
#include <hip/hip_runtime.h>
#include <math.h>

// Problem constants
#define F_DIM 256
#define N_DIM 400
#define C_DIM 128
#define H_DIM 8
#define E_DIM 16
#define ROWS  (F_DIM * N_DIM)          // 102400
#define SBUF  (N_DIM * H_DIM * F_DIM * E_DIM)  // 13107200 floats per q/k/v region

// r14: r13 verified 607us (attn 199 steady, VALUBusy 60%, occ 39%, LDS
// 29696 -> 5 blocks/CU). This round:
//  (1) R2_STRIDE 298->258 (cols 257..287 were never read; d clamped <=256)
//      -> LDS 27136 -> 6 blocks/CU.
//  (2) fold s=sqrt(0.25*log2e)=0.6005612 into q/k/emb packing; element loop
//      uses exp2f(S+b1+b2) directly (drops *0.25 and *log2e VALU).
//  (3) xw_pack: x and W_qkv pre-packed fp16 RTZ (bit-identical inputs);
//      qkv_gemm loses 32 cvts/k-step and halves its x stream (read 6x).
//  (4) attn grid XCD-swizzle: bn and bn^1 share q/k lines -> same XCD.
#define S_SCALE 0.6005612043932249f

typedef _Float16 half2_t __attribute__((ext_vector_type(2)));
typedef _Float16 f16x8   __attribute__((ext_vector_type(8)));
typedef float    f32x16  __attribute__((ext_vector_type(16)));
typedef float    f32x4   __attribute__((ext_vector_type(4)));

struct H2x4 { half2_t h[4]; };

// pack 8 consecutive fp32 (two float4) into an f16x8 fragment (RTZ)
__device__ inline f16x8 pack8(float4 a, float4 b) {
    H2x4 t;
    t.h[0] = __builtin_bit_cast(half2_t, __builtin_amdgcn_cvt_pkrtz(a.x, a.y));
    t.h[1] = __builtin_bit_cast(half2_t, __builtin_amdgcn_cvt_pkrtz(a.z, a.w));
    t.h[2] = __builtin_bit_cast(half2_t, __builtin_amdgcn_cvt_pkrtz(b.x, b.y));
    t.h[3] = __builtin_bit_cast(half2_t, __builtin_amdgcn_cvt_pkrtz(b.z, b.w));
    return __builtin_bit_cast(f16x8, t);
}

// scalar fp32 -> fp16 with RTZ (matches pack8 rounding)
__device__ inline _Float16 h_rtz(float v) {
    half2_t p = __builtin_bit_cast(half2_t, __builtin_amdgcn_cvt_pkrtz(v, v));
    return p[0];
}

__device__ inline int iclamp256(int v) { return v < 0 ? 0 : (v > 256 ? 256 : v); }

// ---------------------------------------------------------------------------
// K0: tree_k / tree_v projections (unchanged)
// ---------------------------------------------------------------------------
__global__ __launch_bounds__(256) void tree_proj(
    const float* __restrict__ te, const float* __restrict__ Wtk,
    const float* __restrict__ Wtv, float* __restrict__ tk, float* __restrict__ tv)
{
    int n = blockIdx.x;
    int t = threadIdx.x;
    const float* W = (t < 128) ? Wtk : Wtv;
    float* outp    = (t < 128) ? tk : tv;
    int j = t & 127;
    float acc = 0.f;
    #pragma unroll 4
    for (int c = 0; c < 128; ++c)
        acc += te[n * 128 + c] * W[c * 128 + j];
    outp[n * 128 + j] = acc;
}

// ---------------------------------------------------------------------------
// K0b: pack emb (257 x 16 fp32) into fp16 (RTZ), scaled by S_SCALE
// ---------------------------------------------------------------------------
__global__ __launch_bounds__(256) void emb_pack(
    const float* __restrict__ emb, _Float16* __restrict__ embh)
{
    int r = blockIdx.x * 256 + threadIdx.x;
    if (r > 256) return;
    const float4* er = (const float4*)(emb + r * 16);
    float4 e0 = er[0], e1 = er[1], e2 = er[2], e3 = er[3];
    e0.x *= S_SCALE; e0.y *= S_SCALE; e0.z *= S_SCALE; e0.w *= S_SCALE;
    e1.x *= S_SCALE; e1.y *= S_SCALE; e1.z *= S_SCALE; e1.w *= S_SCALE;
    e2.x *= S_SCALE; e2.y *= S_SCALE; e2.z *= S_SCALE; e2.w *= S_SCALE;
    e3.x *= S_SCALE; e3.y *= S_SCALE; e3.z *= S_SCALE; e3.w *= S_SCALE;
    *(uint4*)(embh + r * 16)     = __builtin_bit_cast(uint4, pack8(e0, e1));
    *(uint4*)(embh + r * 16 + 8) = __builtin_bit_cast(uint4, pack8(e2, e3));
}

// ---------------------------------------------------------------------------
// K0c: pack x (13107200 fl) and W_qkv (49152 fl) to fp16 RTZ (unscaled --
// identical to the cvt qkv_gemm used to do per-fragment). grid 6424.
// ---------------------------------------------------------------------------
__global__ __launch_bounds__(256) void xw_pack(
    const float* __restrict__ x, const float* __restrict__ Wq,
    _Float16* __restrict__ xh, _Float16* __restrict__ Wqh)
{
    if (blockIdx.x < 6400) {
        int i = (blockIdx.x * 256 + threadIdx.x) * 8;      // exact: 6400*256*8 = 13107200
        const float4* s = (const float4*)(x + i);
        *(uint4*)(xh + i) = __builtin_bit_cast(uint4, pack8(s[0], s[1]));
    } else {
        int i = ((blockIdx.x - 6400) * 256 + threadIdx.x) * 8;  // exact: 24*256*8 = 49152
        const float4* s = (const float4*)(Wq + i);
        *(uint4*)(Wqh + i) = __builtin_bit_cast(uint4, pack8(s[0], s[1]));
    }
}

// ---------------------------------------------------------------------------
// K1: qkv GEMM via fp16 MFMA; inputs pre-packed fp16 (direct f16x8 loads).
// q/k stores scaled by S_SCALE (softmax scale folded; see r14 note).
// Natural (r,c) fp16 stores (full-line); V transposed by v_pack.
// ---------------------------------------------------------------------------
__global__ __launch_bounds__(256) void qkv_gemm(
    const _Float16* __restrict__ xh, const _Float16* __restrict__ Wqh,
    const float* __restrict__ tk, const float* __restrict__ tv,
    _Float16* __restrict__ qn, _Float16* __restrict__ kn, _Float16* __restrict__ vn)
{
    int tid  = threadIdx.x;
    int wave = tid >> 6, lane = tid & 63;
    int m32  = lane & 31, khalf = lane >> 5;
    int row0 = blockIdx.y * 64 + (wave & 1) * 32;
    int col0 = blockIdx.x * 64 + (wave >> 1) * 32;

    const _Float16* xp = xh  + (row0 + m32) * 128 + khalf * 8;
    const _Float16* wp = Wqh + (col0 + m32) * 128 + khalf * 8;

    f32x16 acc;
    #pragma unroll
    for (int i = 0; i < 16; ++i) acc[i] = 0.f;

    #pragma unroll
    for (int k0 = 0; k0 < 128; k0 += 16) {
        f16x8 xa = __builtin_bit_cast(f16x8, *(const uint4*)(xp + k0));
        f16x8 wa = __builtin_bit_cast(f16x8, *(const uint4*)(wp + k0));
        acc = __builtin_amdgcn_mfma_f32_32x32x16_f16(xa, wa, acc, 0, 0, 0);
    }

    int o   = col0 + m32;
    int sec = o >> 7;
    int rem = o & 127;
    #pragma unroll
    for (int reg = 0; reg < 16; ++reg) {
        int r = row0 + (reg & 3) + 8 * (reg >> 2) + 4 * khalf;  // r = f*400+n
        float val = acc[reg];
        if (sec == 0) {
            qn[r * 128 + rem] = h_rtz(val * S_SCALE);
        } else {
            int f = r / 400;
            int n = r - f * 400;
            if (sec == 1) {
                kn[r * 128 + rem] = h_rtz((val + tk[n * 128 + rem]) * S_SCALE);
            } else {
                vn[r * 128 + rem] = (_Float16)(val + tv[n * 128 + rem]);  // RTN, unscaled
            }
        }
    }
}

// ---------------------------------------------------------------------------
// K1b: V transpose per (n,h): natural (f, e) -> vT (n,h,e,f).
// ---------------------------------------------------------------------------
__global__ __launch_bounds__(256) void v_pack(
    const _Float16* __restrict__ vn, _Float16* __restrict__ vT)
{
    __shared__ _Float16 sm[16 * 264];
    int bn = blockIdx.x;             // n*8 + h
    int n  = bn >> 3, h = bn & 7;
    int t  = threadIdx.x;            // f = t

    const uint4* src = (const uint4*)(vn + (t * 400 + n) * 128 + h * 16);
    uint4 a = src[0], b = src[1];
    union { uint4 u; _Float16 hv[8]; } ua, ub;
    ua.u = a; ub.u = b;
    #pragma unroll
    for (int e = 0; e < 8; ++e) sm[e * 264 + t]       = ua.hv[e];
    #pragma unroll
    for (int e = 0; e < 8; ++e) sm[(e + 8) * 264 + t] = ub.hv[e];
    __syncthreads();

    #pragma unroll
    for (int k = 0; k < 2; ++k) {
        int idx = (k * 256 + t) * 8;         // halves into (e,f) plane
        int e = idx >> 8, f0 = idx & 255;
        uint4 o = *(const uint4*)(sm + e * 264 + f0);
        *(uint4*)(vT + bn * 4096 + idx) = o;
    }
}

// ---------------------------------------------------------------------------
// K2: MFMA flash attention per (n,h). 4 waves; wave w owns l in [64w,64w+64).
// r14: R2_STRIDE 258 (cols >257 never read; write-guarded) -> LDS 27136 ->
// 6 blocks/CU. exp2f with pre-folded scale. XCD-swizzled bn.
// ---------------------------------------------------------------------------
#define R2_STRIDE 258   // halves per R2 row; dword stride 129 (odd) = conflict-free
#define PS_STRIDE 40    // halves per P row (80B, b128-aligned, odd-dword)

__global__ __launch_bounds__(256, 4) void attn_kernel(
    const _Float16* __restrict__ qb, const _Float16* __restrict__ kb,
    const _Float16* __restrict__ vb, const _Float16* __restrict__ embh,
    _Float16* __restrict__ y)
{
    __shared__ __align__(16) _Float16 R2sh[32 * R2_STRIDE];   // 16.5 KB
    __shared__ __align__(16) _Float16 Psh[4 * 32 * PS_STRIDE];// 10.2 KB

    int tid  = threadIdx.x;
    int wave = tid >> 6, lane = tid & 63;
    int bid  = blockIdx.x;
    // XCD swizzle: consecutive bn (which share q/k cache lines) -> same XCD.
    int bn   = (bid & 7) * 400 + (bid >> 3);   // 3200 % 8 == 0: bijective
    int n    = bn >> 3, h = bn & 7;
    int base = bn * 4096;             // halves (vT only)

    int nn  = lane & 31;            // score col / s-local / frag m-or-n index
    int kh  = lane >> 5;            // wave half (frag k split for 32-shapes)
    int khb = (lane & 32) << 2;     // bpermute addr offset into own half
    int cbase = 31 + 4 * kh - nn;   // window col base per lane
    int dbase = 4 * kh - nn;        // d offset per lane
    int q16 = (lane >> 4) & 3;      // quad for 16x16 shapes

    // natural-layout fragment offset for this (n,h,kh)
    int nat_off = n * 128 + h * 16 + kh * 8;

    // Q fragments for this wave's two l-tiles (direct 16B loads from global)
    f16x8 aq[2];
    #pragma unroll
    for (int lt = 0; lt < 2; ++lt)
        aq[lt] = __builtin_bit_cast(f16x8,
            *(const uint4*)(qb + (64 * wave + 32 * lt + nn) * 51200 + nat_off));

    f32x4 O[2][2];
    #pragma unroll
    for (int i = 0; i < 2; ++i)
        #pragma unroll
        for (int j = 0; j < 2; ++j)
            #pragma unroll
            for (int r = 0; r < 4; ++r) O[i][j][r] = 0.f;
    float denom = 0.f;

    _Float16* psw = Psh + wave * 32 * PS_STRIDE;

    for (int st = 0; st < 8; ++st) {
        // K-tile fragment (A for R2, B for QK): row f = 32*st + nn
        f16x8 bk = __builtin_bit_cast(f16x8,
            *(const uint4*)(kb + (32 * st + nn) * 51200 + nat_off));

        // ---- shared R2 table: R2[s_local][d] = K[32st+s_local] . emb[d] ----
        for (int ct = wave; ct < 9; ct += 4) {
            int erow = 32 * ct + nn; if (erow > 256) erow = 256;
            f16x8 be = __builtin_bit_cast(f16x8,
                *(const uint4*)(embh + erow * 16 + kh * 8));
            f32x16 c2;
            #pragma unroll
            for (int i = 0; i < 16; ++i) c2[i] = 0.f;
            c2 = __builtin_amdgcn_mfma_f32_32x32x16_f16(bk, be, c2, 0, 0, 0);
            int col = 32 * ct + nn;
            if (col <= 257) {
                #pragma unroll
                for (int r = 0; r < 16; ++r) {
                    int srow = (r & 3) + 8 * (r >> 2) + 4 * kh;
                    R2sh[srow * R2_STRIDE + col] = (_Float16)c2[r];
                }
            }
        }
        __syncthreads();   // R2 ready for all waves

        // PV B-fragment: V^T[e = lane&15][k = s-local = q16*8+j], direct global
        f16x8 bv = __builtin_bit_cast(f16x8,
            *(const uint4*)(vb + base + (lane & 15) * 256 + 32 * st + q16 * 8));

        #pragma unroll
        for (int lt = 0; lt < 2; ++lt) {
            int U0 = 64 * wave + 32 * lt - 32 * st + 128;

            // scores
            f32x16 S;
            #pragma unroll
            for (int i = 0; i < 16; ++i) S[i] = 0.f;
            S = __builtin_amdgcn_mfma_f32_32x32x16_f16(aq[lt], bk, S, 0, 0, 0);

            // bias1 windows: W[m][c] = Q[l0+m] . emb[clamp(U0-31+c)]
            int br0 = iclamp256(U0 - 31 + nn);
            int br1 = iclamp256(U0 + 1 + nn);
            f16x8 be0 = __builtin_bit_cast(f16x8,
                *(const uint4*)(embh + br0 * 16 + kh * 8));
            f16x8 be1 = __builtin_bit_cast(f16x8,
                *(const uint4*)(embh + br1 * 16 + kh * 8));
            f32x16 W0, W1;
            #pragma unroll
            for (int i = 0; i < 16; ++i) { W0[i] = 0.f; W1[i] = 0.f; }
            W0 = __builtin_amdgcn_mfma_f32_32x32x16_f16(aq[lt], be0, W0, 0, 0, 0);
            W1 = __builtin_amdgcn_mfma_f32_32x32x16_f16(aq[lt], be1, W1, 0, 0, 0);

            #pragma unroll
            for (int r = 0; r < 16; ++r) {
                int rmr = (r & 3) + 8 * (r >> 2);
                int c   = rmr + cbase;                 // [0,62]
                int addr = ((c & 31) << 2) + khb;
                // pack (W0[r], W1[r]) as fp16 pair -> ONE bpermute, select half
                int w01 = __builtin_bit_cast(int,
                    __builtin_amdgcn_cvt_pkrtz(W0[r], W1[r]));
                half2_t hh = __builtin_bit_cast(half2_t,
                    __builtin_amdgcn_ds_bpermute(addr, w01));
                float b1 = (float)((c < 32) ? hh[0] : hh[1]);
                int d = iclamp256(U0 + rmr + dbase);
                float b2 = (float)R2sh[nn * R2_STRIDE + d];
                float p = exp2f(S[r] + b1 + b2);   // scale pre-folded into q/k/emb
                int mloc = rmr + 4 * kh;
                psw[mloc * PS_STRIDE + nn] = (_Float16)p;
            }

            // denom: lane j (with j>>5==lt) sums its own row — ALL 32 values
            if ((lane >> 5) == lt) {
                const uint4* rp = (const uint4*)(psw + (lane & 31) * PS_STRIDE);
                uint4 u0 = rp[0], u1 = rp[1], u2 = rp[2], u3 = rp[3];
                half2_t hs0 =
                    (__builtin_bit_cast(half2_t, u0.x) + __builtin_bit_cast(half2_t, u0.y)) +
                    (__builtin_bit_cast(half2_t, u0.z) + __builtin_bit_cast(half2_t, u0.w));
                half2_t hs1 =
                    (__builtin_bit_cast(half2_t, u1.x) + __builtin_bit_cast(half2_t, u1.y)) +
                    (__builtin_bit_cast(half2_t, u1.z) + __builtin_bit_cast(half2_t, u1.w));
                half2_t hs2 =
                    (__builtin_bit_cast(half2_t, u2.x) + __builtin_bit_cast(half2_t, u2.y)) +
                    (__builtin_bit_cast(half2_t, u2.z) + __builtin_bit_cast(half2_t, u2.w));
                half2_t hs3 =
                    (__builtin_bit_cast(half2_t, u3.x) + __builtin_bit_cast(half2_t, u3.y)) +
                    (__builtin_bit_cast(half2_t, u3.z) + __builtin_bit_cast(half2_t, u3.w));
                half2_t hsum = (hs0 + hs1) + (hs2 + hs3);
                denom += (float)hsum.x + (float)hsum.y;
            }

            // PV: 2 sub-tiles of 16 l-rows each, K = 32 (this s-tile)
            #pragma unroll
            for (int a = 0; a < 2; ++a) {
                f16x8 ap = __builtin_bit_cast(f16x8,
                    *(const uint4*)(psw + (16 * a + (lane & 15)) * PS_STRIDE + q16 * 8));
                O[lt][a] = __builtin_amdgcn_mfma_f32_16x16x32_f16(ap, bv, O[lt][a], 0, 0, 0);
            }
        }
        __syncthreads();   // all reads of R2sh done before next st overwrites
    }

    // ---- epilogue: normalize + write (fp16 y) ----
    float inv = 1.0f / denom;   // lane owns l = 64*wave + lane
    int iinv = __builtin_bit_cast(int, inv);
    #pragma unroll
    for (int lt = 0; lt < 2; ++lt) {
        #pragma unroll
        for (int a = 0; a < 2; ++a) {
            #pragma unroll
            for (int r = 0; r < 4; ++r) {
                int row  = q16 * 4 + r;
                int lloc = 32 * lt + 16 * a + row;
                float dv = __builtin_bit_cast(float,
                    __builtin_amdgcn_ds_bpermute(lloc << 2, iinv));
                int lg = 64 * wave + lloc;
                y[(lg * 400 + n) * 128 + h * 16 + (lane & 15)] =
                    (_Float16)(O[lt][a][r] * dv);
            }
        }
    }
}

// ---------------------------------------------------------------------------
// K3: gate+LN1 (y fp16)
// ---------------------------------------------------------------------------
__global__ __launch_bounds__(256) void gate_ln1(
    const float* __restrict__ x, const _Float16* __restrict__ yh,
    const float* __restrict__ Wb, const float* __restrict__ g,
    const float* __restrict__ b, float* __restrict__ h1)
{
    int tid  = threadIdx.x;
    int r    = blockIdx.x * 4 + (tid >> 6);
    int lane = tid & 63;
    int c    = lane * 2;

    float2 xv = *(const float2*)(x + r * 128 + c);
    half2_t yv2 = *(const half2_t*)(yh + r * 128 + c);
    float yvx = (float)yv2[0], yvy = (float)yv2[1];
    float2 w0 = *(const float2*)(Wb + c);
    float2 w1 = *(const float2*)(Wb + 128 + c);
    float2 w2 = *(const float2*)(Wb + 256 + c);

    float sv = yvx * w0.x + yvy * w0.y
             + xv.x * w1.x + xv.y * w1.y
             + (yvx - xv.x) * w2.x + (yvy - xv.y) * w2.y;
    #pragma unroll
    for (int off = 32; off > 0; off >>= 1) sv += __shfl_xor(sv, off);
    float gate = 1.0f / (1.0f + __expf(-sv));

    float z0 = gate * xv.x + (1.0f - gate) * yvx;
    float z1 = gate * xv.y + (1.0f - gate) * yvy;
    float s1 = z0 + z1, s2 = z0 * z0 + z1 * z1;
    #pragma unroll
    for (int off = 32; off > 0; off >>= 1) {
        s1 += __shfl_xor(s1, off);
        s2 += __shfl_xor(s2, off);
    }
    float mu  = s1 * (1.0f / 128.0f);
    float var = s2 * (1.0f / 128.0f) - mu * mu;
    float rs  = rsqrtf(var + 1e-5f);

    float2 gv = *(const float2*)(g + c);
    float2 bv = *(const float2*)(b + c);
    float2 ov;
    ov.x = (z0 - mu) * rs * gv.x + bv.x;
    ov.y = (z1 - mu) * rs * gv.y + bv.y;
    *(float2*)(h1 + r * 128 + c) = ov;
}

// ---------------------------------------------------------------------------
// K4: ff1 fp16 MFMA + exact GELU; output stored fp16
// ---------------------------------------------------------------------------
__global__ __launch_bounds__(256) void ff1_gemm(
    const float* __restrict__ A, const float* __restrict__ W,
    const float* __restrict__ bias, _Float16* __restrict__ outp)
{
    int tid  = threadIdx.x;
    int wave = tid >> 6, lane = tid & 63;
    int m32  = lane & 31, khalf = lane >> 5;
    int row0 = blockIdx.y * 64 + (wave & 1) * 32;
    int col0 = blockIdx.x * 64 + (wave >> 1) * 32;

    const float* ap = A + (row0 + m32) * 128 + khalf * 8;
    const float* wp = W + (col0 + m32) * 128 + khalf * 8;

    f32x16 acc;
    #pragma unroll
    for (int i = 0; i < 16; ++i) acc[i] = 0.f;

    #pragma unroll
    for (int k0 = 0; k0 < 128; k0 += 16) {
        float4 aa = *(const float4*)(ap + k0);
        float4 ab = *(const float4*)(ap + k0 + 4);
        float4 wa = *(const float4*)(wp + k0);
        float4 wb = *(const float4*)(wp + k0 + 4);
        acc = __builtin_amdgcn_mfma_f32_32x32x16_f16(pack8(aa, ab), pack8(wa, wb), acc, 0, 0, 0);
    }

    int   c  = col0 + m32;
    float bi = bias[c];
    #pragma unroll
    for (int reg = 0; reg < 16; ++reg) {
        int r = row0 + (reg & 3) + 8 * (reg >> 2) + 4 * khalf;
        float v = acc[reg] + bi;
        v = 0.5f * v * (1.0f + erff(v * 0.70710678118654752f));  // exact GELU
        outp[r * 128 + c] = (_Float16)v;
    }
}

// ---------------------------------------------------------------------------
// K5: ff2 + LN2 fp16 MFMA (A arrives fp16 -> direct f16x8 fragment loads)
// ---------------------------------------------------------------------------
__global__ __launch_bounds__(256) void ff2_ln2(
    const _Float16* __restrict__ A, const float* __restrict__ W2,
    const float* __restrict__ b2, const float* __restrict__ h1,
    const float* __restrict__ g, const float* __restrict__ bb,
    float* __restrict__ outp)
{
    __shared__ float Cs[32 * 132];
    int tid  = threadIdx.x;
    int wave = tid >> 6, lane = tid & 63;
    int m32  = lane & 31, khalf = lane >> 5;
    int row0 = blockIdx.x * 32;
    int col0 = wave * 32;

    const _Float16* ap = A  + (row0 + m32) * 128 + khalf * 8;
    const float*    wp = W2 + (col0 + m32) * 128 + khalf * 8;

    f32x16 acc;
    #pragma unroll
    for (int i = 0; i < 16; ++i) acc[i] = 0.f;

    #pragma unroll
    for (int k0 = 0; k0 < 128; k0 += 16) {
        f16x8 aa16 = __builtin_bit_cast(f16x8, *(const uint4*)(ap + k0));
        float4 wa = *(const float4*)(wp + k0);
        float4 wb = *(const float4*)(wp + k0 + 4);
        acc = __builtin_amdgcn_mfma_f32_32x32x16_f16(aa16, pack8(wa, wb), acc, 0, 0, 0);
    }

    #pragma unroll
    for (int reg = 0; reg < 16; ++reg) {
        int rloc = (reg & 3) + 8 * (reg >> 2) + 4 * khalf;
        Cs[rloc * 132 + col0 + m32] = acc[reg];
    }
    __syncthreads();

    int rloc = tid >> 3, seg = (tid & 7) * 16;
    int r = row0 + rloc;
    float z[16];
    float s1 = 0.f, s2 = 0.f;
    #pragma unroll
    for (int j4 = 0; j4 < 4; ++j4) {
        float4 cv = *(const float4*)(Cs + rloc * 132 + seg + j4 * 4);
        float4 hv = *(const float4*)(h1 + r * 128 + seg + j4 * 4);
        float4 bv = *(const float4*)(b2 + seg + j4 * 4);
        z[j4*4+0] = cv.x + bv.x + hv.x;
        z[j4*4+1] = cv.y + bv.y + hv.y;
        z[j4*4+2] = cv.z + bv.z + hv.z;
        z[j4*4+3] = cv.w + bv.w + hv.w;
        s1 += z[j4*4+0] + z[j4*4+1] + z[j4*4+2] + z[j4*4+3];
        s2 += z[j4*4+0]*z[j4*4+0] + z[j4*4+1]*z[j4*4+1]
            + z[j4*4+2]*z[j4*4+2] + z[j4*4+3]*z[j4*4+3];
    }
    #pragma unroll
    for (int off = 4; off > 0; off >>= 1) {
        s1 += __shfl_xor(s1, off);
        s2 += __shfl_xor(s2, off);
    }
    float mu  = s1 * (1.0f / 128.0f);
    float var = s2 * (1.0f / 128.0f) - mu * mu;
    float rs  = rsqrtf(var + 1e-5f);
    #pragma unroll
    for (int j4 = 0; j4 < 4; ++j4) {
        float4 gv = *(const float4*)(g  + seg + j4 * 4);
        float4 bv = *(const float4*)(bb + seg + j4 * 4);
        float4 ov;
        ov.x = (z[j4*4+0] - mu) * rs * gv.x + bv.x;
        ov.y = (z[j4*4+1] - mu) * rs * gv.y + bv.y;
        ov.z = (z[j4*4+2] - mu) * rs * gv.z + bv.z;
        ov.w = (z[j4*4+3] - mu) * rs * gv.w + bv.w;
        *(float4*)(outp + r * 128 + seg + j4 * 4) = ov;
    }
}

// ---------------------------------------------------------------------------
extern "C" void kernel_launch(void* const* d_in, const int* in_sizes, int n_in,
                              void* d_out, int out_size, void* d_ws, size_t ws_size,
                              hipStream_t stream)
{
    const float* x     = (const float*)d_in[0];
    const float* te    = (const float*)d_in[1];
    const float* Wqkv  = (const float*)d_in[2];
    const float* Wtk   = (const float*)d_in[3];
    const float* Wtv   = (const float*)d_in[4];
    const float* emb   = (const float*)d_in[5];
    const float* Wbeta = (const float*)d_in[6];
    const float* ln1g  = (const float*)d_in[7];
    const float* ln1b  = (const float*)d_in[8];
    const float* ln2g  = (const float*)d_in[9];
    const float* ln2b  = (const float*)d_in[10];
    const float* W1    = (const float*)d_in[11];
    const float* b1    = (const float*)d_in[12];
    const float* W2    = (const float*)d_in[13];
    const float* b2    = (const float*)d_in[14];
    float* outp = (float*)d_out;

    float* ws = (float*)d_ws;
    float* tk = ws;                        // 51200
    float* tv = ws + 51200;                // 51200
    float* qb_region = ws + 102400;        // SBUF floats
    float* kb_region = qb_region + SBUF;   // SBUF floats
    float* vb_region = kb_region + SBUF;   // SBUF floats
    float* yb        = vb_region + SBUF;   // SBUF floats

    _Float16* qnat = (_Float16*)qb_region;                   // natural (r,c) fp16
    _Float16* knat = (_Float16*)kb_region;                   // natural (r,c) fp16
    _Float16* vnat = (_Float16*)vb_region;                   // natural (r,c) fp16
    _Float16* vT   = (_Float16*)(vb_region + SBUF / 2);      // (n,h,e,f) fp16
    _Float16* embh = (_Float16*)(qb_region + SBUF / 2);      // spare half of q region
    _Float16* yh   = (_Float16*)yb;                          // y fp16 (f,n,c), lower half
    _Float16* xh   = (_Float16*)(kb_region + SBUF / 2);      // x fp16 (dead when h1 written)
    _Float16* Wqh  = (_Float16*)(yb + SBUF / 2);             // W_qkv fp16 (yb upper, free)

    float*    h1   = kb_region;            // reuse: k+xh dead after attention
    _Float16* ff1h = (_Float16*)qb_region; // reuse: q+embh dead after attention

    tree_proj<<<400, 256, 0, stream>>>(te, Wtk, Wtv, tk, tv);
    emb_pack<<<2, 256, 0, stream>>>(emb, embh);
    xw_pack<<<6424, 256, 0, stream>>>(x, Wqkv, xh, Wqh);
    qkv_gemm<<<dim3(6, 1600), 256, 0, stream>>>(xh, Wqh, tk, tv, qnat, knat, vnat);
    v_pack<<<3200, 256, 0, stream>>>(vnat, vT);
    attn_kernel<<<3200, 256, 0, stream>>>(qnat, knat, vT, embh, yh);
    gate_ln1<<<ROWS / 4, 256, 0, stream>>>(x, yh, Wbeta, ln1g, ln1b, h1);
    ff1_gemm<<<dim3(2, 1600), 256, 0, stream>>>(h1, W1, b1, ff1h);
    ff2_ln2<<<3200, 256, 0, stream>>>(ff1h, W2, b2, h1, ln2g, ln2b, outp);
}

// Round 8
// 531.327 us; speedup vs baseline: 1.8509x; 1.0311x over previous
//
#include <hip/hip_runtime.h>
#include <math.h>

// Problem constants
#define F_DIM 256
#define N_DIM 400
#define C_DIM 128
#define H_DIM 8
#define E_DIM 16
#define ROWS  (F_DIM * N_DIM)          // 102400
#define SBUF  (N_DIM * H_DIM * F_DIM * E_DIM)  // 13107200 floats per q/k/v region

// r15: r14 verified 548us (attn 191.7, VALUBusy 70%, conflicts 6.92M
// unchanged -> traced to denom row-read: dword stride 20, gcd(20,32)=4 ->
// 4-way). This round:
//  (1) denominator via ones-MFMA: rowsum(P) = mfma_16x16x32(ap, ones)
//      accumulated across tiles; output layout matches O exactly ->
//      deletes divergent denom block (4x conflicted uint4 reads + fp16
//      adds) AND the 16 epilogue ds_bpermutes. +2 MFMAs/(st,lt) on the
//      idle matrix pipe, +16 VGPR (~80 < 128 cap).
//  (2) prep_pack: tree_proj + emb_pack + xw_pack merged (9->7 launches).
#define S_SCALE 0.6005612043932249f

typedef _Float16 half2_t __attribute__((ext_vector_type(2)));
typedef _Float16 f16x8   __attribute__((ext_vector_type(8)));
typedef float    f32x16  __attribute__((ext_vector_type(16)));
typedef float    f32x4   __attribute__((ext_vector_type(4)));

struct H2x4 { half2_t h[4]; };

// pack 8 consecutive fp32 (two float4) into an f16x8 fragment (RTZ)
__device__ inline f16x8 pack8(float4 a, float4 b) {
    H2x4 t;
    t.h[0] = __builtin_bit_cast(half2_t, __builtin_amdgcn_cvt_pkrtz(a.x, a.y));
    t.h[1] = __builtin_bit_cast(half2_t, __builtin_amdgcn_cvt_pkrtz(a.z, a.w));
    t.h[2] = __builtin_bit_cast(half2_t, __builtin_amdgcn_cvt_pkrtz(b.x, b.y));
    t.h[3] = __builtin_bit_cast(half2_t, __builtin_amdgcn_cvt_pkrtz(b.z, b.w));
    return __builtin_bit_cast(f16x8, t);
}

// scalar fp32 -> fp16 with RTZ (matches pack8 rounding)
__device__ inline _Float16 h_rtz(float v) {
    half2_t p = __builtin_bit_cast(half2_t, __builtin_amdgcn_cvt_pkrtz(v, v));
    return p[0];
}

__device__ inline int iclamp256(int v) { return v < 0 ? 0 : (v > 256 ? 256 : v); }

// ---------------------------------------------------------------------------
// K0: fused prep — x pack, W_qkv pack, emb pack (scaled), tree projections.
// grid 6826 x 256.
// ---------------------------------------------------------------------------
__global__ __launch_bounds__(256) void prep_pack(
    const float* __restrict__ x, const float* __restrict__ Wq,
    const float* __restrict__ emb, const float* __restrict__ te,
    const float* __restrict__ Wtk, const float* __restrict__ Wtv,
    _Float16* __restrict__ xh, _Float16* __restrict__ Wqh,
    _Float16* __restrict__ embh, float* __restrict__ tk, float* __restrict__ tv)
{
    int bid = blockIdx.x;
    int t   = threadIdx.x;
    if (bid < 6400) {
        int i = (bid * 256 + t) * 8;                 // 6400*256*8 = 13107200 exact
        const float4* s = (const float4*)(x + i);
        *(uint4*)(xh + i) = __builtin_bit_cast(uint4, pack8(s[0], s[1]));
    } else if (bid < 6424) {
        int i = ((bid - 6400) * 256 + t) * 8;        // 24*256*8 = 49152 exact
        const float4* s = (const float4*)(Wq + i);
        *(uint4*)(Wqh + i) = __builtin_bit_cast(uint4, pack8(s[0], s[1]));
    } else if (bid < 6426) {
        int r = (bid - 6424) * 256 + t;
        if (r > 256) return;
        const float4* er = (const float4*)(emb + r * 16);
        float4 e0 = er[0], e1 = er[1], e2 = er[2], e3 = er[3];
        e0.x *= S_SCALE; e0.y *= S_SCALE; e0.z *= S_SCALE; e0.w *= S_SCALE;
        e1.x *= S_SCALE; e1.y *= S_SCALE; e1.z *= S_SCALE; e1.w *= S_SCALE;
        e2.x *= S_SCALE; e2.y *= S_SCALE; e2.z *= S_SCALE; e2.w *= S_SCALE;
        e3.x *= S_SCALE; e3.y *= S_SCALE; e3.z *= S_SCALE; e3.w *= S_SCALE;
        *(uint4*)(embh + r * 16)     = __builtin_bit_cast(uint4, pack8(e0, e1));
        *(uint4*)(embh + r * 16 + 8) = __builtin_bit_cast(uint4, pack8(e2, e3));
    } else {
        int n = bid - 6426;                          // 400 blocks
        const float* W = (t < 128) ? Wtk : Wtv;
        float* outp    = (t < 128) ? tk : tv;
        int j = t & 127;
        float acc = 0.f;
        #pragma unroll 4
        for (int c = 0; c < 128; ++c)
            acc += te[n * 128 + c] * W[c * 128 + j];
        outp[n * 128 + j] = acc;
    }
}

// ---------------------------------------------------------------------------
// K1: qkv GEMM via fp16 MFMA; inputs pre-packed fp16 (direct f16x8 loads).
// q/k stores scaled by S_SCALE (softmax scale folded). Natural (r,c) fp16
// full-line stores; V transposed by v_pack.
// ---------------------------------------------------------------------------
__global__ __launch_bounds__(256) void qkv_gemm(
    const _Float16* __restrict__ xh, const _Float16* __restrict__ Wqh,
    const float* __restrict__ tk, const float* __restrict__ tv,
    _Float16* __restrict__ qn, _Float16* __restrict__ kn, _Float16* __restrict__ vn)
{
    int tid  = threadIdx.x;
    int wave = tid >> 6, lane = tid & 63;
    int m32  = lane & 31, khalf = lane >> 5;
    int row0 = blockIdx.y * 64 + (wave & 1) * 32;
    int col0 = blockIdx.x * 64 + (wave >> 1) * 32;

    const _Float16* xp = xh  + (row0 + m32) * 128 + khalf * 8;
    const _Float16* wp = Wqh + (col0 + m32) * 128 + khalf * 8;

    f32x16 acc;
    #pragma unroll
    for (int i = 0; i < 16; ++i) acc[i] = 0.f;

    #pragma unroll
    for (int k0 = 0; k0 < 128; k0 += 16) {
        f16x8 xa = __builtin_bit_cast(f16x8, *(const uint4*)(xp + k0));
        f16x8 wa = __builtin_bit_cast(f16x8, *(const uint4*)(wp + k0));
        acc = __builtin_amdgcn_mfma_f32_32x32x16_f16(xa, wa, acc, 0, 0, 0);
    }

    int o   = col0 + m32;
    int sec = o >> 7;
    int rem = o & 127;
    #pragma unroll
    for (int reg = 0; reg < 16; ++reg) {
        int r = row0 + (reg & 3) + 8 * (reg >> 2) + 4 * khalf;  // r = f*400+n
        float val = acc[reg];
        if (sec == 0) {
            qn[r * 128 + rem] = h_rtz(val * S_SCALE);
        } else {
            int f = r / 400;
            int n = r - f * 400;
            if (sec == 1) {
                kn[r * 128 + rem] = h_rtz((val + tk[n * 128 + rem]) * S_SCALE);
            } else {
                vn[r * 128 + rem] = (_Float16)(val + tv[n * 128 + rem]);  // RTN, unscaled
            }
        }
    }
}

// ---------------------------------------------------------------------------
// K1b: V transpose per (n,h): natural (f, e) -> vT (n,h,e,f).
// ---------------------------------------------------------------------------
__global__ __launch_bounds__(256) void v_pack(
    const _Float16* __restrict__ vn, _Float16* __restrict__ vT)
{
    __shared__ _Float16 sm[16 * 264];
    int bn = blockIdx.x;             // n*8 + h
    int n  = bn >> 3, h = bn & 7;
    int t  = threadIdx.x;            // f = t

    const uint4* src = (const uint4*)(vn + (t * 400 + n) * 128 + h * 16);
    uint4 a = src[0], b = src[1];
    union { uint4 u; _Float16 hv[8]; } ua, ub;
    ua.u = a; ub.u = b;
    #pragma unroll
    for (int e = 0; e < 8; ++e) sm[e * 264 + t]       = ua.hv[e];
    #pragma unroll
    for (int e = 0; e < 8; ++e) sm[(e + 8) * 264 + t] = ub.hv[e];
    __syncthreads();

    #pragma unroll
    for (int k = 0; k < 2; ++k) {
        int idx = (k * 256 + t) * 8;         // halves into (e,f) plane
        int e = idx >> 8, f0 = idx & 255;
        uint4 o = *(const uint4*)(sm + e * 264 + f0);
        *(uint4*)(vT + bn * 4096 + idx) = o;
    }
}

// ---------------------------------------------------------------------------
// K2: MFMA flash attention per (n,h). 4 waves; wave w owns l in [64w,64w+64).
// r15: denominator via ones-MFMA (layout-aligned with O; no divergent denom
// block, no epilogue bpermutes). R2_STRIDE 258, exp2f w/ pre-folded scale,
// XCD-swizzled bn. LDS 27136.
// ---------------------------------------------------------------------------
#define R2_STRIDE 258   // halves per R2 row; dword stride 129 (odd) = conflict-free
#define PS_STRIDE 40    // halves per P row (80B, b128-aligned, odd-dword)

__global__ __launch_bounds__(256, 4) void attn_kernel(
    const _Float16* __restrict__ qb, const _Float16* __restrict__ kb,
    const _Float16* __restrict__ vb, const _Float16* __restrict__ embh,
    _Float16* __restrict__ y)
{
    __shared__ __align__(16) _Float16 R2sh[32 * R2_STRIDE];   // 16.5 KB
    __shared__ __align__(16) _Float16 Psh[4 * 32 * PS_STRIDE];// 10.2 KB

    int tid  = threadIdx.x;
    int wave = tid >> 6, lane = tid & 63;
    int bid  = blockIdx.x;
    // XCD swizzle: consecutive bn (which share q/k cache lines) -> same XCD.
    int bn   = (bid & 7) * 400 + (bid >> 3);   // 3200 % 8 == 0: bijective
    int n    = bn >> 3, h = bn & 7;
    int base = bn * 4096;             // halves (vT only)

    int nn  = lane & 31;            // score col / s-local / frag m-or-n index
    int kh  = lane >> 5;            // wave half (frag k split for 32-shapes)
    int khb = (lane & 32) << 2;     // bpermute addr offset into own half
    int cbase = 31 + 4 * kh - nn;   // window col base per lane
    int dbase = 4 * kh - nn;        // d offset per lane
    int q16 = (lane >> 4) & 3;      // quad for 16x16 shapes

    // natural-layout fragment offset for this (n,h,kh)
    int nat_off = n * 128 + h * 16 + kh * 8;

    // Q fragments for this wave's two l-tiles (direct 16B loads from global)
    f16x8 aq[2];
    #pragma unroll
    for (int lt = 0; lt < 2; ++lt)
        aq[lt] = __builtin_bit_cast(f16x8,
            *(const uint4*)(qb + (64 * wave + 32 * lt + nn) * 51200 + nat_off));

    // ones fragment for rowsum-MFMA (denominator)
    f16x8 bones;
    #pragma unroll
    for (int i = 0; i < 8; ++i) bones[i] = (_Float16)1.0f;

    f32x4 O[2][2];     // PV accumulators
    f32x4 Od[2][2];    // denominator accumulators (rowsum of P)
    #pragma unroll
    for (int i = 0; i < 2; ++i)
        #pragma unroll
        for (int j = 0; j < 2; ++j)
            #pragma unroll
            for (int r = 0; r < 4; ++r) { O[i][j][r] = 0.f; Od[i][j][r] = 0.f; }

    _Float16* psw = Psh + wave * 32 * PS_STRIDE;

    for (int st = 0; st < 8; ++st) {
        // K-tile fragment (A for R2, B for QK): row f = 32*st + nn
        f16x8 bk = __builtin_bit_cast(f16x8,
            *(const uint4*)(kb + (32 * st + nn) * 51200 + nat_off));

        // ---- shared R2 table: R2[s_local][d] = K[32st+s_local] . emb[d] ----
        for (int ct = wave; ct < 9; ct += 4) {
            int erow = 32 * ct + nn; if (erow > 256) erow = 256;
            f16x8 be = __builtin_bit_cast(f16x8,
                *(const uint4*)(embh + erow * 16 + kh * 8));
            f32x16 c2;
            #pragma unroll
            for (int i = 0; i < 16; ++i) c2[i] = 0.f;
            c2 = __builtin_amdgcn_mfma_f32_32x32x16_f16(bk, be, c2, 0, 0, 0);
            int col = 32 * ct + nn;
            if (col <= 257) {
                #pragma unroll
                for (int r = 0; r < 16; ++r) {
                    int srow = (r & 3) + 8 * (r >> 2) + 4 * kh;
                    R2sh[srow * R2_STRIDE + col] = (_Float16)c2[r];
                }
            }
        }
        __syncthreads();   // R2 ready for all waves

        // PV B-fragment: V^T[e = lane&15][k = s-local = q16*8+j], direct global
        f16x8 bv = __builtin_bit_cast(f16x8,
            *(const uint4*)(vb + base + (lane & 15) * 256 + 32 * st + q16 * 8));

        #pragma unroll
        for (int lt = 0; lt < 2; ++lt) {
            int U0 = 64 * wave + 32 * lt - 32 * st + 128;

            // scores
            f32x16 S;
            #pragma unroll
            for (int i = 0; i < 16; ++i) S[i] = 0.f;
            S = __builtin_amdgcn_mfma_f32_32x32x16_f16(aq[lt], bk, S, 0, 0, 0);

            // bias1 windows: W[m][c] = Q[l0+m] . emb[clamp(U0-31+c)]
            int br0 = iclamp256(U0 - 31 + nn);
            int br1 = iclamp256(U0 + 1 + nn);
            f16x8 be0 = __builtin_bit_cast(f16x8,
                *(const uint4*)(embh + br0 * 16 + kh * 8));
            f16x8 be1 = __builtin_bit_cast(f16x8,
                *(const uint4*)(embh + br1 * 16 + kh * 8));
            f32x16 W0, W1;
            #pragma unroll
            for (int i = 0; i < 16; ++i) { W0[i] = 0.f; W1[i] = 0.f; }
            W0 = __builtin_amdgcn_mfma_f32_32x32x16_f16(aq[lt], be0, W0, 0, 0, 0);
            W1 = __builtin_amdgcn_mfma_f32_32x32x16_f16(aq[lt], be1, W1, 0, 0, 0);

            #pragma unroll
            for (int r = 0; r < 16; ++r) {
                int rmr = (r & 3) + 8 * (r >> 2);
                int c   = rmr + cbase;                 // [0,62]
                int addr = ((c & 31) << 2) + khb;
                // pack (W0[r], W1[r]) as fp16 pair -> ONE bpermute, select half
                int w01 = __builtin_bit_cast(int,
                    __builtin_amdgcn_cvt_pkrtz(W0[r], W1[r]));
                half2_t hh = __builtin_bit_cast(half2_t,
                    __builtin_amdgcn_ds_bpermute(addr, w01));
                float b1 = (float)((c < 32) ? hh[0] : hh[1]);
                int d = iclamp256(U0 + rmr + dbase);
                float b2 = (float)R2sh[nn * R2_STRIDE + d];
                float p = exp2f(S[r] + b1 + b2);   // scale pre-folded into q/k/emb
                int mloc = rmr + 4 * kh;
                psw[mloc * PS_STRIDE + nn] = (_Float16)p;
            }

            // PV + denom: 2 sub-tiles of 16 l-rows each, K = 32 (this s-tile)
            #pragma unroll
            for (int a = 0; a < 2; ++a) {
                f16x8 ap = __builtin_bit_cast(f16x8,
                    *(const uint4*)(psw + (16 * a + (lane & 15)) * PS_STRIDE + q16 * 8));
                O[lt][a]  = __builtin_amdgcn_mfma_f32_16x16x32_f16(ap, bv,    O[lt][a],  0, 0, 0);
                Od[lt][a] = __builtin_amdgcn_mfma_f32_16x16x32_f16(ap, bones, Od[lt][a], 0, 0, 0);
            }
        }
        __syncthreads();   // all reads of R2sh done before next st overwrites
    }

    // ---- epilogue: normalize + write (fp16 y); denom layout == O layout ----
    #pragma unroll
    for (int lt = 0; lt < 2; ++lt) {
        #pragma unroll
        for (int a = 0; a < 2; ++a) {
            #pragma unroll
            for (int r = 0; r < 4; ++r) {
                int row  = q16 * 4 + r;
                int lloc = 32 * lt + 16 * a + row;
                int lg = 64 * wave + lloc;
                y[(lg * 400 + n) * 128 + h * 16 + (lane & 15)] =
                    (_Float16)(O[lt][a][r] / Od[lt][a][r]);
            }
        }
    }
}

// ---------------------------------------------------------------------------
// K3: gate+LN1 (y fp16)
// ---------------------------------------------------------------------------
__global__ __launch_bounds__(256) void gate_ln1(
    const float* __restrict__ x, const _Float16* __restrict__ yh,
    const float* __restrict__ Wb, const float* __restrict__ g,
    const float* __restrict__ b, float* __restrict__ h1)
{
    int tid  = threadIdx.x;
    int r    = blockIdx.x * 4 + (tid >> 6);
    int lane = tid & 63;
    int c    = lane * 2;

    float2 xv = *(const float2*)(x + r * 128 + c);
    half2_t yv2 = *(const half2_t*)(yh + r * 128 + c);
    float yvx = (float)yv2[0], yvy = (float)yv2[1];
    float2 w0 = *(const float2*)(Wb + c);
    float2 w1 = *(const float2*)(Wb + 128 + c);
    float2 w2 = *(const float2*)(Wb + 256 + c);

    float sv = yvx * w0.x + yvy * w0.y
             + xv.x * w1.x + xv.y * w1.y
             + (yvx - xv.x) * w2.x + (yvy - xv.y) * w2.y;
    #pragma unroll
    for (int off = 32; off > 0; off >>= 1) sv += __shfl_xor(sv, off);
    float gate = 1.0f / (1.0f + __expf(-sv));

    float z0 = gate * xv.x + (1.0f - gate) * yvx;
    float z1 = gate * xv.y + (1.0f - gate) * yvy;
    float s1 = z0 + z1, s2 = z0 * z0 + z1 * z1;
    #pragma unroll
    for (int off = 32; off > 0; off >>= 1) {
        s1 += __shfl_xor(s1, off);
        s2 += __shfl_xor(s2, off);
    }
    float mu  = s1 * (1.0f / 128.0f);
    float var = s2 * (1.0f / 128.0f) - mu * mu;
    float rs  = rsqrtf(var + 1e-5f);

    float2 gv = *(const float2*)(g + c);
    float2 bv = *(const float2*)(b + c);
    float2 ov;
    ov.x = (z0 - mu) * rs * gv.x + bv.x;
    ov.y = (z1 - mu) * rs * gv.y + bv.y;
    *(float2*)(h1 + r * 128 + c) = ov;
}

// ---------------------------------------------------------------------------
// K4: ff1 fp16 MFMA + exact GELU; output stored fp16
// ---------------------------------------------------------------------------
__global__ __launch_bounds__(256) void ff1_gemm(
    const float* __restrict__ A, const float* __restrict__ W,
    const float* __restrict__ bias, _Float16* __restrict__ outp)
{
    int tid  = threadIdx.x;
    int wave = tid >> 6, lane = tid & 63;
    int m32  = lane & 31, khalf = lane >> 5;
    int row0 = blockIdx.y * 64 + (wave & 1) * 32;
    int col0 = blockIdx.x * 64 + (wave >> 1) * 32;

    const float* ap = A + (row0 + m32) * 128 + khalf * 8;
    const float* wp = W + (col0 + m32) * 128 + khalf * 8;

    f32x16 acc;
    #pragma unroll
    for (int i = 0; i < 16; ++i) acc[i] = 0.f;

    #pragma unroll
    for (int k0 = 0; k0 < 128; k0 += 16) {
        float4 aa = *(const float4*)(ap + k0);
        float4 ab = *(const float4*)(ap + k0 + 4);
        float4 wa = *(const float4*)(wp + k0);
        float4 wb = *(const float4*)(wp + k0 + 4);
        acc = __builtin_amdgcn_mfma_f32_32x32x16_f16(pack8(aa, ab), pack8(wa, wb), acc, 0, 0, 0);
    }

    int   c  = col0 + m32;
    float bi = bias[c];
    #pragma unroll
    for (int reg = 0; reg < 16; ++reg) {
        int r = row0 + (reg & 3) + 8 * (reg >> 2) + 4 * khalf;
        float v = acc[reg] + bi;
        v = 0.5f * v * (1.0f + erff(v * 0.70710678118654752f));  // exact GELU
        outp[r * 128 + c] = (_Float16)v;
    }
}

// ---------------------------------------------------------------------------
// K5: ff2 + LN2 fp16 MFMA (A arrives fp16 -> direct f16x8 fragment loads)
// ---------------------------------------------------------------------------
__global__ __launch_bounds__(256) void ff2_ln2(
    const _Float16* __restrict__ A, const float* __restrict__ W2,
    const float* __restrict__ b2, const float* __restrict__ h1,
    const float* __restrict__ g, const float* __restrict__ bb,
    float* __restrict__ outp)
{
    __shared__ float Cs[32 * 132];
    int tid  = threadIdx.x;
    int wave = tid >> 6, lane = tid & 63;
    int m32  = lane & 31, khalf = lane >> 5;
    int row0 = blockIdx.x * 32;
    int col0 = wave * 32;

    const _Float16* ap = A  + (row0 + m32) * 128 + khalf * 8;
    const float*    wp = W2 + (col0 + m32) * 128 + khalf * 8;

    f32x16 acc;
    #pragma unroll
    for (int i = 0; i < 16; ++i) acc[i] = 0.f;

    #pragma unroll
    for (int k0 = 0; k0 < 128; k0 += 16) {
        f16x8 aa16 = __builtin_bit_cast(f16x8, *(const uint4*)(ap + k0));
        float4 wa = *(const float4*)(wp + k0);
        float4 wb = *(const float4*)(wp + k0 + 4);
        acc = __builtin_amdgcn_mfma_f32_32x32x16_f16(aa16, pack8(wa, wb), acc, 0, 0, 0);
    }

    #pragma unroll
    for (int reg = 0; reg < 16; ++reg) {
        int rloc = (reg & 3) + 8 * (reg >> 2) + 4 * khalf;
        Cs[rloc * 132 + col0 + m32] = acc[reg];
    }
    __syncthreads();

    int rloc = tid >> 3, seg = (tid & 7) * 16;
    int r = row0 + rloc;
    float z[16];
    float s1 = 0.f, s2 = 0.f;
    #pragma unroll
    for (int j4 = 0; j4 < 4; ++j4) {
        float4 cv = *(const float4*)(Cs + rloc * 132 + seg + j4 * 4);
        float4 hv = *(const float4*)(h1 + r * 128 + seg + j4 * 4);
        float4 bv = *(const float4*)(b2 + seg + j4 * 4);
        z[j4*4+0] = cv.x + bv.x + hv.x;
        z[j4*4+1] = cv.y + bv.y + hv.y;
        z[j4*4+2] = cv.z + bv.z + hv.z;
        z[j4*4+3] = cv.w + bv.w + hv.w;
        s1 += z[j4*4+0] + z[j4*4+1] + z[j4*4+2] + z[j4*4+3];
        s2 += z[j4*4+0]*z[j4*4+0] + z[j4*4+1]*z[j4*4+1]
            + z[j4*4+2]*z[j4*4+2] + z[j4*4+3]*z[j4*4+3];
    }
    #pragma unroll
    for (int off = 4; off > 0; off >>= 1) {
        s1 += __shfl_xor(s1, off);
        s2 += __shfl_xor(s2, off);
    }
    float mu  = s1 * (1.0f / 128.0f);
    float var = s2 * (1.0f / 128.0f) - mu * mu;
    float rs  = rsqrtf(var + 1e-5f);
    #pragma unroll
    for (int j4 = 0; j4 < 4; ++j4) {
        float4 gv = *(const float4*)(g  + seg + j4 * 4);
        float4 bv = *(const float4*)(bb + seg + j4 * 4);
        float4 ov;
        ov.x = (z[j4*4+0] - mu) * rs * gv.x + bv.x;
        ov.y = (z[j4*4+1] - mu) * rs * gv.y + bv.y;
        ov.z = (z[j4*4+2] - mu) * rs * gv.z + bv.z;
        ov.w = (z[j4*4+3] - mu) * rs * gv.w + bv.w;
        *(float4*)(outp + r * 128 + seg + j4 * 4) = ov;
    }
}

// ---------------------------------------------------------------------------
extern "C" void kernel_launch(void* const* d_in, const int* in_sizes, int n_in,
                              void* d_out, int out_size, void* d_ws, size_t ws_size,
                              hipStream_t stream)
{
    const float* x     = (const float*)d_in[0];
    const float* te    = (const float*)d_in[1];
    const float* Wqkv  = (const float*)d_in[2];
    const float* Wtk   = (const float*)d_in[3];
    const float* Wtv   = (const float*)d_in[4];
    const float* emb   = (const float*)d_in[5];
    const float* Wbeta = (const float*)d_in[6];
    const float* ln1g  = (const float*)d_in[7];
    const float* ln1b  = (const float*)d_in[8];
    const float* ln2g  = (const float*)d_in[9];
    const float* ln2b  = (const float*)d_in[10];
    const float* W1    = (const float*)d_in[11];
    const float* b1    = (const float*)d_in[12];
    const float* W2    = (const float*)d_in[13];
    const float* b2    = (const float*)d_in[14];
    float* outp = (float*)d_out;

    float* ws = (float*)d_ws;
    float* tk = ws;                        // 51200
    float* tv = ws + 51200;                // 51200
    float* qb_region = ws + 102400;        // SBUF floats
    float* kb_region = qb_region + SBUF;   // SBUF floats
    float* vb_region = kb_region + SBUF;   // SBUF floats
    float* yb        = vb_region + SBUF;   // SBUF floats

    _Float16* qnat = (_Float16*)qb_region;                   // natural (r,c) fp16
    _Float16* knat = (_Float16*)kb_region;                   // natural (r,c) fp16
    _Float16* vnat = (_Float16*)vb_region;                   // natural (r,c) fp16
    _Float16* vT   = (_Float16*)(vb_region + SBUF / 2);      // (n,h,e,f) fp16
    _Float16* embh = (_Float16*)(qb_region + SBUF / 2);      // spare half of q region
    _Float16* yh   = (_Float16*)yb;                          // y fp16 (f,n,c), lower half
    _Float16* xh   = (_Float16*)(kb_region + SBUF / 2);      // x fp16 (dead when h1 written)
    _Float16* Wqh  = (_Float16*)(yb + SBUF / 2);             // W_qkv fp16 (yb upper, free)

    float*    h1   = kb_region;            // reuse: k+xh dead after attention
    _Float16* ff1h = (_Float16*)qb_region; // reuse: q+embh dead after attention

    prep_pack<<<6826, 256, 0, stream>>>(x, Wqkv, emb, te, Wtk, Wtv,
                                        xh, Wqh, embh, tk, tv);
    qkv_gemm<<<dim3(6, 1600), 256, 0, stream>>>(xh, Wqh, tk, tv, qnat, knat, vnat);
    v_pack<<<3200, 256, 0, stream>>>(vnat, vT);
    attn_kernel<<<3200, 256, 0, stream>>>(qnat, knat, vT, embh, yh);
    gate_ln1<<<ROWS / 4, 256, 0, stream>>>(x, yh, Wbeta, ln1g, ln1b, h1);
    ff1_gemm<<<dim3(2, 1600), 256, 0, stream>>>(h1, W1, b1, ff1h);
    ff2_ln2<<<3200, 256, 0, stream>>>(ff1h, W2, b2, h1, ln2g, ln2b, outp);
}

// Round 9
// 525.848 us; speedup vs baseline: 1.8702x; 1.0104x over previous
//
#include <hip/hip_runtime.h>
#include <math.h>

// Problem constants
#define F_DIM 256
#define N_DIM 400
#define C_DIM 128
#define H_DIM 8
#define E_DIM 16
#define ROWS  (F_DIM * N_DIM)          // 102400
#define SBUF  (N_DIM * H_DIM * F_DIM * E_DIM)  // 13107200 floats per q/k/v region

// r16: r15 verified 531us (attn 180.5, VALUBusy 74%, occ pinned ~39%).
// Occupancy diagnosis: combined VGPR+AGPR ~160/thread (S+W0+W1 = 48 f32
// live + accums) -> 12 waves/CU, matching measured 12.5. Conflicts were
// bit-identical 6.9248M across r13-r15 -> NOT the denom read; not the lever.
// This round:
//  (1) attn -> 8 waves x 32 rows (512 thr): per-thread state halves
//      (aq/O/Od), no lt loop; R2 build amortized over 8 waves.
//  (2) bpermutes hoisted right after W MFMAs -> W0/W1 (32 regs) collapse
//      into 8 packed fp16 regs before the element loop.
//  (3) exp2 via __builtin_amdgcn_exp2f (raw v_exp_f32).
//  LDS 16.5K(R2) + 20.5K(Psh) = 37K -> 4 blk/CU x 8 waves = 32 waves/CU cap.
#define S_SCALE 0.6005612043932249f

typedef _Float16 half2_t __attribute__((ext_vector_type(2)));
typedef _Float16 f16x8   __attribute__((ext_vector_type(8)));
typedef float    f32x16  __attribute__((ext_vector_type(16)));
typedef float    f32x4   __attribute__((ext_vector_type(4)));

struct H2x4 { half2_t h[4]; };

// pack 8 consecutive fp32 (two float4) into an f16x8 fragment (RTZ)
__device__ inline f16x8 pack8(float4 a, float4 b) {
    H2x4 t;
    t.h[0] = __builtin_bit_cast(half2_t, __builtin_amdgcn_cvt_pkrtz(a.x, a.y));
    t.h[1] = __builtin_bit_cast(half2_t, __builtin_amdgcn_cvt_pkrtz(a.z, a.w));
    t.h[2] = __builtin_bit_cast(half2_t, __builtin_amdgcn_cvt_pkrtz(b.x, b.y));
    t.h[3] = __builtin_bit_cast(half2_t, __builtin_amdgcn_cvt_pkrtz(b.z, b.w));
    return __builtin_bit_cast(f16x8, t);
}

// scalar fp32 -> fp16 with RTZ (matches pack8 rounding)
__device__ inline _Float16 h_rtz(float v) {
    half2_t p = __builtin_bit_cast(half2_t, __builtin_amdgcn_cvt_pkrtz(v, v));
    return p[0];
}

__device__ inline int iclamp256(int v) { return v < 0 ? 0 : (v > 256 ? 256 : v); }

// ---------------------------------------------------------------------------
// K0: fused prep — x pack, W_qkv pack, emb pack (scaled), tree projections.
// grid 6826 x 256.
// ---------------------------------------------------------------------------
__global__ __launch_bounds__(256) void prep_pack(
    const float* __restrict__ x, const float* __restrict__ Wq,
    const float* __restrict__ emb, const float* __restrict__ te,
    const float* __restrict__ Wtk, const float* __restrict__ Wtv,
    _Float16* __restrict__ xh, _Float16* __restrict__ Wqh,
    _Float16* __restrict__ embh, float* __restrict__ tk, float* __restrict__ tv)
{
    int bid = blockIdx.x;
    int t   = threadIdx.x;
    if (bid < 6400) {
        int i = (bid * 256 + t) * 8;                 // 6400*256*8 = 13107200 exact
        const float4* s = (const float4*)(x + i);
        *(uint4*)(xh + i) = __builtin_bit_cast(uint4, pack8(s[0], s[1]));
    } else if (bid < 6424) {
        int i = ((bid - 6400) * 256 + t) * 8;        // 24*256*8 = 49152 exact
        const float4* s = (const float4*)(Wq + i);
        *(uint4*)(Wqh + i) = __builtin_bit_cast(uint4, pack8(s[0], s[1]));
    } else if (bid < 6426) {
        int r = (bid - 6424) * 256 + t;
        if (r > 256) return;
        const float4* er = (const float4*)(emb + r * 16);
        float4 e0 = er[0], e1 = er[1], e2 = er[2], e3 = er[3];
        e0.x *= S_SCALE; e0.y *= S_SCALE; e0.z *= S_SCALE; e0.w *= S_SCALE;
        e1.x *= S_SCALE; e1.y *= S_SCALE; e1.z *= S_SCALE; e1.w *= S_SCALE;
        e2.x *= S_SCALE; e2.y *= S_SCALE; e2.z *= S_SCALE; e2.w *= S_SCALE;
        e3.x *= S_SCALE; e3.y *= S_SCALE; e3.z *= S_SCALE; e3.w *= S_SCALE;
        *(uint4*)(embh + r * 16)     = __builtin_bit_cast(uint4, pack8(e0, e1));
        *(uint4*)(embh + r * 16 + 8) = __builtin_bit_cast(uint4, pack8(e2, e3));
    } else {
        int n = bid - 6426;                          // 400 blocks
        const float* W = (t < 128) ? Wtk : Wtv;
        float* outp    = (t < 128) ? tk : tv;
        int j = t & 127;
        float acc = 0.f;
        #pragma unroll 4
        for (int c = 0; c < 128; ++c)
            acc += te[n * 128 + c] * W[c * 128 + j];
        outp[n * 128 + j] = acc;
    }
}

// ---------------------------------------------------------------------------
// K1: qkv GEMM via fp16 MFMA; inputs pre-packed fp16 (direct f16x8 loads).
// q/k stores scaled by S_SCALE (softmax scale folded). Natural (r,c) fp16
// full-line stores; V transposed by v_pack.
// ---------------------------------------------------------------------------
__global__ __launch_bounds__(256) void qkv_gemm(
    const _Float16* __restrict__ xh, const _Float16* __restrict__ Wqh,
    const float* __restrict__ tk, const float* __restrict__ tv,
    _Float16* __restrict__ qn, _Float16* __restrict__ kn, _Float16* __restrict__ vn)
{
    int tid  = threadIdx.x;
    int wave = tid >> 6, lane = tid & 63;
    int m32  = lane & 31, khalf = lane >> 5;
    int row0 = blockIdx.y * 64 + (wave & 1) * 32;
    int col0 = blockIdx.x * 64 + (wave >> 1) * 32;

    const _Float16* xp = xh  + (row0 + m32) * 128 + khalf * 8;
    const _Float16* wp = Wqh + (col0 + m32) * 128 + khalf * 8;

    f32x16 acc;
    #pragma unroll
    for (int i = 0; i < 16; ++i) acc[i] = 0.f;

    #pragma unroll
    for (int k0 = 0; k0 < 128; k0 += 16) {
        f16x8 xa = __builtin_bit_cast(f16x8, *(const uint4*)(xp + k0));
        f16x8 wa = __builtin_bit_cast(f16x8, *(const uint4*)(wp + k0));
        acc = __builtin_amdgcn_mfma_f32_32x32x16_f16(xa, wa, acc, 0, 0, 0);
    }

    int o   = col0 + m32;
    int sec = o >> 7;
    int rem = o & 127;
    #pragma unroll
    for (int reg = 0; reg < 16; ++reg) {
        int r = row0 + (reg & 3) + 8 * (reg >> 2) + 4 * khalf;  // r = f*400+n
        float val = acc[reg];
        if (sec == 0) {
            qn[r * 128 + rem] = h_rtz(val * S_SCALE);
        } else {
            int f = r / 400;
            int n = r - f * 400;
            if (sec == 1) {
                kn[r * 128 + rem] = h_rtz((val + tk[n * 128 + rem]) * S_SCALE);
            } else {
                vn[r * 128 + rem] = (_Float16)(val + tv[n * 128 + rem]);  // RTN, unscaled
            }
        }
    }
}

// ---------------------------------------------------------------------------
// K1b: V transpose per (n,h): natural (f, e) -> vT (n,h,e,f).
// ---------------------------------------------------------------------------
__global__ __launch_bounds__(256) void v_pack(
    const _Float16* __restrict__ vn, _Float16* __restrict__ vT)
{
    __shared__ _Float16 sm[16 * 264];
    int bn = blockIdx.x;             // n*8 + h
    int n  = bn >> 3, h = bn & 7;
    int t  = threadIdx.x;            // f = t

    const uint4* src = (const uint4*)(vn + (t * 400 + n) * 128 + h * 16);
    uint4 a = src[0], b = src[1];
    union { uint4 u; _Float16 hv[8]; } ua, ub;
    ua.u = a; ub.u = b;
    #pragma unroll
    for (int e = 0; e < 8; ++e) sm[e * 264 + t]       = ua.hv[e];
    #pragma unroll
    for (int e = 0; e < 8; ++e) sm[(e + 8) * 264 + t] = ub.hv[e];
    __syncthreads();

    #pragma unroll
    for (int k = 0; k < 2; ++k) {
        int idx = (k * 256 + t) * 8;         // halves into (e,f) plane
        int e = idx >> 8, f0 = idx & 255;
        uint4 o = *(const uint4*)(sm + e * 264 + f0);
        *(uint4*)(vT + bn * 4096 + idx) = o;
    }
}

// ---------------------------------------------------------------------------
// K2: MFMA flash attention per (n,h). r16: 8 waves x 512 threads; wave w
// owns l in [32w, 32w+32). Denominator via ones-MFMA. bpermutes hoisted
// (W0/W1 freed before element loop). R2_STRIDE 258, exp2 raw, XCD swizzle.
// LDS 36992B -> 4 blocks/CU (32 waves).
// ---------------------------------------------------------------------------
#define R2_STRIDE 258   // halves per R2 row; dword stride 129 (odd) = conflict-free
#define PS_STRIDE 40    // halves per P row (80B, b128-aligned, odd-dword)

__global__ __launch_bounds__(512, 4) void attn_kernel(
    const _Float16* __restrict__ qb, const _Float16* __restrict__ kb,
    const _Float16* __restrict__ vb, const _Float16* __restrict__ embh,
    _Float16* __restrict__ y)
{
    __shared__ __align__(16) _Float16 R2sh[32 * R2_STRIDE];   // 16.5 KB
    __shared__ __align__(16) _Float16 Psh[8 * 32 * PS_STRIDE];// 20.5 KB

    int tid  = threadIdx.x;
    int wave = tid >> 6, lane = tid & 63;
    int bid  = blockIdx.x;
    // XCD swizzle: consecutive bn (which share q/k cache lines) -> same XCD.
    int bn   = (bid & 7) * 400 + (bid >> 3);   // 3200 % 8 == 0: bijective
    int n    = bn >> 3, h = bn & 7;
    int base = bn * 4096;             // halves (vT only)

    int nn  = lane & 31;            // score col / s-local / frag m-or-n index
    int kh  = lane >> 5;            // wave half (frag k split for 32-shapes)
    int khb = (lane & 32) << 2;     // bpermute addr offset into own half
    int cbase = 31 + 4 * kh - nn;   // window col base per lane
    int dbase = 4 * kh - nn;        // d offset per lane
    int q16 = (lane >> 4) & 3;      // quad for 16x16 shapes

    // natural-layout fragment offset for this (n,h,kh)
    int nat_off = n * 128 + h * 16 + kh * 8;

    // Q fragment for this wave's l-tile (direct 16B load from global)
    f16x8 aq = __builtin_bit_cast(f16x8,
        *(const uint4*)(qb + (32 * wave + nn) * 51200 + nat_off));

    // ones fragment for rowsum-MFMA (denominator)
    f16x8 bones;
    #pragma unroll
    for (int i = 0; i < 8; ++i) bones[i] = (_Float16)1.0f;

    f32x4 O[2];     // PV accumulators (two 16-row sub-tiles)
    f32x4 Od[2];    // denominator accumulators
    #pragma unroll
    for (int a = 0; a < 2; ++a)
        #pragma unroll
        for (int r = 0; r < 4; ++r) { O[a][r] = 0.f; Od[a][r] = 0.f; }

    _Float16* psw = Psh + wave * 32 * PS_STRIDE;

    for (int st = 0; st < 8; ++st) {
        // K-tile fragment (A for R2, B for QK): row f = 32*st + nn
        f16x8 bk = __builtin_bit_cast(f16x8,
            *(const uint4*)(kb + (32 * st + nn) * 51200 + nat_off));

        // ---- shared R2 table: R2[s_local][d] = K[32st+s_local] . emb[d] ----
        for (int ct = wave; ct < 9; ct += 8) {
            int erow = 32 * ct + nn; if (erow > 256) erow = 256;
            f16x8 be = __builtin_bit_cast(f16x8,
                *(const uint4*)(embh + erow * 16 + kh * 8));
            f32x16 c2;
            #pragma unroll
            for (int i = 0; i < 16; ++i) c2[i] = 0.f;
            c2 = __builtin_amdgcn_mfma_f32_32x32x16_f16(bk, be, c2, 0, 0, 0);
            int col = 32 * ct + nn;
            if (col <= 257) {
                #pragma unroll
                for (int r = 0; r < 16; ++r) {
                    int srow = (r & 3) + 8 * (r >> 2) + 4 * kh;
                    R2sh[srow * R2_STRIDE + col] = (_Float16)c2[r];
                }
            }
        }
        __syncthreads();   // R2 ready for all waves

        // PV B-fragment: V^T[e = lane&15][k = s-local = q16*8+j], direct global
        f16x8 bv = __builtin_bit_cast(f16x8,
            *(const uint4*)(vb + base + (lane & 15) * 256 + 32 * st + q16 * 8));

        int U0 = 32 * wave - 32 * st + 128;

        // scores
        f32x16 S;
        #pragma unroll
        for (int i = 0; i < 16; ++i) S[i] = 0.f;
        S = __builtin_amdgcn_mfma_f32_32x32x16_f16(aq, bk, S, 0, 0, 0);

        // bias1 windows: W[m][c] = Q[l0+m] . emb[clamp(U0-31+c)]
        int br0 = iclamp256(U0 - 31 + nn);
        int br1 = iclamp256(U0 + 1 + nn);
        f16x8 be0 = __builtin_bit_cast(f16x8,
            *(const uint4*)(embh + br0 * 16 + kh * 8));
        f16x8 be1 = __builtin_bit_cast(f16x8,
            *(const uint4*)(embh + br1 * 16 + kh * 8));
        f32x16 W0, W1;
        #pragma unroll
        for (int i = 0; i < 16; ++i) { W0[i] = 0.f; W1[i] = 0.f; }
        W0 = __builtin_amdgcn_mfma_f32_32x32x16_f16(aq, be0, W0, 0, 0, 0);
        W1 = __builtin_amdgcn_mfma_f32_32x32x16_f16(aq, be1, W1, 0, 0, 0);

        // hoisted packed bpermutes: b1 per element as fp16, frees W0/W1
        half2_t b1p[8];
        #pragma unroll
        for (int r = 0; r < 16; ++r) {
            int rmr = (r & 3) + 8 * (r >> 2);
            int c   = rmr + cbase;                 // [0,62]
            int addr = ((c & 31) << 2) + khb;
            int w01 = __builtin_bit_cast(int,
                __builtin_amdgcn_cvt_pkrtz(W0[r], W1[r]));
            half2_t hh = __builtin_bit_cast(half2_t,
                __builtin_amdgcn_ds_bpermute(addr, w01));
            b1p[r >> 1][r & 1] = (c < 32) ? hh[0] : hh[1];
        }

        #pragma unroll
        for (int r = 0; r < 16; ++r) {
            int rmr = (r & 3) + 8 * (r >> 2);
            float b1 = (float)b1p[r >> 1][r & 1];
            int d = iclamp256(U0 + rmr + dbase);
            float b2 = (float)R2sh[nn * R2_STRIDE + d];
            float p = __builtin_amdgcn_exp2f(S[r] + b1 + b2);
            int mloc = rmr + 4 * kh;
            psw[mloc * PS_STRIDE + nn] = (_Float16)p;
        }

        // PV + denom: 2 sub-tiles of 16 l-rows each, K = 32 (this s-tile)
        #pragma unroll
        for (int a = 0; a < 2; ++a) {
            f16x8 ap = __builtin_bit_cast(f16x8,
                *(const uint4*)(psw + (16 * a + (lane & 15)) * PS_STRIDE + q16 * 8));
            O[a]  = __builtin_amdgcn_mfma_f32_16x16x32_f16(ap, bv,    O[a],  0, 0, 0);
            Od[a] = __builtin_amdgcn_mfma_f32_16x16x32_f16(ap, bones, Od[a], 0, 0, 0);
        }
        __syncthreads();   // all reads of R2sh done before next st overwrites
    }

    // ---- epilogue: normalize + write (fp16 y); denom layout == O layout ----
    #pragma unroll
    for (int a = 0; a < 2; ++a) {
        #pragma unroll
        for (int r = 0; r < 4; ++r) {
            int row  = q16 * 4 + r;
            int lloc = 16 * a + row;
            int lg = 32 * wave + lloc;
            y[(lg * 400 + n) * 128 + h * 16 + (lane & 15)] =
                (_Float16)(O[a][r] / Od[a][r]);
        }
    }
}

// ---------------------------------------------------------------------------
// K3: gate+LN1 (y fp16)
// ---------------------------------------------------------------------------
__global__ __launch_bounds__(256) void gate_ln1(
    const float* __restrict__ x, const _Float16* __restrict__ yh,
    const float* __restrict__ Wb, const float* __restrict__ g,
    const float* __restrict__ b, float* __restrict__ h1)
{
    int tid  = threadIdx.x;
    int r    = blockIdx.x * 4 + (tid >> 6);
    int lane = tid & 63;
    int c    = lane * 2;

    float2 xv = *(const float2*)(x + r * 128 + c);
    half2_t yv2 = *(const half2_t*)(yh + r * 128 + c);
    float yvx = (float)yv2[0], yvy = (float)yv2[1];
    float2 w0 = *(const float2*)(Wb + c);
    float2 w1 = *(const float2*)(Wb + 128 + c);
    float2 w2 = *(const float2*)(Wb + 256 + c);

    float sv = yvx * w0.x + yvy * w0.y
             + xv.x * w1.x + xv.y * w1.y
             + (yvx - xv.x) * w2.x + (yvy - xv.y) * w2.y;
    #pragma unroll
    for (int off = 32; off > 0; off >>= 1) sv += __shfl_xor(sv, off);
    float gate = 1.0f / (1.0f + __expf(-sv));

    float z0 = gate * xv.x + (1.0f - gate) * yvx;
    float z1 = gate * xv.y + (1.0f - gate) * yvy;
    float s1 = z0 + z1, s2 = z0 * z0 + z1 * z1;
    #pragma unroll
    for (int off = 32; off > 0; off >>= 1) {
        s1 += __shfl_xor(s1, off);
        s2 += __shfl_xor(s2, off);
    }
    float mu  = s1 * (1.0f / 128.0f);
    float var = s2 * (1.0f / 128.0f) - mu * mu;
    float rs  = rsqrtf(var + 1e-5f);

    float2 gv = *(const float2*)(g + c);
    float2 bv = *(const float2*)(b + c);
    float2 ov;
    ov.x = (z0 - mu) * rs * gv.x + bv.x;
    ov.y = (z1 - mu) * rs * gv.y + bv.y;
    *(float2*)(h1 + r * 128 + c) = ov;
}

// ---------------------------------------------------------------------------
// K4: ff1 fp16 MFMA + exact GELU; output stored fp16
// ---------------------------------------------------------------------------
__global__ __launch_bounds__(256) void ff1_gemm(
    const float* __restrict__ A, const float* __restrict__ W,
    const float* __restrict__ bias, _Float16* __restrict__ outp)
{
    int tid  = threadIdx.x;
    int wave = tid >> 6, lane = tid & 63;
    int m32  = lane & 31, khalf = lane >> 5;
    int row0 = blockIdx.y * 64 + (wave & 1) * 32;
    int col0 = blockIdx.x * 64 + (wave >> 1) * 32;

    const float* ap = A + (row0 + m32) * 128 + khalf * 8;
    const float* wp = W + (col0 + m32) * 128 + khalf * 8;

    f32x16 acc;
    #pragma unroll
    for (int i = 0; i < 16; ++i) acc[i] = 0.f;

    #pragma unroll
    for (int k0 = 0; k0 < 128; k0 += 16) {
        float4 aa = *(const float4*)(ap + k0);
        float4 ab = *(const float4*)(ap + k0 + 4);
        float4 wa = *(const float4*)(wp + k0);
        float4 wb = *(const float4*)(wp + k0 + 4);
        acc = __builtin_amdgcn_mfma_f32_32x32x16_f16(pack8(aa, ab), pack8(wa, wb), acc, 0, 0, 0);
    }

    int   c  = col0 + m32;
    float bi = bias[c];
    #pragma unroll
    for (int reg = 0; reg < 16; ++reg) {
        int r = row0 + (reg & 3) + 8 * (reg >> 2) + 4 * khalf;
        float v = acc[reg] + bi;
        v = 0.5f * v * (1.0f + erff(v * 0.70710678118654752f));  // exact GELU
        outp[r * 128 + c] = (_Float16)v;
    }
}

// ---------------------------------------------------------------------------
// K5: ff2 + LN2 fp16 MFMA (A arrives fp16 -> direct f16x8 fragment loads)
// ---------------------------------------------------------------------------
__global__ __launch_bounds__(256) void ff2_ln2(
    const _Float16* __restrict__ A, const float* __restrict__ W2,
    const float* __restrict__ b2, const float* __restrict__ h1,
    const float* __restrict__ g, const float* __restrict__ bb,
    float* __restrict__ outp)
{
    __shared__ float Cs[32 * 132];
    int tid  = threadIdx.x;
    int wave = tid >> 6, lane = tid & 63;
    int m32  = lane & 31, khalf = lane >> 5;
    int row0 = blockIdx.x * 32;
    int col0 = wave * 32;

    const _Float16* ap = A  + (row0 + m32) * 128 + khalf * 8;
    const float*    wp = W2 + (col0 + m32) * 128 + khalf * 8;

    f32x16 acc;
    #pragma unroll
    for (int i = 0; i < 16; ++i) acc[i] = 0.f;

    #pragma unroll
    for (int k0 = 0; k0 < 128; k0 += 16) {
        f16x8 aa16 = __builtin_bit_cast(f16x8, *(const uint4*)(ap + k0));
        float4 wa = *(const float4*)(wp + k0);
        float4 wb = *(const float4*)(wp + k0 + 4);
        acc = __builtin_amdgcn_mfma_f32_32x32x16_f16(aa16, pack8(wa, wb), acc, 0, 0, 0);
    }

    #pragma unroll
    for (int reg = 0; reg < 16; ++reg) {
        int rloc = (reg & 3) + 8 * (reg >> 2) + 4 * khalf;
        Cs[rloc * 132 + col0 + m32] = acc[reg];
    }
    __syncthreads();

    int rloc = tid >> 3, seg = (tid & 7) * 16;
    int r = row0 + rloc;
    float z[16];
    float s1 = 0.f, s2 = 0.f;
    #pragma unroll
    for (int j4 = 0; j4 < 4; ++j4) {
        float4 cv = *(const float4*)(Cs + rloc * 132 + seg + j4 * 4);
        float4 hv = *(const float4*)(h1 + r * 128 + seg + j4 * 4);
        float4 bv = *(const float4*)(b2 + seg + j4 * 4);
        z[j4*4+0] = cv.x + bv.x + hv.x;
        z[j4*4+1] = cv.y + bv.y + hv.y;
        z[j4*4+2] = cv.z + bv.z + hv.z;
        z[j4*4+3] = cv.w + bv.w + hv.w;
        s1 += z[j4*4+0] + z[j4*4+1] + z[j4*4+2] + z[j4*4+3];
        s2 += z[j4*4+0]*z[j4*4+0] + z[j4*4+1]*z[j4*4+1]
            + z[j4*4+2]*z[j4*4+2] + z[j4*4+3]*z[j4*4+3];
    }
    #pragma unroll
    for (int off = 4; off > 0; off >>= 1) {
        s1 += __shfl_xor(s1, off);
        s2 += __shfl_xor(s2, off);
    }
    float mu  = s1 * (1.0f / 128.0f);
    float var = s2 * (1.0f / 128.0f) - mu * mu;
    float rs  = rsqrtf(var + 1e-5f);
    #pragma unroll
    for (int j4 = 0; j4 < 4; ++j4) {
        float4 gv = *(const float4*)(g  + seg + j4 * 4);
        float4 bv = *(const float4*)(bb + seg + j4 * 4);
        float4 ov;
        ov.x = (z[j4*4+0] - mu) * rs * gv.x + bv.x;
        ov.y = (z[j4*4+1] - mu) * rs * gv.y + bv.y;
        ov.z = (z[j4*4+2] - mu) * rs * gv.z + bv.z;
        ov.w = (z[j4*4+3] - mu) * rs * gv.w + bv.w;
        *(float4*)(outp + r * 128 + seg + j4 * 4) = ov;
    }
}

// ---------------------------------------------------------------------------
extern "C" void kernel_launch(void* const* d_in, const int* in_sizes, int n_in,
                              void* d_out, int out_size, void* d_ws, size_t ws_size,
                              hipStream_t stream)
{
    const float* x     = (const float*)d_in[0];
    const float* te    = (const float*)d_in[1];
    const float* Wqkv  = (const float*)d_in[2];
    const float* Wtk   = (const float*)d_in[3];
    const float* Wtv   = (const float*)d_in[4];
    const float* emb   = (const float*)d_in[5];
    const float* Wbeta = (const float*)d_in[6];
    const float* ln1g  = (const float*)d_in[7];
    const float* ln1b  = (const float*)d_in[8];
    const float* ln2g  = (const float*)d_in[9];
    const float* ln2b  = (const float*)d_in[10];
    const float* W1    = (const float*)d_in[11];
    const float* b1    = (const float*)d_in[12];
    const float* W2    = (const float*)d_in[13];
    const float* b2    = (const float*)d_in[14];
    float* outp = (float*)d_out;

    float* ws = (float*)d_ws;
    float* tk = ws;                        // 51200
    float* tv = ws + 51200;                // 51200
    float* qb_region = ws + 102400;        // SBUF floats
    float* kb_region = qb_region + SBUF;   // SBUF floats
    float* vb_region = kb_region + SBUF;   // SBUF floats
    float* yb        = vb_region + SBUF;   // SBUF floats

    _Float16* qnat = (_Float16*)qb_region;                   // natural (r,c) fp16
    _Float16* knat = (_Float16*)kb_region;                   // natural (r,c) fp16
    _Float16* vnat = (_Float16*)vb_region;                   // natural (r,c) fp16
    _Float16* vT   = (_Float16*)(vb_region + SBUF / 2);      // (n,h,e,f) fp16
    _Float16* embh = (_Float16*)(qb_region + SBUF / 2);      // spare half of q region
    _Float16* yh   = (_Float16*)yb;                          // y fp16 (f,n,c), lower half
    _Float16* xh   = (_Float16*)(kb_region + SBUF / 2);      // x fp16 (dead when h1 written)
    _Float16* Wqh  = (_Float16*)(yb + SBUF / 2);             // W_qkv fp16 (yb upper, free)

    float*    h1   = kb_region;            // reuse: k+xh dead after attention
    _Float16* ff1h = (_Float16*)qb_region; // reuse: q+embh dead after attention

    prep_pack<<<6826, 256, 0, stream>>>(x, Wqkv, emb, te, Wtk, Wtv,
                                        xh, Wqh, embh, tk, tv);
    qkv_gemm<<<dim3(6, 1600), 256, 0, stream>>>(xh, Wqh, tk, tv, qnat, knat, vnat);
    v_pack<<<3200, 256, 0, stream>>>(vnat, vT);
    attn_kernel<<<3200, 512, 0, stream>>>(qnat, knat, vT, embh, yh);
    gate_ln1<<<ROWS / 4, 256, 0, stream>>>(x, yh, Wbeta, ln1g, ln1b, h1);
    ff1_gemm<<<dim3(2, 1600), 256, 0, stream>>>(h1, W1, b1, ff1h);
    ff2_ln2<<<3200, 256, 0, stream>>>(ff1h, W2, b2, h1, ln2g, ln2b, outp);
}

// Round 11
// 519.159 us; speedup vs baseline: 1.8943x; 1.0129x over previous
//
#include <hip/hip_runtime.h>
#include <math.h>

// Problem constants
#define F_DIM 256
#define N_DIM 400
#define C_DIM 128
#define H_DIM 8
#define E_DIM 16
#define ROWS  (F_DIM * N_DIM)          // 102400
#define SBUF  (N_DIM * H_DIM * F_DIM * E_DIM)  // 13107200 floats per q/k/v region

// r18 == r17 with one-line compile fix (cvt_pkrtz result needs bit_cast to
// uint in gate_ln1's h1h store). r17 theory untested:
//  (1) qkv_gemm + ff1: 1-D grid with XCD-aligned decode
//      bid = (rp%8) + 8*(CB*(rp/8)+cb) -> all col-blocks of a panel share
//      bid%8 (same XCD) -> L2 assembles full q/k/v row-lines (no RMW).
//  (2) gate_ln1 emits h1 ALSO as fp16 -> ff1 loads f16x8 (no cvts, -52MB).
//  (3) attn: rotate 9th R2 tile across waves; R2 write guard col<=256.
#define S_SCALE 0.6005612043932249f

typedef _Float16 half2_t __attribute__((ext_vector_type(2)));
typedef _Float16 f16x8   __attribute__((ext_vector_type(8)));
typedef float    f32x16  __attribute__((ext_vector_type(16)));
typedef float    f32x4   __attribute__((ext_vector_type(4)));

struct H2x4 { half2_t h[4]; };

// pack 8 consecutive fp32 (two float4) into an f16x8 fragment (RTZ)
__device__ inline f16x8 pack8(float4 a, float4 b) {
    H2x4 t;
    t.h[0] = __builtin_bit_cast(half2_t, __builtin_amdgcn_cvt_pkrtz(a.x, a.y));
    t.h[1] = __builtin_bit_cast(half2_t, __builtin_amdgcn_cvt_pkrtz(a.z, a.w));
    t.h[2] = __builtin_bit_cast(half2_t, __builtin_amdgcn_cvt_pkrtz(b.x, b.y));
    t.h[3] = __builtin_bit_cast(half2_t, __builtin_amdgcn_cvt_pkrtz(b.z, b.w));
    return __builtin_bit_cast(f16x8, t);
}

// scalar fp32 -> fp16 with RTZ (matches pack8 rounding)
__device__ inline _Float16 h_rtz(float v) {
    half2_t p = __builtin_bit_cast(half2_t, __builtin_amdgcn_cvt_pkrtz(v, v));
    return p[0];
}

__device__ inline int iclamp256(int v) { return v < 0 ? 0 : (v > 256 ? 256 : v); }

// ---------------------------------------------------------------------------
// K0: fused prep — x pack, W_qkv pack, emb pack (scaled), tree projections.
// grid 6826 x 256.
// ---------------------------------------------------------------------------
__global__ __launch_bounds__(256) void prep_pack(
    const float* __restrict__ x, const float* __restrict__ Wq,
    const float* __restrict__ emb, const float* __restrict__ te,
    const float* __restrict__ Wtk, const float* __restrict__ Wtv,
    _Float16* __restrict__ xh, _Float16* __restrict__ Wqh,
    _Float16* __restrict__ embh, float* __restrict__ tk, float* __restrict__ tv)
{
    int bid = blockIdx.x;
    int t   = threadIdx.x;
    if (bid < 6400) {
        int i = (bid * 256 + t) * 8;                 // 6400*256*8 = 13107200 exact
        const float4* s = (const float4*)(x + i);
        *(uint4*)(xh + i) = __builtin_bit_cast(uint4, pack8(s[0], s[1]));
    } else if (bid < 6424) {
        int i = ((bid - 6400) * 256 + t) * 8;        // 24*256*8 = 49152 exact
        const float4* s = (const float4*)(Wq + i);
        *(uint4*)(Wqh + i) = __builtin_bit_cast(uint4, pack8(s[0], s[1]));
    } else if (bid < 6426) {
        int r = (bid - 6424) * 256 + t;
        if (r > 256) return;
        const float4* er = (const float4*)(emb + r * 16);
        float4 e0 = er[0], e1 = er[1], e2 = er[2], e3 = er[3];
        e0.x *= S_SCALE; e0.y *= S_SCALE; e0.z *= S_SCALE; e0.w *= S_SCALE;
        e1.x *= S_SCALE; e1.y *= S_SCALE; e1.z *= S_SCALE; e1.w *= S_SCALE;
        e2.x *= S_SCALE; e2.y *= S_SCALE; e2.z *= S_SCALE; e2.w *= S_SCALE;
        e3.x *= S_SCALE; e3.y *= S_SCALE; e3.z *= S_SCALE; e3.w *= S_SCALE;
        *(uint4*)(embh + r * 16)     = __builtin_bit_cast(uint4, pack8(e0, e1));
        *(uint4*)(embh + r * 16 + 8) = __builtin_bit_cast(uint4, pack8(e2, e3));
    } else {
        int n = bid - 6426;                          // 400 blocks
        const float* W = (t < 128) ? Wtk : Wtv;
        float* outp    = (t < 128) ? tk : tv;
        int j = t & 127;
        float acc = 0.f;
        #pragma unroll 4
        for (int c = 0; c < 128; ++c)
            acc += te[n * 128 + c] * W[c * 128 + j];
        outp[n * 128 + j] = acc;
    }
}

// ---------------------------------------------------------------------------
// K1: qkv GEMM via fp16 MFMA; inputs pre-packed fp16 (direct f16x8 loads).
// q/k stores scaled by S_SCALE. Natural (r,c) fp16 stores.
// r17: 1-D grid 9600, XCD-aligned decode: all 6 col-blocks of a row-panel
// share bid%8 (same XCD) so q/k/v row-lines are assembled in one L2.
// ---------------------------------------------------------------------------
__global__ __launch_bounds__(256) void qkv_gemm(
    const _Float16* __restrict__ xh, const _Float16* __restrict__ Wqh,
    const float* __restrict__ tk, const float* __restrict__ tv,
    _Float16* __restrict__ qn, _Float16* __restrict__ kn, _Float16* __restrict__ vn)
{
    int tid  = threadIdx.x;
    int wave = tid >> 6, lane = tid & 63;
    int m32  = lane & 31, khalf = lane >> 5;

    int bid = blockIdx.x;            // 9600 = 1600 row-panels x 6 col-blocks
    int xcd = bid & 7;
    int tt  = bid >> 3;              // 0..1199
    int cb  = tt % 6;
    int rp  = (tt / 6) * 8 + xcd;    // 0..1599
    int row0 = rp * 64 + (wave & 1) * 32;
    int col0 = cb * 64 + (wave >> 1) * 32;

    const _Float16* xp = xh  + (row0 + m32) * 128 + khalf * 8;
    const _Float16* wp = Wqh + (col0 + m32) * 128 + khalf * 8;

    f32x16 acc;
    #pragma unroll
    for (int i = 0; i < 16; ++i) acc[i] = 0.f;

    #pragma unroll
    for (int k0 = 0; k0 < 128; k0 += 16) {
        f16x8 xa = __builtin_bit_cast(f16x8, *(const uint4*)(xp + k0));
        f16x8 wa = __builtin_bit_cast(f16x8, *(const uint4*)(wp + k0));
        acc = __builtin_amdgcn_mfma_f32_32x32x16_f16(xa, wa, acc, 0, 0, 0);
    }

    int o   = col0 + m32;
    int sec = o >> 7;
    int rem = o & 127;
    #pragma unroll
    for (int reg = 0; reg < 16; ++reg) {
        int r = row0 + (reg & 3) + 8 * (reg >> 2) + 4 * khalf;  // r = f*400+n
        float val = acc[reg];
        if (sec == 0) {
            qn[r * 128 + rem] = h_rtz(val * S_SCALE);
        } else {
            int f = r / 400;
            int n = r - f * 400;
            if (sec == 1) {
                kn[r * 128 + rem] = h_rtz((val + tk[n * 128 + rem]) * S_SCALE);
            } else {
                vn[r * 128 + rem] = (_Float16)(val + tv[n * 128 + rem]);  // RTN, unscaled
            }
        }
    }
}

// ---------------------------------------------------------------------------
// K1b: V transpose per (n,h): natural (f, e) -> vT (n,h,e,f).
// ---------------------------------------------------------------------------
__global__ __launch_bounds__(256) void v_pack(
    const _Float16* __restrict__ vn, _Float16* __restrict__ vT)
{
    __shared__ _Float16 sm[16 * 264];
    int bn = blockIdx.x;             // n*8 + h
    int n  = bn >> 3, h = bn & 7;
    int t  = threadIdx.x;            // f = t

    const uint4* src = (const uint4*)(vn + (t * 400 + n) * 128 + h * 16);
    uint4 a = src[0], b = src[1];
    union { uint4 u; _Float16 hv[8]; } ua, ub;
    ua.u = a; ub.u = b;
    #pragma unroll
    for (int e = 0; e < 8; ++e) sm[e * 264 + t]       = ua.hv[e];
    #pragma unroll
    for (int e = 0; e < 8; ++e) sm[(e + 8) * 264 + t] = ub.hv[e];
    __syncthreads();

    #pragma unroll
    for (int k = 0; k < 2; ++k) {
        int idx = (k * 256 + t) * 8;         // halves into (e,f) plane
        int e = idx >> 8, f0 = idx & 255;
        uint4 o = *(const uint4*)(sm + e * 264 + f0);
        *(uint4*)(vT + bn * 4096 + idx) = o;
    }
}

// ---------------------------------------------------------------------------
// K2: MFMA flash attention per (n,h). 8 waves x 512 threads; wave w owns
// l in [32w, 32w+32). Denominator via ones-MFMA; hoisted packed bpermutes;
// R2 tile 8 rotated across waves (r17). LDS 36992B.
// ---------------------------------------------------------------------------
#define R2_STRIDE 258   // halves per R2 row; dword stride 129 (odd) = conflict-free
#define PS_STRIDE 40    // halves per P row (80B, b128-aligned, odd-dword)

__global__ __launch_bounds__(512, 4) void attn_kernel(
    const _Float16* __restrict__ qb, const _Float16* __restrict__ kb,
    const _Float16* __restrict__ vb, const _Float16* __restrict__ embh,
    _Float16* __restrict__ y)
{
    __shared__ __align__(16) _Float16 R2sh[32 * R2_STRIDE];   // 16.5 KB
    __shared__ __align__(16) _Float16 Psh[8 * 32 * PS_STRIDE];// 20.5 KB

    int tid  = threadIdx.x;
    int wave = tid >> 6, lane = tid & 63;
    int bid  = blockIdx.x;
    // XCD swizzle: consecutive bn (which share q/k cache lines) -> same XCD.
    int bn   = (bid & 7) * 400 + (bid >> 3);   // 3200 % 8 == 0: bijective
    int n    = bn >> 3, h = bn & 7;
    int base = bn * 4096;             // halves (vT only)

    int nn  = lane & 31;            // score col / s-local / frag m-or-n index
    int kh  = lane >> 5;            // wave half (frag k split for 32-shapes)
    int khb = (lane & 32) << 2;     // bpermute addr offset into own half
    int cbase = 31 + 4 * kh - nn;   // window col base per lane
    int dbase = 4 * kh - nn;        // d offset per lane
    int q16 = (lane >> 4) & 3;      // quad for 16x16 shapes

    // natural-layout fragment offset for this (n,h,kh)
    int nat_off = n * 128 + h * 16 + kh * 8;

    // Q fragment for this wave's l-tile (direct 16B load from global)
    f16x8 aq = __builtin_bit_cast(f16x8,
        *(const uint4*)(qb + (32 * wave + nn) * 51200 + nat_off));

    // ones fragment for rowsum-MFMA (denominator)
    f16x8 bones;
    #pragma unroll
    for (int i = 0; i < 8; ++i) bones[i] = (_Float16)1.0f;

    f32x4 O[2];     // PV accumulators (two 16-row sub-tiles)
    f32x4 Od[2];    // denominator accumulators
    #pragma unroll
    for (int a = 0; a < 2; ++a)
        #pragma unroll
        for (int r = 0; r < 4; ++r) { O[a][r] = 0.f; Od[a][r] = 0.f; }

    _Float16* psw = Psh + wave * 32 * PS_STRIDE;

    for (int st = 0; st < 8; ++st) {
        // K-tile fragment (A for R2, B for QK): row f = 32*st + nn
        f16x8 bk = __builtin_bit_cast(f16x8,
            *(const uint4*)(kb + (32 * st + nn) * 51200 + nat_off));

        // ---- shared R2 table: R2[s_local][d] = K[32st+s_local] . emb[d] ----
        auto r2tile = [&](int ct) {
            int erow = 32 * ct + nn; if (erow > 256) erow = 256;
            f16x8 be = __builtin_bit_cast(f16x8,
                *(const uint4*)(embh + erow * 16 + kh * 8));
            f32x16 c2;
            #pragma unroll
            for (int i = 0; i < 16; ++i) c2[i] = 0.f;
            c2 = __builtin_amdgcn_mfma_f32_32x32x16_f16(bk, be, c2, 0, 0, 0);
            int col = 32 * ct + nn;
            if (col <= 256) {
                #pragma unroll
                for (int r = 0; r < 16; ++r) {
                    int srow = (r & 3) + 8 * (r >> 2) + 4 * kh;
                    R2sh[srow * R2_STRIDE + col] = (_Float16)c2[r];
                }
            }
        };
        r2tile(wave);
        if (wave == (st & 7)) r2tile(8);   // rotate the 9th tile's owner
        __syncthreads();   // R2 ready for all waves

        // PV B-fragment: V^T[e = lane&15][k = s-local = q16*8+j], direct global
        f16x8 bv = __builtin_bit_cast(f16x8,
            *(const uint4*)(vb + base + (lane & 15) * 256 + 32 * st + q16 * 8));

        int U0 = 32 * wave - 32 * st + 128;

        // scores
        f32x16 S;
        #pragma unroll
        for (int i = 0; i < 16; ++i) S[i] = 0.f;
        S = __builtin_amdgcn_mfma_f32_32x32x16_f16(aq, bk, S, 0, 0, 0);

        // bias1 windows: W[m][c] = Q[l0+m] . emb[clamp(U0-31+c)]
        int br0 = iclamp256(U0 - 31 + nn);
        int br1 = iclamp256(U0 + 1 + nn);
        f16x8 be0 = __builtin_bit_cast(f16x8,
            *(const uint4*)(embh + br0 * 16 + kh * 8));
        f16x8 be1 = __builtin_bit_cast(f16x8,
            *(const uint4*)(embh + br1 * 16 + kh * 8));
        f32x16 W0, W1;
        #pragma unroll
        for (int i = 0; i < 16; ++i) { W0[i] = 0.f; W1[i] = 0.f; }
        W0 = __builtin_amdgcn_mfma_f32_32x32x16_f16(aq, be0, W0, 0, 0, 0);
        W1 = __builtin_amdgcn_mfma_f32_32x32x16_f16(aq, be1, W1, 0, 0, 0);

        // hoisted packed bpermutes: b1 per element as fp16, frees W0/W1
        half2_t b1p[8];
        #pragma unroll
        for (int r = 0; r < 16; ++r) {
            int rmr = (r & 3) + 8 * (r >> 2);
            int c   = rmr + cbase;                 // [0,62]
            int addr = ((c & 31) << 2) + khb;
            int w01 = __builtin_bit_cast(int,
                __builtin_amdgcn_cvt_pkrtz(W0[r], W1[r]));
            half2_t hh = __builtin_bit_cast(half2_t,
                __builtin_amdgcn_ds_bpermute(addr, w01));
            b1p[r >> 1][r & 1] = (c < 32) ? hh[0] : hh[1];
        }

        #pragma unroll
        for (int r = 0; r < 16; ++r) {
            int rmr = (r & 3) + 8 * (r >> 2);
            float b1 = (float)b1p[r >> 1][r & 1];
            int d = iclamp256(U0 + rmr + dbase);
            float b2 = (float)R2sh[nn * R2_STRIDE + d];
            float p = __builtin_amdgcn_exp2f(S[r] + b1 + b2);
            int mloc = rmr + 4 * kh;
            psw[mloc * PS_STRIDE + nn] = (_Float16)p;
        }

        // PV + denom: 2 sub-tiles of 16 l-rows each, K = 32 (this s-tile)
        #pragma unroll
        for (int a = 0; a < 2; ++a) {
            f16x8 ap = __builtin_bit_cast(f16x8,
                *(const uint4*)(psw + (16 * a + (lane & 15)) * PS_STRIDE + q16 * 8));
            O[a]  = __builtin_amdgcn_mfma_f32_16x16x32_f16(ap, bv,    O[a],  0, 0, 0);
            Od[a] = __builtin_amdgcn_mfma_f32_16x16x32_f16(ap, bones, Od[a], 0, 0, 0);
        }
        __syncthreads();   // all reads of R2sh done before next st overwrites
    }

    // ---- epilogue: normalize + write (fp16 y); denom layout == O layout ----
    #pragma unroll
    for (int a = 0; a < 2; ++a) {
        #pragma unroll
        for (int r = 0; r < 4; ++r) {
            int row  = q16 * 4 + r;
            int lloc = 16 * a + row;
            int lg = 32 * wave + lloc;
            y[(lg * 400 + n) * 128 + h * 16 + (lane & 15)] =
                (_Float16)(O[a][r] / Od[a][r]);
        }
    }
}

// ---------------------------------------------------------------------------
// K3: gate+LN1 (y fp16). r17: also writes h1 as fp16 for ff1's fragments.
// ---------------------------------------------------------------------------
__global__ __launch_bounds__(256) void gate_ln1(
    const float* __restrict__ x, const _Float16* __restrict__ yh,
    const float* __restrict__ Wb, const float* __restrict__ g,
    const float* __restrict__ b, float* __restrict__ h1,
    _Float16* __restrict__ h1h)
{
    int tid  = threadIdx.x;
    int r    = blockIdx.x * 4 + (tid >> 6);
    int lane = tid & 63;
    int c    = lane * 2;

    float2 xv = *(const float2*)(x + r * 128 + c);
    half2_t yv2 = *(const half2_t*)(yh + r * 128 + c);
    float yvx = (float)yv2[0], yvy = (float)yv2[1];
    float2 w0 = *(const float2*)(Wb + c);
    float2 w1 = *(const float2*)(Wb + 128 + c);
    float2 w2 = *(const float2*)(Wb + 256 + c);

    float sv = yvx * w0.x + yvy * w0.y
             + xv.x * w1.x + xv.y * w1.y
             + (yvx - xv.x) * w2.x + (yvy - xv.y) * w2.y;
    #pragma unroll
    for (int off = 32; off > 0; off >>= 1) sv += __shfl_xor(sv, off);
    float gate = 1.0f / (1.0f + __expf(-sv));

    float z0 = gate * xv.x + (1.0f - gate) * yvx;
    float z1 = gate * xv.y + (1.0f - gate) * yvy;
    float s1 = z0 + z1, s2 = z0 * z0 + z1 * z1;
    #pragma unroll
    for (int off = 32; off > 0; off >>= 1) {
        s1 += __shfl_xor(s1, off);
        s2 += __shfl_xor(s2, off);
    }
    float mu  = s1 * (1.0f / 128.0f);
    float var = s2 * (1.0f / 128.0f) - mu * mu;
    float rs  = rsqrtf(var + 1e-5f);

    float2 gv = *(const float2*)(g + c);
    float2 bv = *(const float2*)(b + c);
    float2 ov;
    ov.x = (z0 - mu) * rs * gv.x + bv.x;
    ov.y = (z1 - mu) * rs * gv.y + bv.y;
    *(float2*)(h1 + r * 128 + c) = ov;
    *(uint*)(h1h + r * 128 + c) = __builtin_bit_cast(uint,
        __builtin_amdgcn_cvt_pkrtz(ov.x, ov.y));
}

// ---------------------------------------------------------------------------
// K4: ff1 fp16 MFMA + exact GELU; A fp16; output fp16.
// r17: 1-D grid 3200, XCD-aligned decode (both col-blocks same XCD).
// ---------------------------------------------------------------------------
__global__ __launch_bounds__(256) void ff1_gemm(
    const _Float16* __restrict__ A, const float* __restrict__ W,
    const float* __restrict__ bias, _Float16* __restrict__ outp)
{
    int tid  = threadIdx.x;
    int wave = tid >> 6, lane = tid & 63;
    int m32  = lane & 31, khalf = lane >> 5;

    int bid = blockIdx.x;            // 3200 = 1600 row-panels x 2 col-blocks
    int xcd = bid & 7;
    int tt  = bid >> 3;              // 0..399
    int cb  = tt & 1;
    int rp  = (tt >> 1) * 8 + xcd;   // 0..1599
    int row0 = rp * 64 + (wave & 1) * 32;
    int col0 = cb * 64 + (wave >> 1) * 32;

    const _Float16* ap = A + (row0 + m32) * 128 + khalf * 8;
    const float*    wp = W + (col0 + m32) * 128 + khalf * 8;

    f32x16 acc;
    #pragma unroll
    for (int i = 0; i < 16; ++i) acc[i] = 0.f;

    #pragma unroll
    for (int k0 = 0; k0 < 128; k0 += 16) {
        f16x8 aa16 = __builtin_bit_cast(f16x8, *(const uint4*)(ap + k0));
        float4 wa = *(const float4*)(wp + k0);
        float4 wb = *(const float4*)(wp + k0 + 4);
        acc = __builtin_amdgcn_mfma_f32_32x32x16_f16(aa16, pack8(wa, wb), acc, 0, 0, 0);
    }

    int   c  = col0 + m32;
    float bi = bias[c];
    #pragma unroll
    for (int reg = 0; reg < 16; ++reg) {
        int r = row0 + (reg & 3) + 8 * (reg >> 2) + 4 * khalf;
        float v = acc[reg] + bi;
        v = 0.5f * v * (1.0f + erff(v * 0.70710678118654752f));  // exact GELU
        outp[r * 128 + c] = (_Float16)v;
    }
}

// ---------------------------------------------------------------------------
// K5: ff2 + LN2 fp16 MFMA (A fp16 -> direct f16x8 fragment loads)
// ---------------------------------------------------------------------------
__global__ __launch_bounds__(256) void ff2_ln2(
    const _Float16* __restrict__ A, const float* __restrict__ W2,
    const float* __restrict__ b2, const float* __restrict__ h1,
    const float* __restrict__ g, const float* __restrict__ bb,
    float* __restrict__ outp)
{
    __shared__ float Cs[32 * 132];
    int tid  = threadIdx.x;
    int wave = tid >> 6, lane = tid & 63;
    int m32  = lane & 31, khalf = lane >> 5;
    int row0 = blockIdx.x * 32;
    int col0 = wave * 32;

    const _Float16* ap = A  + (row0 + m32) * 128 + khalf * 8;
    const float*    wp = W2 + (col0 + m32) * 128 + khalf * 8;

    f32x16 acc;
    #pragma unroll
    for (int i = 0; i < 16; ++i) acc[i] = 0.f;

    #pragma unroll
    for (int k0 = 0; k0 < 128; k0 += 16) {
        f16x8 aa16 = __builtin_bit_cast(f16x8, *(const uint4*)(ap + k0));
        float4 wa = *(const float4*)(wp + k0);
        float4 wb = *(const float4*)(wp + k0 + 4);
        acc = __builtin_amdgcn_mfma_f32_32x32x16_f16(aa16, pack8(wa, wb), acc, 0, 0, 0);
    }

    #pragma unroll
    for (int reg = 0; reg < 16; ++reg) {
        int rloc = (reg & 3) + 8 * (reg >> 2) + 4 * khalf;
        Cs[rloc * 132 + col0 + m32] = acc[reg];
    }
    __syncthreads();

    int rloc = tid >> 3, seg = (tid & 7) * 16;
    int r = row0 + rloc;
    float z[16];
    float s1 = 0.f, s2 = 0.f;
    #pragma unroll
    for (int j4 = 0; j4 < 4; ++j4) {
        float4 cv = *(const float4*)(Cs + rloc * 132 + seg + j4 * 4);
        float4 hv = *(const float4*)(h1 + r * 128 + seg + j4 * 4);
        float4 bv = *(const float4*)(b2 + seg + j4 * 4);
        z[j4*4+0] = cv.x + bv.x + hv.x;
        z[j4*4+1] = cv.y + bv.y + hv.y;
        z[j4*4+2] = cv.z + bv.z + hv.z;
        z[j4*4+3] = cv.w + bv.w + hv.w;
        s1 += z[j4*4+0] + z[j4*4+1] + z[j4*4+2] + z[j4*4+3];
        s2 += z[j4*4+0]*z[j4*4+0] + z[j4*4+1]*z[j4*4+1]
            + z[j4*4+2]*z[j4*4+2] + z[j4*4+3]*z[j4*4+3];
    }
    #pragma unroll
    for (int off = 4; off > 0; off >>= 1) {
        s1 += __shfl_xor(s1, off);
        s2 += __shfl_xor(s2, off);
    }
    float mu  = s1 * (1.0f / 128.0f);
    float var = s2 * (1.0f / 128.0f) - mu * mu;
    float rs  = rsqrtf(var + 1e-5f);
    #pragma unroll
    for (int j4 = 0; j4 < 4; ++j4) {
        float4 gv = *(const float4*)(g  + seg + j4 * 4);
        float4 bv = *(const float4*)(bb + seg + j4 * 4);
        float4 ov;
        ov.x = (z[j4*4+0] - mu) * rs * gv.x + bv.x;
        ov.y = (z[j4*4+1] - mu) * rs * gv.y + bv.y;
        ov.z = (z[j4*4+2] - mu) * rs * gv.z + bv.z;
        ov.w = (z[j4*4+3] - mu) * rs * gv.w + bv.w;
        *(float4*)(outp + r * 128 + seg + j4 * 4) = ov;
    }
}

// ---------------------------------------------------------------------------
extern "C" void kernel_launch(void* const* d_in, const int* in_sizes, int n_in,
                              void* d_out, int out_size, void* d_ws, size_t ws_size,
                              hipStream_t stream)
{
    const float* x     = (const float*)d_in[0];
    const float* te    = (const float*)d_in[1];
    const float* Wqkv  = (const float*)d_in[2];
    const float* Wtk   = (const float*)d_in[3];
    const float* Wtv   = (const float*)d_in[4];
    const float* emb   = (const float*)d_in[5];
    const float* Wbeta = (const float*)d_in[6];
    const float* ln1g  = (const float*)d_in[7];
    const float* ln1b  = (const float*)d_in[8];
    const float* ln2g  = (const float*)d_in[9];
    const float* ln2b  = (const float*)d_in[10];
    const float* W1    = (const float*)d_in[11];
    const float* b1    = (const float*)d_in[12];
    const float* W2    = (const float*)d_in[13];
    const float* b2    = (const float*)d_in[14];
    float* outp = (float*)d_out;

    float* ws = (float*)d_ws;
    float* tk = ws;                        // 51200
    float* tv = ws + 51200;                // 51200
    float* qb_region = ws + 102400;        // SBUF floats
    float* kb_region = qb_region + SBUF;   // SBUF floats
    float* vb_region = kb_region + SBUF;   // SBUF floats
    float* yb        = vb_region + SBUF;   // SBUF floats

    _Float16* qnat = (_Float16*)qb_region;                   // natural (r,c) fp16
    _Float16* knat = (_Float16*)kb_region;                   // natural (r,c) fp16
    _Float16* vnat = (_Float16*)vb_region;                   // natural (r,c) fp16
    _Float16* vT   = (_Float16*)(vb_region + SBUF / 2);      // (n,h,e,f) fp16
    _Float16* embh = (_Float16*)(qb_region + SBUF / 2);      // spare half of q region
    _Float16* yh   = (_Float16*)yb;                          // y fp16 (f,n,c), lower half
    _Float16* xh   = (_Float16*)(kb_region + SBUF / 2);      // x fp16 (dead when h1 written)
    _Float16* Wqh  = (_Float16*)(yb + SBUF / 2);             // W_qkv fp16 (yb upper, free)

    float*    h1   = kb_region;            // reuse: k+xh dead after attention
    _Float16* h1h  = (_Float16*)vb_region; // reuse: vnat dead after v_pack
    _Float16* ff1h = (_Float16*)qb_region; // reuse: q+embh dead after attention

    prep_pack<<<6826, 256, 0, stream>>>(x, Wqkv, emb, te, Wtk, Wtv,
                                        xh, Wqh, embh, tk, tv);
    qkv_gemm<<<9600, 256, 0, stream>>>(xh, Wqh, tk, tv, qnat, knat, vnat);
    v_pack<<<3200, 256, 0, stream>>>(vnat, vT);
    attn_kernel<<<3200, 512, 0, stream>>>(qnat, knat, vT, embh, yh);
    gate_ln1<<<ROWS / 4, 256, 0, stream>>>(x, yh, Wbeta, ln1g, ln1b, h1, h1h);
    ff1_gemm<<<3200, 256, 0, stream>>>(h1h, W1, b1, ff1h);
    ff2_ln2<<<3200, 256, 0, stream>>>(ff1h, W2, b2, h1, ln2g, ln2b, outp);
}

// Round 12
// 479.897 us; speedup vs baseline: 2.0493x; 1.0818x over previous
//
#include <hip/hip_runtime.h>
#include <math.h>

// Problem constants
#define F_DIM 256
#define N_DIM 400
#define C_DIM 128
#define H_DIM 8
#define E_DIM 16
#define ROWS  (F_DIM * N_DIM)          // 102400
#define SBUF  (N_DIM * H_DIM * F_DIM * E_DIM)  // 13107200 floats per q/k/v region

// r19: r18 verified 519us (attn 176.5 flat; XCD-decode gain was only ~7us
// -> per pre-commitment, XCD-RMW theory for non-attn REJECTED). Non-attn
// = 343us vs ~150 ideal; excess is h1/ff1h HBM round-trips (~210MB).
// This round: ffn_fused = gate+LN1+FF1+GELU+FF2+LN2 in ONE kernel
// (3200 blocks x 32 rows): h1 residual lives in 16 regs/thread (phase-1
// and phase-4 thread maps identical), h1-fp16 and gelu output live in
// LDS; FF1/FF2 are 4-wave 32x32 MFMA tiles from LDS. Back-half traffic
// 338MB -> 130MB; 7 -> 5 launches. attn untouched.
#define S_SCALE 0.6005612043932249f

typedef _Float16 half2_t __attribute__((ext_vector_type(2)));
typedef _Float16 f16x8   __attribute__((ext_vector_type(8)));
typedef float    f32x16  __attribute__((ext_vector_type(16)));
typedef float    f32x4   __attribute__((ext_vector_type(4)));

struct H2x4 { half2_t h[4]; };

// pack 8 consecutive fp32 (two float4) into an f16x8 fragment (RTZ)
__device__ inline f16x8 pack8(float4 a, float4 b) {
    H2x4 t;
    t.h[0] = __builtin_bit_cast(half2_t, __builtin_amdgcn_cvt_pkrtz(a.x, a.y));
    t.h[1] = __builtin_bit_cast(half2_t, __builtin_amdgcn_cvt_pkrtz(a.z, a.w));
    t.h[2] = __builtin_bit_cast(half2_t, __builtin_amdgcn_cvt_pkrtz(b.x, b.y));
    t.h[3] = __builtin_bit_cast(half2_t, __builtin_amdgcn_cvt_pkrtz(b.z, b.w));
    return __builtin_bit_cast(f16x8, t);
}

// scalar fp32 -> fp16 with RTZ (matches pack8 rounding)
__device__ inline _Float16 h_rtz(float v) {
    half2_t p = __builtin_bit_cast(half2_t, __builtin_amdgcn_cvt_pkrtz(v, v));
    return p[0];
}

__device__ inline int iclamp256(int v) { return v < 0 ? 0 : (v > 256 ? 256 : v); }

// ---------------------------------------------------------------------------
// K0: fused prep — x pack, W_qkv pack, emb pack (scaled), tree projections.
// grid 6826 x 256.
// ---------------------------------------------------------------------------
__global__ __launch_bounds__(256) void prep_pack(
    const float* __restrict__ x, const float* __restrict__ Wq,
    const float* __restrict__ emb, const float* __restrict__ te,
    const float* __restrict__ Wtk, const float* __restrict__ Wtv,
    _Float16* __restrict__ xh, _Float16* __restrict__ Wqh,
    _Float16* __restrict__ embh, float* __restrict__ tk, float* __restrict__ tv)
{
    int bid = blockIdx.x;
    int t   = threadIdx.x;
    if (bid < 6400) {
        int i = (bid * 256 + t) * 8;                 // 6400*256*8 = 13107200 exact
        const float4* s = (const float4*)(x + i);
        *(uint4*)(xh + i) = __builtin_bit_cast(uint4, pack8(s[0], s[1]));
    } else if (bid < 6424) {
        int i = ((bid - 6400) * 256 + t) * 8;        // 24*256*8 = 49152 exact
        const float4* s = (const float4*)(Wq + i);
        *(uint4*)(Wqh + i) = __builtin_bit_cast(uint4, pack8(s[0], s[1]));
    } else if (bid < 6426) {
        int r = (bid - 6424) * 256 + t;
        if (r > 256) return;
        const float4* er = (const float4*)(emb + r * 16);
        float4 e0 = er[0], e1 = er[1], e2 = er[2], e3 = er[3];
        e0.x *= S_SCALE; e0.y *= S_SCALE; e0.z *= S_SCALE; e0.w *= S_SCALE;
        e1.x *= S_SCALE; e1.y *= S_SCALE; e1.z *= S_SCALE; e1.w *= S_SCALE;
        e2.x *= S_SCALE; e2.y *= S_SCALE; e2.z *= S_SCALE; e2.w *= S_SCALE;
        e3.x *= S_SCALE; e3.y *= S_SCALE; e3.z *= S_SCALE; e3.w *= S_SCALE;
        *(uint4*)(embh + r * 16)     = __builtin_bit_cast(uint4, pack8(e0, e1));
        *(uint4*)(embh + r * 16 + 8) = __builtin_bit_cast(uint4, pack8(e2, e3));
    } else {
        int n = bid - 6426;                          // 400 blocks
        const float* W = (t < 128) ? Wtk : Wtv;
        float* outp    = (t < 128) ? tk : tv;
        int j = t & 127;
        float acc = 0.f;
        #pragma unroll 4
        for (int c = 0; c < 128; ++c)
            acc += te[n * 128 + c] * W[c * 128 + j];
        outp[n * 128 + j] = acc;
    }
}

// ---------------------------------------------------------------------------
// K1: qkv GEMM via fp16 MFMA; inputs pre-packed fp16 (direct f16x8 loads).
// q/k stores scaled by S_SCALE. Natural (r,c) fp16 stores. XCD-aligned grid.
// ---------------------------------------------------------------------------
__global__ __launch_bounds__(256) void qkv_gemm(
    const _Float16* __restrict__ xh, const _Float16* __restrict__ Wqh,
    const float* __restrict__ tk, const float* __restrict__ tv,
    _Float16* __restrict__ qn, _Float16* __restrict__ kn, _Float16* __restrict__ vn)
{
    int tid  = threadIdx.x;
    int wave = tid >> 6, lane = tid & 63;
    int m32  = lane & 31, khalf = lane >> 5;

    int bid = blockIdx.x;            // 9600 = 1600 row-panels x 6 col-blocks
    int xcd = bid & 7;
    int tt  = bid >> 3;              // 0..1199
    int cb  = tt % 6;
    int rp  = (tt / 6) * 8 + xcd;    // 0..1599
    int row0 = rp * 64 + (wave & 1) * 32;
    int col0 = cb * 64 + (wave >> 1) * 32;

    const _Float16* xp = xh  + (row0 + m32) * 128 + khalf * 8;
    const _Float16* wp = Wqh + (col0 + m32) * 128 + khalf * 8;

    f32x16 acc;
    #pragma unroll
    for (int i = 0; i < 16; ++i) acc[i] = 0.f;

    #pragma unroll
    for (int k0 = 0; k0 < 128; k0 += 16) {
        f16x8 xa = __builtin_bit_cast(f16x8, *(const uint4*)(xp + k0));
        f16x8 wa = __builtin_bit_cast(f16x8, *(const uint4*)(wp + k0));
        acc = __builtin_amdgcn_mfma_f32_32x32x16_f16(xa, wa, acc, 0, 0, 0);
    }

    int o   = col0 + m32;
    int sec = o >> 7;
    int rem = o & 127;
    #pragma unroll
    for (int reg = 0; reg < 16; ++reg) {
        int r = row0 + (reg & 3) + 8 * (reg >> 2) + 4 * khalf;  // r = f*400+n
        float val = acc[reg];
        if (sec == 0) {
            qn[r * 128 + rem] = h_rtz(val * S_SCALE);
        } else {
            int f = r / 400;
            int n = r - f * 400;
            if (sec == 1) {
                kn[r * 128 + rem] = h_rtz((val + tk[n * 128 + rem]) * S_SCALE);
            } else {
                vn[r * 128 + rem] = (_Float16)(val + tv[n * 128 + rem]);  // RTN, unscaled
            }
        }
    }
}

// ---------------------------------------------------------------------------
// K1b: V transpose per (n,h): natural (f, e) -> vT (n,h,e,f).
// ---------------------------------------------------------------------------
__global__ __launch_bounds__(256) void v_pack(
    const _Float16* __restrict__ vn, _Float16* __restrict__ vT)
{
    __shared__ _Float16 sm[16 * 264];
    int bn = blockIdx.x;             // n*8 + h
    int n  = bn >> 3, h = bn & 7;
    int t  = threadIdx.x;            // f = t

    const uint4* src = (const uint4*)(vn + (t * 400 + n) * 128 + h * 16);
    uint4 a = src[0], b = src[1];
    union { uint4 u; _Float16 hv[8]; } ua, ub;
    ua.u = a; ub.u = b;
    #pragma unroll
    for (int e = 0; e < 8; ++e) sm[e * 264 + t]       = ua.hv[e];
    #pragma unroll
    for (int e = 0; e < 8; ++e) sm[(e + 8) * 264 + t] = ub.hv[e];
    __syncthreads();

    #pragma unroll
    for (int k = 0; k < 2; ++k) {
        int idx = (k * 256 + t) * 8;         // halves into (e,f) plane
        int e = idx >> 8, f0 = idx & 255;
        uint4 o = *(const uint4*)(sm + e * 264 + f0);
        *(uint4*)(vT + bn * 4096 + idx) = o;
    }
}

// ---------------------------------------------------------------------------
// K2: MFMA flash attention per (n,h). 8 waves x 512 threads; wave w owns
// l in [32w, 32w+32). Denominator via ones-MFMA; hoisted packed bpermutes;
// R2 tile 8 rotated across waves. LDS 36992B. (unchanged from r18)
// ---------------------------------------------------------------------------
#define R2_STRIDE 258   // halves per R2 row; dword stride 129 (odd) = conflict-free
#define PS_STRIDE 40    // halves per P row (80B, b128-aligned, odd-dword)

__global__ __launch_bounds__(512, 4) void attn_kernel(
    const _Float16* __restrict__ qb, const _Float16* __restrict__ kb,
    const _Float16* __restrict__ vb, const _Float16* __restrict__ embh,
    _Float16* __restrict__ y)
{
    __shared__ __align__(16) _Float16 R2sh[32 * R2_STRIDE];   // 16.5 KB
    __shared__ __align__(16) _Float16 Psh[8 * 32 * PS_STRIDE];// 20.5 KB

    int tid  = threadIdx.x;
    int wave = tid >> 6, lane = tid & 63;
    int bid  = blockIdx.x;
    // XCD swizzle: consecutive bn (which share q/k cache lines) -> same XCD.
    int bn   = (bid & 7) * 400 + (bid >> 3);   // 3200 % 8 == 0: bijective
    int n    = bn >> 3, h = bn & 7;
    int base = bn * 4096;             // halves (vT only)

    int nn  = lane & 31;            // score col / s-local / frag m-or-n index
    int kh  = lane >> 5;            // wave half (frag k split for 32-shapes)
    int khb = (lane & 32) << 2;     // bpermute addr offset into own half
    int cbase = 31 + 4 * kh - nn;   // window col base per lane
    int dbase = 4 * kh - nn;        // d offset per lane
    int q16 = (lane >> 4) & 3;      // quad for 16x16 shapes

    // natural-layout fragment offset for this (n,h,kh)
    int nat_off = n * 128 + h * 16 + kh * 8;

    // Q fragment for this wave's l-tile (direct 16B load from global)
    f16x8 aq = __builtin_bit_cast(f16x8,
        *(const uint4*)(qb + (32 * wave + nn) * 51200 + nat_off));

    // ones fragment for rowsum-MFMA (denominator)
    f16x8 bones;
    #pragma unroll
    for (int i = 0; i < 8; ++i) bones[i] = (_Float16)1.0f;

    f32x4 O[2];     // PV accumulators (two 16-row sub-tiles)
    f32x4 Od[2];    // denominator accumulators
    #pragma unroll
    for (int a = 0; a < 2; ++a)
        #pragma unroll
        for (int r = 0; r < 4; ++r) { O[a][r] = 0.f; Od[a][r] = 0.f; }

    _Float16* psw = Psh + wave * 32 * PS_STRIDE;

    for (int st = 0; st < 8; ++st) {
        // K-tile fragment (A for R2, B for QK): row f = 32*st + nn
        f16x8 bk = __builtin_bit_cast(f16x8,
            *(const uint4*)(kb + (32 * st + nn) * 51200 + nat_off));

        // ---- shared R2 table: R2[s_local][d] = K[32st+s_local] . emb[d] ----
        auto r2tile = [&](int ct) {
            int erow = 32 * ct + nn; if (erow > 256) erow = 256;
            f16x8 be = __builtin_bit_cast(f16x8,
                *(const uint4*)(embh + erow * 16 + kh * 8));
            f32x16 c2;
            #pragma unroll
            for (int i = 0; i < 16; ++i) c2[i] = 0.f;
            c2 = __builtin_amdgcn_mfma_f32_32x32x16_f16(bk, be, c2, 0, 0, 0);
            int col = 32 * ct + nn;
            if (col <= 256) {
                #pragma unroll
                for (int r = 0; r < 16; ++r) {
                    int srow = (r & 3) + 8 * (r >> 2) + 4 * kh;
                    R2sh[srow * R2_STRIDE + col] = (_Float16)c2[r];
                }
            }
        };
        r2tile(wave);
        if (wave == (st & 7)) r2tile(8);   // rotate the 9th tile's owner
        __syncthreads();   // R2 ready for all waves

        // PV B-fragment: V^T[e = lane&15][k = s-local = q16*8+j], direct global
        f16x8 bv = __builtin_bit_cast(f16x8,
            *(const uint4*)(vb + base + (lane & 15) * 256 + 32 * st + q16 * 8));

        int U0 = 32 * wave - 32 * st + 128;

        // scores
        f32x16 S;
        #pragma unroll
        for (int i = 0; i < 16; ++i) S[i] = 0.f;
        S = __builtin_amdgcn_mfma_f32_32x32x16_f16(aq, bk, S, 0, 0, 0);

        // bias1 windows: W[m][c] = Q[l0+m] . emb[clamp(U0-31+c)]
        int br0 = iclamp256(U0 - 31 + nn);
        int br1 = iclamp256(U0 + 1 + nn);
        f16x8 be0 = __builtin_bit_cast(f16x8,
            *(const uint4*)(embh + br0 * 16 + kh * 8));
        f16x8 be1 = __builtin_bit_cast(f16x8,
            *(const uint4*)(embh + br1 * 16 + kh * 8));
        f32x16 W0, W1;
        #pragma unroll
        for (int i = 0; i < 16; ++i) { W0[i] = 0.f; W1[i] = 0.f; }
        W0 = __builtin_amdgcn_mfma_f32_32x32x16_f16(aq, be0, W0, 0, 0, 0);
        W1 = __builtin_amdgcn_mfma_f32_32x32x16_f16(aq, be1, W1, 0, 0, 0);

        // hoisted packed bpermutes: b1 per element as fp16, frees W0/W1
        half2_t b1p[8];
        #pragma unroll
        for (int r = 0; r < 16; ++r) {
            int rmr = (r & 3) + 8 * (r >> 2);
            int c   = rmr + cbase;                 // [0,62]
            int addr = ((c & 31) << 2) + khb;
            int w01 = __builtin_bit_cast(int,
                __builtin_amdgcn_cvt_pkrtz(W0[r], W1[r]));
            half2_t hh = __builtin_bit_cast(half2_t,
                __builtin_amdgcn_ds_bpermute(addr, w01));
            b1p[r >> 1][r & 1] = (c < 32) ? hh[0] : hh[1];
        }

        #pragma unroll
        for (int r = 0; r < 16; ++r) {
            int rmr = (r & 3) + 8 * (r >> 2);
            float b1 = (float)b1p[r >> 1][r & 1];
            int d = iclamp256(U0 + rmr + dbase);
            float b2 = (float)R2sh[nn * R2_STRIDE + d];
            float p = __builtin_amdgcn_exp2f(S[r] + b1 + b2);
            int mloc = rmr + 4 * kh;
            psw[mloc * PS_STRIDE + nn] = (_Float16)p;
        }

        // PV + denom: 2 sub-tiles of 16 l-rows each, K = 32 (this s-tile)
        #pragma unroll
        for (int a = 0; a < 2; ++a) {
            f16x8 ap = __builtin_bit_cast(f16x8,
                *(const uint4*)(psw + (16 * a + (lane & 15)) * PS_STRIDE + q16 * 8));
            O[a]  = __builtin_amdgcn_mfma_f32_16x16x32_f16(ap, bv,    O[a],  0, 0, 0);
            Od[a] = __builtin_amdgcn_mfma_f32_16x16x32_f16(ap, bones, Od[a], 0, 0, 0);
        }
        __syncthreads();   // all reads of R2sh done before next st overwrites
    }

    // ---- epilogue: normalize + write (fp16 y); denom layout == O layout ----
    #pragma unroll
    for (int a = 0; a < 2; ++a) {
        #pragma unroll
        for (int r = 0; r < 4; ++r) {
            int row  = q16 * 4 + r;
            int lloc = 16 * a + row;
            int lg = 32 * wave + lloc;
            y[(lg * 400 + n) * 128 + h * 16 + (lane & 15)] =
                (_Float16)(O[a][r] / Od[a][r]);
        }
    }
}

// ---------------------------------------------------------------------------
// K3 (r19): FUSED back half — gate+LN1 -> FF1+GELU -> FF2 -> +h1, LN2.
// 3200 blocks x 256 threads; block owns 32 full rows. h1 residual stays in
// 16 regs/thread (phase-1 and phase-4 use the same rloc/seg map); h1-fp16
// and gelu output live in LDS; FF1/FF2 are 4-wave 32x32 MFMA tiles (K=128).
// LDS: h1sh 8704B + gsh 8704B + Cs 16896B = 34304B.
// ---------------------------------------------------------------------------
__global__ __launch_bounds__(256) void ffn_fused(
    const float* __restrict__ x, const _Float16* __restrict__ yh,
    const float* __restrict__ Wb,
    const float* __restrict__ ln1g, const float* __restrict__ ln1b,
    const float* __restrict__ W1, const float* __restrict__ b1,
    const float* __restrict__ W2, const float* __restrict__ b2,
    const float* __restrict__ ln2g, const float* __restrict__ ln2b,
    float* __restrict__ outp)
{
    __shared__ __align__(16) _Float16 h1sh[32 * 136];  // 8704 B
    __shared__ __align__(16) _Float16 gsh[32 * 136];   // 8704 B
    __shared__ float Cs[32 * 132];                     // 16896 B

    int tid  = threadIdx.x;
    int rloc = tid >> 3;               // 0..31 (row within block)
    int seg  = (tid & 7) * 16;         // 16-col segment
    int r    = blockIdx.x * 32 + rloc;

    // ---- phase 1: gate + LN1 (8 threads per row, shfl over 8 lanes) ----
    float xv[16], yv[16];
    {
        const float4* xp = (const float4*)(x + r * 128 + seg);
        float4 x0 = xp[0], x1 = xp[1], x2 = xp[2], x3 = xp[3];
        xv[0]=x0.x; xv[1]=x0.y; xv[2]=x0.z; xv[3]=x0.w;
        xv[4]=x1.x; xv[5]=x1.y; xv[6]=x1.z; xv[7]=x1.w;
        xv[8]=x2.x; xv[9]=x2.y; xv[10]=x2.z; xv[11]=x2.w;
        xv[12]=x3.x; xv[13]=x3.y; xv[14]=x3.z; xv[15]=x3.w;
        const uint4* yp = (const uint4*)(yh + r * 128 + seg);
        uint4 y0 = yp[0], y1 = yp[1];
        union { uint4 u; _Float16 hv[8]; } uy0, uy1;
        uy0.u = y0; uy1.u = y1;
        #pragma unroll
        for (int j = 0; j < 8; ++j) { yv[j] = (float)uy0.hv[j]; yv[8+j] = (float)uy1.hv[j]; }
    }
    float sv = 0.f;
    {
        const float4* w0p = (const float4*)(Wb + seg);
        const float4* w1p = (const float4*)(Wb + 128 + seg);
        const float4* w2p = (const float4*)(Wb + 256 + seg);
        #pragma unroll
        for (int j4 = 0; j4 < 4; ++j4) {
            float4 w0 = w0p[j4], w1 = w1p[j4], w2 = w2p[j4];
            float* w0f = (float*)&w0; float* w1f = (float*)&w1; float* w2f = (float*)&w2;
            #pragma unroll
            for (int jj = 0; jj < 4; ++jj) {
                int j = j4 * 4 + jj;
                sv += yv[j] * w0f[jj] + xv[j] * w1f[jj] + (yv[j] - xv[j]) * w2f[jj];
            }
        }
    }
    #pragma unroll
    for (int off = 4; off > 0; off >>= 1) sv += __shfl_xor(sv, off);
    float gate = 1.0f / (1.0f + __expf(-sv));

    float z[16], s1 = 0.f, s2 = 0.f;
    #pragma unroll
    for (int j = 0; j < 16; ++j) {
        z[j] = gate * xv[j] + (1.0f - gate) * yv[j];
        s1 += z[j]; s2 += z[j] * z[j];
    }
    #pragma unroll
    for (int off = 4; off > 0; off >>= 1) {
        s1 += __shfl_xor(s1, off);
        s2 += __shfl_xor(s2, off);
    }
    float mu  = s1 * (1.0f / 128.0f);
    float var = s2 * (1.0f / 128.0f) - mu * mu;
    float rs  = rsqrtf(var + 1e-5f);

    float h1r[16];   // h1 residual, stays in registers until phase 4
    {
        const float4* gp = (const float4*)(ln1g + seg);
        const float4* bp = (const float4*)(ln1b + seg);
        #pragma unroll
        for (int j4 = 0; j4 < 4; ++j4) {
            float4 gv = gp[j4], bv = bp[j4];
            float* gf = (float*)&gv; float* bf = (float*)&bv;
            #pragma unroll
            for (int jj = 0; jj < 4; ++jj) {
                int j = j4 * 4 + jj;
                h1r[j] = (z[j] - mu) * rs * gf[jj] + bf[jj];
            }
        }
        // store fp16 h1 to LDS for the FF1 fragments
        #pragma unroll
        for (int j = 0; j < 8; ++j) {
            *(uint*)(h1sh + rloc * 136 + seg + 2 * j) = __builtin_bit_cast(uint,
                __builtin_amdgcn_cvt_pkrtz(h1r[2 * j], h1r[2 * j + 1]));
        }
    }
    __syncthreads();

    // ---- phase 2: FF1 + GELU -> gsh (4 waves, each a 32x32 tile, K=128) ----
    int wave = tid >> 6, lane = tid & 63;
    int m32  = lane & 31, khalf = lane >> 5;
    int col0 = wave * 32;
    {
        f32x16 acc;
        #pragma unroll
        for (int i = 0; i < 16; ++i) acc[i] = 0.f;
        const _Float16* ap = h1sh + m32 * 136 + khalf * 8;
        const float*    wp = W1 + (col0 + m32) * 128 + khalf * 8;
        #pragma unroll
        for (int k0 = 0; k0 < 128; k0 += 16) {
            f16x8 aa = __builtin_bit_cast(f16x8, *(const uint4*)(ap + k0));
            float4 wa = *(const float4*)(wp + k0);
            float4 wb = *(const float4*)(wp + k0 + 4);
            acc = __builtin_amdgcn_mfma_f32_32x32x16_f16(aa, pack8(wa, wb), acc, 0, 0, 0);
        }
        int   c  = col0 + m32;
        float bi = b1[c];
        #pragma unroll
        for (int reg = 0; reg < 16; ++reg) {
            int row2 = (reg & 3) + 8 * (reg >> 2) + 4 * khalf;
            float v = acc[reg] + bi;
            v = 0.5f * v * (1.0f + erff(v * 0.70710678118654752f));  // exact GELU
            gsh[row2 * 136 + c] = (_Float16)v;
        }
    }
    __syncthreads();

    // ---- phase 3: FF2 -> Cs ----
    {
        f32x16 acc;
        #pragma unroll
        for (int i = 0; i < 16; ++i) acc[i] = 0.f;
        const _Float16* ap = gsh + m32 * 136 + khalf * 8;
        const float*    wp = W2 + (col0 + m32) * 128 + khalf * 8;
        #pragma unroll
        for (int k0 = 0; k0 < 128; k0 += 16) {
            f16x8 aa = __builtin_bit_cast(f16x8, *(const uint4*)(ap + k0));
            float4 wa = *(const float4*)(wp + k0);
            float4 wb = *(const float4*)(wp + k0 + 4);
            acc = __builtin_amdgcn_mfma_f32_32x32x16_f16(aa, pack8(wa, wb), acc, 0, 0, 0);
        }
        #pragma unroll
        for (int reg = 0; reg < 16; ++reg) {
            int row2 = (reg & 3) + 8 * (reg >> 2) + 4 * khalf;
            Cs[row2 * 132 + col0 + m32] = acc[reg];
        }
    }
    __syncthreads();

    // ---- phase 4: residual (from regs) + LN2 + write ----
    float z2[16];
    float t1 = 0.f, t2 = 0.f;
    #pragma unroll
    for (int j4 = 0; j4 < 4; ++j4) {
        float4 cv = *(const float4*)(Cs + rloc * 132 + seg + j4 * 4);
        float4 bv = *(const float4*)(b2 + seg + j4 * 4);
        float* cf = (float*)&cv; float* bf = (float*)&bv;
        #pragma unroll
        for (int jj = 0; jj < 4; ++jj) {
            int j = j4 * 4 + jj;
            z2[j] = cf[jj] + bf[jj] + h1r[j];
            t1 += z2[j]; t2 += z2[j] * z2[j];
        }
    }
    #pragma unroll
    for (int off = 4; off > 0; off >>= 1) {
        t1 += __shfl_xor(t1, off);
        t2 += __shfl_xor(t2, off);
    }
    float mu2  = t1 * (1.0f / 128.0f);
    float var2 = t2 * (1.0f / 128.0f) - mu2 * mu2;
    float rs2  = rsqrtf(var2 + 1e-5f);
    #pragma unroll
    for (int j4 = 0; j4 < 4; ++j4) {
        float4 gv = *(const float4*)(ln2g + seg + j4 * 4);
        float4 bv = *(const float4*)(ln2b + seg + j4 * 4);
        float* gf = (float*)&gv; float* bf = (float*)&bv;
        float4 ov;
        float* of = (float*)&ov;
        #pragma unroll
        for (int jj = 0; jj < 4; ++jj) {
            int j = j4 * 4 + jj;
            of[jj] = (z2[j] - mu2) * rs2 * gf[jj] + bf[jj];
        }
        *(float4*)(outp + r * 128 + seg + j4 * 4) = ov;
    }
}

// ---------------------------------------------------------------------------
extern "C" void kernel_launch(void* const* d_in, const int* in_sizes, int n_in,
                              void* d_out, int out_size, void* d_ws, size_t ws_size,
                              hipStream_t stream)
{
    const float* x     = (const float*)d_in[0];
    const float* te    = (const float*)d_in[1];
    const float* Wqkv  = (const float*)d_in[2];
    const float* Wtk   = (const float*)d_in[3];
    const float* Wtv   = (const float*)d_in[4];
    const float* emb   = (const float*)d_in[5];
    const float* Wbeta = (const float*)d_in[6];
    const float* ln1g  = (const float*)d_in[7];
    const float* ln1b  = (const float*)d_in[8];
    const float* ln2g  = (const float*)d_in[9];
    const float* ln2b  = (const float*)d_in[10];
    const float* W1    = (const float*)d_in[11];
    const float* b1    = (const float*)d_in[12];
    const float* W2    = (const float*)d_in[13];
    const float* b2    = (const float*)d_in[14];
    float* outp = (float*)d_out;

    float* ws = (float*)d_ws;
    float* tk = ws;                        // 51200
    float* tv = ws + 51200;                // 51200
    float* qb_region = ws + 102400;        // SBUF floats
    float* kb_region = qb_region + SBUF;   // SBUF floats
    float* vb_region = kb_region + SBUF;   // SBUF floats
    float* yb        = vb_region + SBUF;   // SBUF floats

    _Float16* qnat = (_Float16*)qb_region;                   // natural (r,c) fp16
    _Float16* knat = (_Float16*)kb_region;                   // natural (r,c) fp16
    _Float16* vnat = (_Float16*)vb_region;                   // natural (r,c) fp16
    _Float16* vT   = (_Float16*)(vb_region + SBUF / 2);      // (n,h,e,f) fp16
    _Float16* embh = (_Float16*)(qb_region + SBUF / 2);      // spare half of q region
    _Float16* yh   = (_Float16*)yb;                          // y fp16 (f,n,c), lower half
    _Float16* xh   = (_Float16*)(kb_region + SBUF / 2);      // x fp16 packed
    _Float16* Wqh  = (_Float16*)(yb + SBUF / 2);             // W_qkv fp16 (yb upper, free)

    prep_pack<<<6826, 256, 0, stream>>>(x, Wqkv, emb, te, Wtk, Wtv,
                                        xh, Wqh, embh, tk, tv);
    qkv_gemm<<<9600, 256, 0, stream>>>(xh, Wqh, tk, tv, qnat, knat, vnat);
    v_pack<<<3200, 256, 0, stream>>>(vnat, vT);
    attn_kernel<<<3200, 512, 0, stream>>>(qnat, knat, vT, embh, yh);
    ffn_fused<<<3200, 256, 0, stream>>>(x, yh, Wbeta, ln1g, ln1b,
                                        W1, b1, W2, b2, ln2g, ln2b, outp);
}

// Round 13
// 458.540 us; speedup vs baseline: 2.1448x; 1.0466x over previous
//
#include <hip/hip_runtime.h>
#include <math.h>

// Problem constants
#define F_DIM 256
#define N_DIM 400
#define C_DIM 128
#define H_DIM 8
#define E_DIM 16
#define ROWS  (F_DIM * N_DIM)          // 102400
#define SBUF  (N_DIM * H_DIM * F_DIM * E_DIM)  // 13107200 floats per q/k/v region

// r20: r19 verified 480us (ffn fusion +39us as predicted; attn 176 flat).
// Diagnosis: attn occupancy 41% is AGPR-limited (S+W0+W1+O/Od+c2 ~80 AGPR
// hidden from VGPR_Count=60 -> ~140 combined -> 14.6 waves/CU = measured).
// Bank-conflict counter = 1.6% of cycles -> red herring, dropped.
// This round:
//  (1) attn: sink S MFMA below the b1p bpermutes -> W0/W1 dead before S
//      lives; peak AGPR -16 -> ~16.5 waves/CU.
//  (2) prep_pack: W1/W2 pre-packed fp16 (RTZ, bit-identical to ffn's old
//      in-loop pack8); ffn_fused loads f16x8 W fragments (half bytes, no
//      cvts). grid 6842.
#define S_SCALE 0.6005612043932249f

typedef _Float16 half2_t __attribute__((ext_vector_type(2)));
typedef _Float16 f16x8   __attribute__((ext_vector_type(8)));
typedef float    f32x16  __attribute__((ext_vector_type(16)));
typedef float    f32x4   __attribute__((ext_vector_type(4)));

struct H2x4 { half2_t h[4]; };

// pack 8 consecutive fp32 (two float4) into an f16x8 fragment (RTZ)
__device__ inline f16x8 pack8(float4 a, float4 b) {
    H2x4 t;
    t.h[0] = __builtin_bit_cast(half2_t, __builtin_amdgcn_cvt_pkrtz(a.x, a.y));
    t.h[1] = __builtin_bit_cast(half2_t, __builtin_amdgcn_cvt_pkrtz(a.z, a.w));
    t.h[2] = __builtin_bit_cast(half2_t, __builtin_amdgcn_cvt_pkrtz(b.x, b.y));
    t.h[3] = __builtin_bit_cast(half2_t, __builtin_amdgcn_cvt_pkrtz(b.z, b.w));
    return __builtin_bit_cast(f16x8, t);
}

// scalar fp32 -> fp16 with RTZ (matches pack8 rounding)
__device__ inline _Float16 h_rtz(float v) {
    half2_t p = __builtin_bit_cast(half2_t, __builtin_amdgcn_cvt_pkrtz(v, v));
    return p[0];
}

__device__ inline int iclamp256(int v) { return v < 0 ? 0 : (v > 256 ? 256 : v); }

// ---------------------------------------------------------------------------
// K0: fused prep — x/Wq/W1/W2 fp16 pack, emb pack (scaled), tree proj.
// grid 6842 x 256.
// ---------------------------------------------------------------------------
__global__ __launch_bounds__(256) void prep_pack(
    const float* __restrict__ x, const float* __restrict__ Wq,
    const float* __restrict__ emb, const float* __restrict__ te,
    const float* __restrict__ Wtk, const float* __restrict__ Wtv,
    const float* __restrict__ W1, const float* __restrict__ W2,
    _Float16* __restrict__ xh, _Float16* __restrict__ Wqh,
    _Float16* __restrict__ embh, float* __restrict__ tk, float* __restrict__ tv,
    _Float16* __restrict__ W1h, _Float16* __restrict__ W2h)
{
    int bid = blockIdx.x;
    int t   = threadIdx.x;
    if (bid < 6400) {
        int i = (bid * 256 + t) * 8;                 // 6400*256*8 = 13107200 exact
        const float4* s = (const float4*)(x + i);
        *(uint4*)(xh + i) = __builtin_bit_cast(uint4, pack8(s[0], s[1]));
    } else if (bid < 6424) {
        int i = ((bid - 6400) * 256 + t) * 8;        // 24*256*8 = 49152 exact
        const float4* s = (const float4*)(Wq + i);
        *(uint4*)(Wqh + i) = __builtin_bit_cast(uint4, pack8(s[0], s[1]));
    } else if (bid < 6426) {
        int r = (bid - 6424) * 256 + t;
        if (r > 256) return;
        const float4* er = (const float4*)(emb + r * 16);
        float4 e0 = er[0], e1 = er[1], e2 = er[2], e3 = er[3];
        e0.x *= S_SCALE; e0.y *= S_SCALE; e0.z *= S_SCALE; e0.w *= S_SCALE;
        e1.x *= S_SCALE; e1.y *= S_SCALE; e1.z *= S_SCALE; e1.w *= S_SCALE;
        e2.x *= S_SCALE; e2.y *= S_SCALE; e2.z *= S_SCALE; e2.w *= S_SCALE;
        e3.x *= S_SCALE; e3.y *= S_SCALE; e3.z *= S_SCALE; e3.w *= S_SCALE;
        *(uint4*)(embh + r * 16)     = __builtin_bit_cast(uint4, pack8(e0, e1));
        *(uint4*)(embh + r * 16 + 8) = __builtin_bit_cast(uint4, pack8(e2, e3));
    } else if (bid < 6826) {
        int n = bid - 6426;                          // 400 blocks
        const float* W = (t < 128) ? Wtk : Wtv;
        float* outp    = (t < 128) ? tk : tv;
        int j = t & 127;
        float acc = 0.f;
        #pragma unroll 4
        for (int c = 0; c < 128; ++c)
            acc += te[n * 128 + c] * W[c * 128 + j];
        outp[n * 128 + j] = acc;
    } else if (bid < 6834) {
        int i = ((bid - 6826) * 256 + t) * 8;        // 8*256*8 = 16384 exact
        const float4* s = (const float4*)(W1 + i);
        *(uint4*)(W1h + i) = __builtin_bit_cast(uint4, pack8(s[0], s[1]));
    } else {
        int i = ((bid - 6834) * 256 + t) * 8;        // 8*256*8 = 16384 exact
        const float4* s = (const float4*)(W2 + i);
        *(uint4*)(W2h + i) = __builtin_bit_cast(uint4, pack8(s[0], s[1]));
    }
}

// ---------------------------------------------------------------------------
// K1: qkv GEMM via fp16 MFMA; inputs pre-packed fp16 (direct f16x8 loads).
// q/k stores scaled by S_SCALE. Natural (r,c) fp16 stores. XCD-aligned grid.
// ---------------------------------------------------------------------------
__global__ __launch_bounds__(256) void qkv_gemm(
    const _Float16* __restrict__ xh, const _Float16* __restrict__ Wqh,
    const float* __restrict__ tk, const float* __restrict__ tv,
    _Float16* __restrict__ qn, _Float16* __restrict__ kn, _Float16* __restrict__ vn)
{
    int tid  = threadIdx.x;
    int wave = tid >> 6, lane = tid & 63;
    int m32  = lane & 31, khalf = lane >> 5;

    int bid = blockIdx.x;            // 9600 = 1600 row-panels x 6 col-blocks
    int xcd = bid & 7;
    int tt  = bid >> 3;              // 0..1199
    int cb  = tt % 6;
    int rp  = (tt / 6) * 8 + xcd;    // 0..1599
    int row0 = rp * 64 + (wave & 1) * 32;
    int col0 = cb * 64 + (wave >> 1) * 32;

    const _Float16* xp = xh  + (row0 + m32) * 128 + khalf * 8;
    const _Float16* wp = Wqh + (col0 + m32) * 128 + khalf * 8;

    f32x16 acc;
    #pragma unroll
    for (int i = 0; i < 16; ++i) acc[i] = 0.f;

    #pragma unroll
    for (int k0 = 0; k0 < 128; k0 += 16) {
        f16x8 xa = __builtin_bit_cast(f16x8, *(const uint4*)(xp + k0));
        f16x8 wa = __builtin_bit_cast(f16x8, *(const uint4*)(wp + k0));
        acc = __builtin_amdgcn_mfma_f32_32x32x16_f16(xa, wa, acc, 0, 0, 0);
    }

    int o   = col0 + m32;
    int sec = o >> 7;
    int rem = o & 127;
    #pragma unroll
    for (int reg = 0; reg < 16; ++reg) {
        int r = row0 + (reg & 3) + 8 * (reg >> 2) + 4 * khalf;  // r = f*400+n
        float val = acc[reg];
        if (sec == 0) {
            qn[r * 128 + rem] = h_rtz(val * S_SCALE);
        } else {
            int f = r / 400;
            int n = r - f * 400;
            if (sec == 1) {
                kn[r * 128 + rem] = h_rtz((val + tk[n * 128 + rem]) * S_SCALE);
            } else {
                vn[r * 128 + rem] = (_Float16)(val + tv[n * 128 + rem]);  // RTN, unscaled
            }
        }
    }
}

// ---------------------------------------------------------------------------
// K1b: V transpose per (n,h): natural (f, e) -> vT (n,h,e,f).
// ---------------------------------------------------------------------------
__global__ __launch_bounds__(256) void v_pack(
    const _Float16* __restrict__ vn, _Float16* __restrict__ vT)
{
    __shared__ _Float16 sm[16 * 264];
    int bn = blockIdx.x;             // n*8 + h
    int n  = bn >> 3, h = bn & 7;
    int t  = threadIdx.x;            // f = t

    const uint4* src = (const uint4*)(vn + (t * 400 + n) * 128 + h * 16);
    uint4 a = src[0], b = src[1];
    union { uint4 u; _Float16 hv[8]; } ua, ub;
    ua.u = a; ub.u = b;
    #pragma unroll
    for (int e = 0; e < 8; ++e) sm[e * 264 + t]       = ua.hv[e];
    #pragma unroll
    for (int e = 0; e < 8; ++e) sm[(e + 8) * 264 + t] = ub.hv[e];
    __syncthreads();

    #pragma unroll
    for (int k = 0; k < 2; ++k) {
        int idx = (k * 256 + t) * 8;         // halves into (e,f) plane
        int e = idx >> 8, f0 = idx & 255;
        uint4 o = *(const uint4*)(sm + e * 264 + f0);
        *(uint4*)(vT + bn * 4096 + idx) = o;
    }
}

// ---------------------------------------------------------------------------
// K2: MFMA flash attention per (n,h). 8 waves x 512 threads; wave w owns
// l in [32w, 32w+32). Denominator via ones-MFMA; hoisted packed bpermutes.
// r20: S MFMA sunk BELOW b1p (W0/W1 die before S lives; peak AGPR -16).
// LDS 36992B.
// ---------------------------------------------------------------------------
#define R2_STRIDE 258   // halves per R2 row; dword stride 129 (odd) = conflict-free
#define PS_STRIDE 40    // halves per P row (80B, b128-aligned, odd-dword)

__global__ __launch_bounds__(512, 4) void attn_kernel(
    const _Float16* __restrict__ qb, const _Float16* __restrict__ kb,
    const _Float16* __restrict__ vb, const _Float16* __restrict__ embh,
    _Float16* __restrict__ y)
{
    __shared__ __align__(16) _Float16 R2sh[32 * R2_STRIDE];   // 16.5 KB
    __shared__ __align__(16) _Float16 Psh[8 * 32 * PS_STRIDE];// 20.5 KB

    int tid  = threadIdx.x;
    int wave = tid >> 6, lane = tid & 63;
    int bid  = blockIdx.x;
    // XCD swizzle: consecutive bn (which share q/k cache lines) -> same XCD.
    int bn   = (bid & 7) * 400 + (bid >> 3);   // 3200 % 8 == 0: bijective
    int n    = bn >> 3, h = bn & 7;
    int base = bn * 4096;             // halves (vT only)

    int nn  = lane & 31;            // score col / s-local / frag m-or-n index
    int kh  = lane >> 5;            // wave half (frag k split for 32-shapes)
    int khb = (lane & 32) << 2;     // bpermute addr offset into own half
    int cbase = 31 + 4 * kh - nn;   // window col base per lane
    int dbase = 4 * kh - nn;        // d offset per lane
    int q16 = (lane >> 4) & 3;      // quad for 16x16 shapes

    // natural-layout fragment offset for this (n,h,kh)
    int nat_off = n * 128 + h * 16 + kh * 8;

    // Q fragment for this wave's l-tile (direct 16B load from global)
    f16x8 aq = __builtin_bit_cast(f16x8,
        *(const uint4*)(qb + (32 * wave + nn) * 51200 + nat_off));

    // ones fragment for rowsum-MFMA (denominator)
    f16x8 bones;
    #pragma unroll
    for (int i = 0; i < 8; ++i) bones[i] = (_Float16)1.0f;

    f32x4 O[2];     // PV accumulators (two 16-row sub-tiles)
    f32x4 Od[2];    // denominator accumulators
    #pragma unroll
    for (int a = 0; a < 2; ++a)
        #pragma unroll
        for (int r = 0; r < 4; ++r) { O[a][r] = 0.f; Od[a][r] = 0.f; }

    _Float16* psw = Psh + wave * 32 * PS_STRIDE;

    for (int st = 0; st < 8; ++st) {
        // K-tile fragment (A for R2, B for QK): row f = 32*st + nn
        f16x8 bk = __builtin_bit_cast(f16x8,
            *(const uint4*)(kb + (32 * st + nn) * 51200 + nat_off));

        // ---- shared R2 table: R2[s_local][d] = K[32st+s_local] . emb[d] ----
        auto r2tile = [&](int ct) {
            int erow = 32 * ct + nn; if (erow > 256) erow = 256;
            f16x8 be = __builtin_bit_cast(f16x8,
                *(const uint4*)(embh + erow * 16 + kh * 8));
            f32x16 c2;
            #pragma unroll
            for (int i = 0; i < 16; ++i) c2[i] = 0.f;
            c2 = __builtin_amdgcn_mfma_f32_32x32x16_f16(bk, be, c2, 0, 0, 0);
            int col = 32 * ct + nn;
            if (col <= 256) {
                #pragma unroll
                for (int r = 0; r < 16; ++r) {
                    int srow = (r & 3) + 8 * (r >> 2) + 4 * kh;
                    R2sh[srow * R2_STRIDE + col] = (_Float16)c2[r];
                }
            }
        };
        r2tile(wave);
        if (wave == (st & 7)) r2tile(8);   // rotate the 9th tile's owner
        __syncthreads();   // R2 ready for all waves

        // PV B-fragment: V^T[e = lane&15][k = s-local = q16*8+j], direct global
        f16x8 bv = __builtin_bit_cast(f16x8,
            *(const uint4*)(vb + base + (lane & 15) * 256 + 32 * st + q16 * 8));

        int U0 = 32 * wave - 32 * st + 128;

        // bias1 windows FIRST: W[m][c] = Q[l0+m] . emb[clamp(U0-31+c)]
        int br0 = iclamp256(U0 - 31 + nn);
        int br1 = iclamp256(U0 + 1 + nn);
        f16x8 be0 = __builtin_bit_cast(f16x8,
            *(const uint4*)(embh + br0 * 16 + kh * 8));
        f16x8 be1 = __builtin_bit_cast(f16x8,
            *(const uint4*)(embh + br1 * 16 + kh * 8));
        f32x16 W0, W1;
        #pragma unroll
        for (int i = 0; i < 16; ++i) { W0[i] = 0.f; W1[i] = 0.f; }
        W0 = __builtin_amdgcn_mfma_f32_32x32x16_f16(aq, be0, W0, 0, 0, 0);
        W1 = __builtin_amdgcn_mfma_f32_32x32x16_f16(aq, be1, W1, 0, 0, 0);

        // packed bpermutes consume W0/W1 -> b1p (8 regs); W0/W1 die here
        half2_t b1p[8];
        #pragma unroll
        for (int r = 0; r < 16; ++r) {
            int rmr = (r & 3) + 8 * (r >> 2);
            int c   = rmr + cbase;                 // [0,62]
            int addr = ((c & 31) << 2) + khb;
            int w01 = __builtin_bit_cast(int,
                __builtin_amdgcn_cvt_pkrtz(W0[r], W1[r]));
            half2_t hh = __builtin_bit_cast(half2_t,
                __builtin_amdgcn_ds_bpermute(addr, w01));
            b1p[r >> 1][r & 1] = (c < 32) ? hh[0] : hh[1];
        }

        // scores AFTER b1p (peak AGPR reduced)
        f32x16 S;
        #pragma unroll
        for (int i = 0; i < 16; ++i) S[i] = 0.f;
        S = __builtin_amdgcn_mfma_f32_32x32x16_f16(aq, bk, S, 0, 0, 0);

        #pragma unroll
        for (int r = 0; r < 16; ++r) {
            int rmr = (r & 3) + 8 * (r >> 2);
            float b1 = (float)b1p[r >> 1][r & 1];
            int d = iclamp256(U0 + rmr + dbase);
            float b2 = (float)R2sh[nn * R2_STRIDE + d];
            float p = __builtin_amdgcn_exp2f(S[r] + b1 + b2);
            int mloc = rmr + 4 * kh;
            psw[mloc * PS_STRIDE + nn] = (_Float16)p;
        }

        // PV + denom: 2 sub-tiles of 16 l-rows each, K = 32 (this s-tile)
        #pragma unroll
        for (int a = 0; a < 2; ++a) {
            f16x8 ap = __builtin_bit_cast(f16x8,
                *(const uint4*)(psw + (16 * a + (lane & 15)) * PS_STRIDE + q16 * 8));
            O[a]  = __builtin_amdgcn_mfma_f32_16x16x32_f16(ap, bv,    O[a],  0, 0, 0);
            Od[a] = __builtin_amdgcn_mfma_f32_16x16x32_f16(ap, bones, Od[a], 0, 0, 0);
        }
        __syncthreads();   // all reads of R2sh done before next st overwrites
    }

    // ---- epilogue: normalize + write (fp16 y); denom layout == O layout ----
    #pragma unroll
    for (int a = 0; a < 2; ++a) {
        #pragma unroll
        for (int r = 0; r < 4; ++r) {
            int row  = q16 * 4 + r;
            int lloc = 16 * a + row;
            int lg = 32 * wave + lloc;
            y[(lg * 400 + n) * 128 + h * 16 + (lane & 15)] =
                (_Float16)(O[a][r] / Od[a][r]);
        }
    }
}

// ---------------------------------------------------------------------------
// K3: FUSED back half — gate+LN1 -> FF1+GELU -> FF2 -> +h1, LN2.
// r20: W1/W2 arrive fp16 pre-packed -> f16x8 fragment loads, no cvts.
// LDS: h1sh 8704B + gsh 8704B + Cs 16896B = 34304B.
// ---------------------------------------------------------------------------
__global__ __launch_bounds__(256) void ffn_fused(
    const float* __restrict__ x, const _Float16* __restrict__ yh,
    const float* __restrict__ Wb,
    const float* __restrict__ ln1g, const float* __restrict__ ln1b,
    const _Float16* __restrict__ W1h, const float* __restrict__ b1,
    const _Float16* __restrict__ W2h, const float* __restrict__ b2,
    const float* __restrict__ ln2g, const float* __restrict__ ln2b,
    float* __restrict__ outp)
{
    __shared__ __align__(16) _Float16 h1sh[32 * 136];  // 8704 B
    __shared__ __align__(16) _Float16 gsh[32 * 136];   // 8704 B
    __shared__ float Cs[32 * 132];                     // 16896 B

    int tid  = threadIdx.x;
    int rloc = tid >> 3;               // 0..31 (row within block)
    int seg  = (tid & 7) * 16;         // 16-col segment
    int r    = blockIdx.x * 32 + rloc;

    // ---- phase 1: gate + LN1 (8 threads per row, shfl over 8 lanes) ----
    float xv[16], yv[16];
    {
        const float4* xp = (const float4*)(x + r * 128 + seg);
        float4 x0 = xp[0], x1 = xp[1], x2 = xp[2], x3 = xp[3];
        xv[0]=x0.x; xv[1]=x0.y; xv[2]=x0.z; xv[3]=x0.w;
        xv[4]=x1.x; xv[5]=x1.y; xv[6]=x1.z; xv[7]=x1.w;
        xv[8]=x2.x; xv[9]=x2.y; xv[10]=x2.z; xv[11]=x2.w;
        xv[12]=x3.x; xv[13]=x3.y; xv[14]=x3.z; xv[15]=x3.w;
        const uint4* yp = (const uint4*)(yh + r * 128 + seg);
        uint4 y0 = yp[0], y1 = yp[1];
        union { uint4 u; _Float16 hv[8]; } uy0, uy1;
        uy0.u = y0; uy1.u = y1;
        #pragma unroll
        for (int j = 0; j < 8; ++j) { yv[j] = (float)uy0.hv[j]; yv[8+j] = (float)uy1.hv[j]; }
    }
    float sv = 0.f;
    {
        const float4* w0p = (const float4*)(Wb + seg);
        const float4* w1p = (const float4*)(Wb + 128 + seg);
        const float4* w2p = (const float4*)(Wb + 256 + seg);
        #pragma unroll
        for (int j4 = 0; j4 < 4; ++j4) {
            float4 w0 = w0p[j4], w1 = w1p[j4], w2 = w2p[j4];
            float* w0f = (float*)&w0; float* w1f = (float*)&w1; float* w2f = (float*)&w2;
            #pragma unroll
            for (int jj = 0; jj < 4; ++jj) {
                int j = j4 * 4 + jj;
                sv += yv[j] * w0f[jj] + xv[j] * w1f[jj] + (yv[j] - xv[j]) * w2f[jj];
            }
        }
    }
    #pragma unroll
    for (int off = 4; off > 0; off >>= 1) sv += __shfl_xor(sv, off);
    float gate = 1.0f / (1.0f + __expf(-sv));

    float z[16], s1 = 0.f, s2 = 0.f;
    #pragma unroll
    for (int j = 0; j < 16; ++j) {
        z[j] = gate * xv[j] + (1.0f - gate) * yv[j];
        s1 += z[j]; s2 += z[j] * z[j];
    }
    #pragma unroll
    for (int off = 4; off > 0; off >>= 1) {
        s1 += __shfl_xor(s1, off);
        s2 += __shfl_xor(s2, off);
    }
    float mu  = s1 * (1.0f / 128.0f);
    float var = s2 * (1.0f / 128.0f) - mu * mu;
    float rs  = rsqrtf(var + 1e-5f);

    float h1r[16];   // h1 residual, stays in registers until phase 4
    {
        const float4* gp = (const float4*)(ln1g + seg);
        const float4* bp = (const float4*)(ln1b + seg);
        #pragma unroll
        for (int j4 = 0; j4 < 4; ++j4) {
            float4 gv = gp[j4], bv = bp[j4];
            float* gf = (float*)&gv; float* bf = (float*)&bv;
            #pragma unroll
            for (int jj = 0; jj < 4; ++jj) {
                int j = j4 * 4 + jj;
                h1r[j] = (z[j] - mu) * rs * gf[jj] + bf[jj];
            }
        }
        // store fp16 h1 to LDS for the FF1 fragments
        #pragma unroll
        for (int j = 0; j < 8; ++j) {
            *(uint*)(h1sh + rloc * 136 + seg + 2 * j) = __builtin_bit_cast(uint,
                __builtin_amdgcn_cvt_pkrtz(h1r[2 * j], h1r[2 * j + 1]));
        }
    }
    __syncthreads();

    // ---- phase 2: FF1 + GELU -> gsh (4 waves, each a 32x32 tile, K=128) ----
    int wave = tid >> 6, lane = tid & 63;
    int m32  = lane & 31, khalf = lane >> 5;
    int col0 = wave * 32;
    {
        f32x16 acc;
        #pragma unroll
        for (int i = 0; i < 16; ++i) acc[i] = 0.f;
        const _Float16* ap = h1sh + m32 * 136 + khalf * 8;
        const _Float16* wp = W1h + (col0 + m32) * 128 + khalf * 8;
        #pragma unroll
        for (int k0 = 0; k0 < 128; k0 += 16) {
            f16x8 aa = __builtin_bit_cast(f16x8, *(const uint4*)(ap + k0));
            f16x8 wa = __builtin_bit_cast(f16x8, *(const uint4*)(wp + k0));
            acc = __builtin_amdgcn_mfma_f32_32x32x16_f16(aa, wa, acc, 0, 0, 0);
        }
        int   c  = col0 + m32;
        float bi = b1[c];
        #pragma unroll
        for (int reg = 0; reg < 16; ++reg) {
            int row2 = (reg & 3) + 8 * (reg >> 2) + 4 * khalf;
            float v = acc[reg] + bi;
            v = 0.5f * v * (1.0f + erff(v * 0.70710678118654752f));  // exact GELU
            gsh[row2 * 136 + c] = (_Float16)v;
        }
    }
    __syncthreads();

    // ---- phase 3: FF2 -> Cs ----
    {
        f32x16 acc;
        #pragma unroll
        for (int i = 0; i < 16; ++i) acc[i] = 0.f;
        const _Float16* ap = gsh + m32 * 136 + khalf * 8;
        const _Float16* wp = W2h + (col0 + m32) * 128 + khalf * 8;
        #pragma unroll
        for (int k0 = 0; k0 < 128; k0 += 16) {
            f16x8 aa = __builtin_bit_cast(f16x8, *(const uint4*)(ap + k0));
            f16x8 wa = __builtin_bit_cast(f16x8, *(const uint4*)(wp + k0));
            acc = __builtin_amdgcn_mfma_f32_32x32x16_f16(aa, wa, acc, 0, 0, 0);
        }
        #pragma unroll
        for (int reg = 0; reg < 16; ++reg) {
            int row2 = (reg & 3) + 8 * (reg >> 2) + 4 * khalf;
            Cs[row2 * 132 + col0 + m32] = acc[reg];
        }
    }
    __syncthreads();

    // ---- phase 4: residual (from regs) + LN2 + write ----
    float z2[16];
    float t1 = 0.f, t2 = 0.f;
    #pragma unroll
    for (int j4 = 0; j4 < 4; ++j4) {
        float4 cv = *(const float4*)(Cs + rloc * 132 + seg + j4 * 4);
        float4 bv = *(const float4*)(b2 + seg + j4 * 4);
        float* cf = (float*)&cv; float* bf = (float*)&bv;
        #pragma unroll
        for (int jj = 0; jj < 4; ++jj) {
            int j = j4 * 4 + jj;
            z2[j] = cf[jj] + bf[jj] + h1r[j];
            t1 += z2[j]; t2 += z2[j] * z2[j];
        }
    }
    #pragma unroll
    for (int off = 4; off > 0; off >>= 1) {
        t1 += __shfl_xor(t1, off);
        t2 += __shfl_xor(t2, off);
    }
    float mu2  = t1 * (1.0f / 128.0f);
    float var2 = t2 * (1.0f / 128.0f) - mu2 * mu2;
    float rs2  = rsqrtf(var2 + 1e-5f);
    #pragma unroll
    for (int j4 = 0; j4 < 4; ++j4) {
        float4 gv = *(const float4*)(ln2g + seg + j4 * 4);
        float4 bv = *(const float4*)(ln2b + seg + j4 * 4);
        float* gf = (float*)&gv; float* bf = (float*)&bv;
        float4 ov;
        float* of = (float*)&ov;
        #pragma unroll
        for (int jj = 0; jj < 4; ++jj) {
            int j = j4 * 4 + jj;
            of[jj] = (z2[j] - mu2) * rs2 * gf[jj] + bf[jj];
        }
        *(float4*)(outp + r * 128 + seg + j4 * 4) = ov;
    }
}

// ---------------------------------------------------------------------------
extern "C" void kernel_launch(void* const* d_in, const int* in_sizes, int n_in,
                              void* d_out, int out_size, void* d_ws, size_t ws_size,
                              hipStream_t stream)
{
    const float* x     = (const float*)d_in[0];
    const float* te    = (const float*)d_in[1];
    const float* Wqkv  = (const float*)d_in[2];
    const float* Wtk   = (const float*)d_in[3];
    const float* Wtv   = (const float*)d_in[4];
    const float* emb   = (const float*)d_in[5];
    const float* Wbeta = (const float*)d_in[6];
    const float* ln1g  = (const float*)d_in[7];
    const float* ln1b  = (const float*)d_in[8];
    const float* ln2g  = (const float*)d_in[9];
    const float* ln2b  = (const float*)d_in[10];
    const float* W1    = (const float*)d_in[11];
    const float* b1    = (const float*)d_in[12];
    const float* W2    = (const float*)d_in[13];
    const float* b2    = (const float*)d_in[14];
    float* outp = (float*)d_out;

    float* ws = (float*)d_ws;
    float* tk = ws;                        // 51200
    float* tv = ws + 51200;                // 51200
    float* qb_region = ws + 102400;        // SBUF floats
    float* kb_region = qb_region + SBUF;   // SBUF floats
    float* vb_region = kb_region + SBUF;   // SBUF floats
    float* yb        = vb_region + SBUF;   // SBUF floats

    _Float16* qnat = (_Float16*)qb_region;                   // natural (r,c) fp16
    _Float16* knat = (_Float16*)kb_region;                   // natural (r,c) fp16
    _Float16* vnat = (_Float16*)vb_region;                   // natural (r,c) fp16
    _Float16* vT   = (_Float16*)(vb_region + SBUF / 2);      // (n,h,e,f) fp16
    _Float16* embh = (_Float16*)(qb_region + SBUF / 2);      // spare half of q region
    _Float16* yh   = (_Float16*)yb;                          // y fp16 (f,n,c), lower half
    _Float16* xh   = (_Float16*)(kb_region + SBUF / 2);      // x fp16 packed
    _Float16* Wqh  = (_Float16*)(yb + SBUF / 2);             // W_qkv fp16 (yb upper)
    _Float16* W1h  = (_Float16*)(yb + SBUF / 2 + 32768);     // W1 fp16 (16384 halves)
    _Float16* W2h  = (_Float16*)(yb + SBUF / 2 + 49152);     // W2 fp16 (16384 halves)

    prep_pack<<<6842, 256, 0, stream>>>(x, Wqkv, emb, te, Wtk, Wtv, W1, W2,
                                        xh, Wqh, embh, tk, tv, W1h, W2h);
    qkv_gemm<<<9600, 256, 0, stream>>>(xh, Wqh, tk, tv, qnat, knat, vnat);
    v_pack<<<3200, 256, 0, stream>>>(vnat, vT);
    attn_kernel<<<3200, 512, 0, stream>>>(qnat, knat, vT, embh, yh);
    ffn_fused<<<3200, 256, 0, stream>>>(x, yh, Wbeta, ln1g, ln1b,
                                        W1h, b1, W2h, b2, ln2g, ln2b, outp);
}

// Round 15
// 426.223 us; speedup vs baseline: 2.3074x; 1.0758x over previous
//
#include <hip/hip_runtime.h>
#include <math.h>

// Problem constants
#define F_DIM 256
#define N_DIM 400
#define C_DIM 128
#define H_DIM 8
#define E_DIM 16
#define ROWS  (F_DIM * N_DIM)          // 102400
#define SBUF  (N_DIM * H_DIM * F_DIM * E_DIM)  // 13107200 floats per q/k/v region

// r22 == r21 resubmitted: round-14 bench died with "MI355X container failed
// twice" (infra acquire error; same signature as rounds 3-4, which passed on
// resubmission). Audit found no hazard: R2 dbuf WAR-safe (writers of buf B
// at st+1 passed barrier(st), after all st-1 readers of B), V staging
// bounds/sync clean, barriers uniform. If this fails again, next round
// reverts the single-barrier change to bisect.
//  (1) attn R2sh double-buffered -> ONE barrier per st (16 -> 8 barriers).
//  (2) v_pack DELETED: attn stages its own (n,h) V-tile (8KB) from natural
//      v in the prologue. -78MB traffic, -1 launch. LDS 61952B.
#define S_SCALE 0.6005612043932249f

typedef _Float16 half2_t __attribute__((ext_vector_type(2)));
typedef _Float16 f16x8   __attribute__((ext_vector_type(8)));
typedef float    f32x16  __attribute__((ext_vector_type(16)));
typedef float    f32x4   __attribute__((ext_vector_type(4)));

struct H2x4 { half2_t h[4]; };

// pack 8 consecutive fp32 (two float4) into an f16x8 fragment (RTZ)
__device__ inline f16x8 pack8(float4 a, float4 b) {
    H2x4 t;
    t.h[0] = __builtin_bit_cast(half2_t, __builtin_amdgcn_cvt_pkrtz(a.x, a.y));
    t.h[1] = __builtin_bit_cast(half2_t, __builtin_amdgcn_cvt_pkrtz(a.z, a.w));
    t.h[2] = __builtin_bit_cast(half2_t, __builtin_amdgcn_cvt_pkrtz(b.x, b.y));
    t.h[3] = __builtin_bit_cast(half2_t, __builtin_amdgcn_cvt_pkrtz(b.z, b.w));
    return __builtin_bit_cast(f16x8, t);
}

// scalar fp32 -> fp16 with RTZ (matches pack8 rounding)
__device__ inline _Float16 h_rtz(float v) {
    half2_t p = __builtin_bit_cast(half2_t, __builtin_amdgcn_cvt_pkrtz(v, v));
    return p[0];
}

__device__ inline int iclamp256(int v) { return v < 0 ? 0 : (v > 256 ? 256 : v); }

// ---------------------------------------------------------------------------
// K0: fused prep — x/Wq/W1/W2 fp16 pack, emb pack (scaled), tree proj.
// grid 6842 x 256.
// ---------------------------------------------------------------------------
__global__ __launch_bounds__(256) void prep_pack(
    const float* __restrict__ x, const float* __restrict__ Wq,
    const float* __restrict__ emb, const float* __restrict__ te,
    const float* __restrict__ Wtk, const float* __restrict__ Wtv,
    const float* __restrict__ W1, const float* __restrict__ W2,
    _Float16* __restrict__ xh, _Float16* __restrict__ Wqh,
    _Float16* __restrict__ embh, float* __restrict__ tk, float* __restrict__ tv,
    _Float16* __restrict__ W1h, _Float16* __restrict__ W2h)
{
    int bid = blockIdx.x;
    int t   = threadIdx.x;
    if (bid < 6400) {
        int i = (bid * 256 + t) * 8;                 // 6400*256*8 = 13107200 exact
        const float4* s = (const float4*)(x + i);
        *(uint4*)(xh + i) = __builtin_bit_cast(uint4, pack8(s[0], s[1]));
    } else if (bid < 6424) {
        int i = ((bid - 6400) * 256 + t) * 8;        // 24*256*8 = 49152 exact
        const float4* s = (const float4*)(Wq + i);
        *(uint4*)(Wqh + i) = __builtin_bit_cast(uint4, pack8(s[0], s[1]));
    } else if (bid < 6426) {
        int r = (bid - 6424) * 256 + t;
        if (r > 256) return;
        const float4* er = (const float4*)(emb + r * 16);
        float4 e0 = er[0], e1 = er[1], e2 = er[2], e3 = er[3];
        e0.x *= S_SCALE; e0.y *= S_SCALE; e0.z *= S_SCALE; e0.w *= S_SCALE;
        e1.x *= S_SCALE; e1.y *= S_SCALE; e1.z *= S_SCALE; e1.w *= S_SCALE;
        e2.x *= S_SCALE; e2.y *= S_SCALE; e2.z *= S_SCALE; e2.w *= S_SCALE;
        e3.x *= S_SCALE; e3.y *= S_SCALE; e3.z *= S_SCALE; e3.w *= S_SCALE;
        *(uint4*)(embh + r * 16)     = __builtin_bit_cast(uint4, pack8(e0, e1));
        *(uint4*)(embh + r * 16 + 8) = __builtin_bit_cast(uint4, pack8(e2, e3));
    } else if (bid < 6826) {
        int n = bid - 6426;                          // 400 blocks
        const float* W = (t < 128) ? Wtk : Wtv;
        float* outp    = (t < 128) ? tk : tv;
        int j = t & 127;
        float acc = 0.f;
        #pragma unroll 4
        for (int c = 0; c < 128; ++c)
            acc += te[n * 128 + c] * W[c * 128 + j];
        outp[n * 128 + j] = acc;
    } else if (bid < 6834) {
        int i = ((bid - 6826) * 256 + t) * 8;        // 8*256*8 = 16384 exact
        const float4* s = (const float4*)(W1 + i);
        *(uint4*)(W1h + i) = __builtin_bit_cast(uint4, pack8(s[0], s[1]));
    } else {
        int i = ((bid - 6834) * 256 + t) * 8;        // 8*256*8 = 16384 exact
        const float4* s = (const float4*)(W2 + i);
        *(uint4*)(W2h + i) = __builtin_bit_cast(uint4, pack8(s[0], s[1]));
    }
}

// ---------------------------------------------------------------------------
// K1: qkv GEMM via fp16 MFMA; inputs pre-packed fp16 (direct f16x8 loads).
// q/k stores scaled by S_SCALE. Natural (r,c) fp16 stores. XCD-aligned grid.
// ---------------------------------------------------------------------------
__global__ __launch_bounds__(256) void qkv_gemm(
    const _Float16* __restrict__ xh, const _Float16* __restrict__ Wqh,
    const float* __restrict__ tk, const float* __restrict__ tv,
    _Float16* __restrict__ qn, _Float16* __restrict__ kn, _Float16* __restrict__ vn)
{
    int tid  = threadIdx.x;
    int wave = tid >> 6, lane = tid & 63;
    int m32  = lane & 31, khalf = lane >> 5;

    int bid = blockIdx.x;            // 9600 = 1600 row-panels x 6 col-blocks
    int xcd = bid & 7;
    int tt  = bid >> 3;              // 0..1199
    int cb  = tt % 6;
    int rp  = (tt / 6) * 8 + xcd;    // 0..1599
    int row0 = rp * 64 + (wave & 1) * 32;
    int col0 = cb * 64 + (wave >> 1) * 32;

    const _Float16* xp = xh  + (row0 + m32) * 128 + khalf * 8;
    const _Float16* wp = Wqh + (col0 + m32) * 128 + khalf * 8;

    f32x16 acc;
    #pragma unroll
    for (int i = 0; i < 16; ++i) acc[i] = 0.f;

    #pragma unroll
    for (int k0 = 0; k0 < 128; k0 += 16) {
        f16x8 xa = __builtin_bit_cast(f16x8, *(const uint4*)(xp + k0));
        f16x8 wa = __builtin_bit_cast(f16x8, *(const uint4*)(wp + k0));
        acc = __builtin_amdgcn_mfma_f32_32x32x16_f16(xa, wa, acc, 0, 0, 0);
    }

    int o   = col0 + m32;
    int sec = o >> 7;
    int rem = o & 127;
    #pragma unroll
    for (int reg = 0; reg < 16; ++reg) {
        int r = row0 + (reg & 3) + 8 * (reg >> 2) + 4 * khalf;  // r = f*400+n
        float val = acc[reg];
        if (sec == 0) {
            qn[r * 128 + rem] = h_rtz(val * S_SCALE);
        } else {
            int f = r / 400;
            int n = r - f * 400;
            if (sec == 1) {
                kn[r * 128 + rem] = h_rtz((val + tk[n * 128 + rem]) * S_SCALE);
            } else {
                vn[r * 128 + rem] = (_Float16)(val + tv[n * 128 + rem]);  // RTN, unscaled
            }
        }
    }
}

// ---------------------------------------------------------------------------
// K2: MFMA flash attention per (n,h). 8 waves x 512 threads; wave w owns
// l in [32w, 32w+32). Denominator via ones-MFMA; hoisted packed bpermutes.
// R2sh double-buffered -> 1 barrier/st; V staged from natural layout in
// prologue (v_pack kernel deleted). LDS 61952B -> 2 blocks/CU.
// ---------------------------------------------------------------------------
#define R2_STRIDE 258   // halves per R2 row; dword stride 129 (odd) = conflict-free
#define PS_STRIDE 40    // halves per P row (80B, b128-aligned, odd-dword)
#define VT_STRIDE 264   // halves per V^T row (528B, 16B-aligned)

__global__ __launch_bounds__(512, 4) void attn_kernel(
    const _Float16* __restrict__ qb, const _Float16* __restrict__ kb,
    const _Float16* __restrict__ vn, const _Float16* __restrict__ embh,
    _Float16* __restrict__ y)
{
    __shared__ __align__(16) _Float16 R2sh[2][32 * R2_STRIDE]; // 33024 B
    __shared__ __align__(16) _Float16 Psh[8 * 32 * PS_STRIDE]; // 20480 B
    __shared__ __align__(16) _Float16 VshT[16 * VT_STRIDE];    // 8448 B

    int tid  = threadIdx.x;
    int wave = tid >> 6, lane = tid & 63;
    int bid  = blockIdx.x;
    // XCD swizzle: consecutive bn (which share q/k cache lines) -> same XCD.
    int bn   = (bid & 7) * 400 + (bid >> 3);   // 3200 % 8 == 0: bijective
    int n    = bn >> 3, h = bn & 7;

    int nn  = lane & 31;            // score col / s-local / frag m-or-n index
    int kh  = lane >> 5;            // wave half (frag k split for 32-shapes)
    int khb = (lane & 32) << 2;     // bpermute addr offset into own half
    int cbase = 31 + 4 * kh - nn;   // window col base per lane
    int dbase = 4 * kh - nn;        // d offset per lane
    int q16 = (lane >> 4) & 3;      // quad for 16x16 shapes

    // natural-layout fragment offset for this (n,h,kh)
    int nat_off = n * 128 + h * 16 + kh * 8;

    // ---- V staging: natural (f-major) -> VshT[e][f] (one time) ----
    {
        int f = tid >> 1, part = tid & 1;
        uint4 vv = *(const uint4*)(vn + (f * 400 + n) * 128 + h * 16 + part * 8);
        union { uint4 u; _Float16 hv[8]; } uv; uv.u = vv;
        #pragma unroll
        for (int j = 0; j < 8; ++j)
            VshT[(part * 8 + j) * VT_STRIDE + f] = uv.hv[j];
    }

    // Q fragment for this wave's l-tile (direct 16B load from global)
    f16x8 aq = __builtin_bit_cast(f16x8,
        *(const uint4*)(qb + (32 * wave + nn) * 51200 + nat_off));

    // ones fragment for rowsum-MFMA (denominator)
    f16x8 bones;
    #pragma unroll
    for (int i = 0; i < 8; ++i) bones[i] = (_Float16)1.0f;

    f32x4 O[2];     // PV accumulators (two 16-row sub-tiles)
    f32x4 Od[2];    // denominator accumulators
    #pragma unroll
    for (int a = 0; a < 2; ++a)
        #pragma unroll
        for (int r = 0; r < 4; ++r) { O[a][r] = 0.f; Od[a][r] = 0.f; }

    _Float16* psw = Psh + wave * 32 * PS_STRIDE;

    for (int st = 0; st < 8; ++st) {
        _Float16* R2cur = &R2sh[st & 1][0];

        // K-tile fragment (A for R2, B for QK): row f = 32*st + nn
        f16x8 bk = __builtin_bit_cast(f16x8,
            *(const uint4*)(kb + (32 * st + nn) * 51200 + nat_off));

        // ---- R2 table (double-buffered): R2[s_local][d] = K . emb[d] ----
        auto r2tile = [&](int ct) {
            int erow = 32 * ct + nn; if (erow > 256) erow = 256;
            f16x8 be = __builtin_bit_cast(f16x8,
                *(const uint4*)(embh + erow * 16 + kh * 8));
            f32x16 c2;
            #pragma unroll
            for (int i = 0; i < 16; ++i) c2[i] = 0.f;
            c2 = __builtin_amdgcn_mfma_f32_32x32x16_f16(bk, be, c2, 0, 0, 0);
            int col = 32 * ct + nn;
            if (col <= 256) {
                #pragma unroll
                for (int r = 0; r < 16; ++r) {
                    int srow = (r & 3) + 8 * (r >> 2) + 4 * kh;
                    R2cur[srow * R2_STRIDE + col] = (_Float16)c2[r];
                }
            }
        };
        r2tile(wave);
        if (wave == (st & 7)) r2tile(8);   // rotate the 9th tile's owner
        __syncthreads();   // R2cur ready; also covers VshT (st=0) and
                           // protects R2sh[st&1] WAR (readers of st-2 done)

        // PV B-fragment from LDS: V^T[e = lane&15][k = 32*st + q16*8 ..]
        f16x8 bv = __builtin_bit_cast(f16x8,
            *(const uint4*)(VshT + (lane & 15) * VT_STRIDE + 32 * st + q16 * 8));

        int U0 = 32 * wave - 32 * st + 128;

        // bias1 windows: W[m][c] = Q[l0+m] . emb[clamp(U0-31+c)]
        int br0 = iclamp256(U0 - 31 + nn);
        int br1 = iclamp256(U0 + 1 + nn);
        f16x8 be0 = __builtin_bit_cast(f16x8,
            *(const uint4*)(embh + br0 * 16 + kh * 8));
        f16x8 be1 = __builtin_bit_cast(f16x8,
            *(const uint4*)(embh + br1 * 16 + kh * 8));
        f32x16 W0, W1;
        #pragma unroll
        for (int i = 0; i < 16; ++i) { W0[i] = 0.f; W1[i] = 0.f; }
        W0 = __builtin_amdgcn_mfma_f32_32x32x16_f16(aq, be0, W0, 0, 0, 0);
        W1 = __builtin_amdgcn_mfma_f32_32x32x16_f16(aq, be1, W1, 0, 0, 0);

        // packed bpermutes consume W0/W1 -> b1p (8 regs)
        half2_t b1p[8];
        #pragma unroll
        for (int r = 0; r < 16; ++r) {
            int rmr = (r & 3) + 8 * (r >> 2);
            int c   = rmr + cbase;                 // [0,62]
            int addr = ((c & 31) << 2) + khb;
            int w01 = __builtin_bit_cast(int,
                __builtin_amdgcn_cvt_pkrtz(W0[r], W1[r]));
            half2_t hh = __builtin_bit_cast(half2_t,
                __builtin_amdgcn_ds_bpermute(addr, w01));
            b1p[r >> 1][r & 1] = (c < 32) ? hh[0] : hh[1];
        }

        // scores
        f32x16 S;
        #pragma unroll
        for (int i = 0; i < 16; ++i) S[i] = 0.f;
        S = __builtin_amdgcn_mfma_f32_32x32x16_f16(aq, bk, S, 0, 0, 0);

        #pragma unroll
        for (int r = 0; r < 16; ++r) {
            int rmr = (r & 3) + 8 * (r >> 2);
            float b1 = (float)b1p[r >> 1][r & 1];
            int d = iclamp256(U0 + rmr + dbase);
            float b2 = (float)R2cur[nn * R2_STRIDE + d];
            float p = __builtin_amdgcn_exp2f(S[r] + b1 + b2);
            int mloc = rmr + 4 * kh;
            psw[mloc * PS_STRIDE + nn] = (_Float16)p;
        }

        // PV + denom: 2 sub-tiles of 16 l-rows each, K = 32 (this s-tile)
        #pragma unroll
        for (int a = 0; a < 2; ++a) {
            f16x8 ap = __builtin_bit_cast(f16x8,
                *(const uint4*)(psw + (16 * a + (lane & 15)) * PS_STRIDE + q16 * 8));
            O[a]  = __builtin_amdgcn_mfma_f32_16x16x32_f16(ap, bv,    O[a],  0, 0, 0);
            Od[a] = __builtin_amdgcn_mfma_f32_16x16x32_f16(ap, bones, Od[a], 0, 0, 0);
        }
        // no trailing barrier: next st writes the OTHER R2 buffer
    }

    // ---- epilogue: normalize + write (fp16 y); denom layout == O layout ----
    #pragma unroll
    for (int a = 0; a < 2; ++a) {
        #pragma unroll
        for (int r = 0; r < 4; ++r) {
            int row  = q16 * 4 + r;
            int lloc = 16 * a + row;
            int lg = 32 * wave + lloc;
            y[(lg * 400 + n) * 128 + h * 16 + (lane & 15)] =
                (_Float16)(O[a][r] / Od[a][r]);
        }
    }
}

// ---------------------------------------------------------------------------
// K3: FUSED back half — gate+LN1 -> FF1+GELU -> FF2 -> +h1, LN2.
// W1/W2 fp16 pre-packed. LDS: h1sh 8704 + gsh 8704 + Cs 16896 = 34304B.
// ---------------------------------------------------------------------------
__global__ __launch_bounds__(256) void ffn_fused(
    const float* __restrict__ x, const _Float16* __restrict__ yh,
    const float* __restrict__ Wb,
    const float* __restrict__ ln1g, const float* __restrict__ ln1b,
    const _Float16* __restrict__ W1h, const float* __restrict__ b1,
    const _Float16* __restrict__ W2h, const float* __restrict__ b2,
    const float* __restrict__ ln2g, const float* __restrict__ ln2b,
    float* __restrict__ outp)
{
    __shared__ __align__(16) _Float16 h1sh[32 * 136];  // 8704 B
    __shared__ __align__(16) _Float16 gsh[32 * 136];   // 8704 B
    __shared__ float Cs[32 * 132];                     // 16896 B

    int tid  = threadIdx.x;
    int rloc = tid >> 3;               // 0..31 (row within block)
    int seg  = (tid & 7) * 16;         // 16-col segment
    int r    = blockIdx.x * 32 + rloc;

    // ---- phase 1: gate + LN1 (8 threads per row, shfl over 8 lanes) ----
    float xv[16], yv[16];
    {
        const float4* xp = (const float4*)(x + r * 128 + seg);
        float4 x0 = xp[0], x1 = xp[1], x2 = xp[2], x3 = xp[3];
        xv[0]=x0.x; xv[1]=x0.y; xv[2]=x0.z; xv[3]=x0.w;
        xv[4]=x1.x; xv[5]=x1.y; xv[6]=x1.z; xv[7]=x1.w;
        xv[8]=x2.x; xv[9]=x2.y; xv[10]=x2.z; xv[11]=x2.w;
        xv[12]=x3.x; xv[13]=x3.y; xv[14]=x3.z; xv[15]=x3.w;
        const uint4* yp = (const uint4*)(yh + r * 128 + seg);
        uint4 y0 = yp[0], y1 = yp[1];
        union { uint4 u; _Float16 hv[8]; } uy0, uy1;
        uy0.u = y0; uy1.u = y1;
        #pragma unroll
        for (int j = 0; j < 8; ++j) { yv[j] = (float)uy0.hv[j]; yv[8+j] = (float)uy1.hv[j]; }
    }
    float sv = 0.f;
    {
        const float4* w0p = (const float4*)(Wb + seg);
        const float4* w1p = (const float4*)(Wb + 128 + seg);
        const float4* w2p = (const float4*)(Wb + 256 + seg);
        #pragma unroll
        for (int j4 = 0; j4 < 4; ++j4) {
            float4 w0 = w0p[j4], w1 = w1p[j4], w2 = w2p[j4];
            float* w0f = (float*)&w0; float* w1f = (float*)&w1; float* w2f = (float*)&w2;
            #pragma unroll
            for (int jj = 0; jj < 4; ++jj) {
                int j = j4 * 4 + jj;
                sv += yv[j] * w0f[jj] + xv[j] * w1f[jj] + (yv[j] - xv[j]) * w2f[jj];
            }
        }
    }
    #pragma unroll
    for (int off = 4; off > 0; off >>= 1) sv += __shfl_xor(sv, off);
    float gate = 1.0f / (1.0f + __expf(-sv));

    float z[16], s1 = 0.f, s2 = 0.f;
    #pragma unroll
    for (int j = 0; j < 16; ++j) {
        z[j] = gate * xv[j] + (1.0f - gate) * yv[j];
        s1 += z[j]; s2 += z[j] * z[j];
    }
    #pragma unroll
    for (int off = 4; off > 0; off >>= 1) {
        s1 += __shfl_xor(s1, off);
        s2 += __shfl_xor(s2, off);
    }
    float mu  = s1 * (1.0f / 128.0f);
    float var = s2 * (1.0f / 128.0f) - mu * mu;
    float rs  = rsqrtf(var + 1e-5f);

    float h1r[16];   // h1 residual, stays in registers until phase 4
    {
        const float4* gp = (const float4*)(ln1g + seg);
        const float4* bp = (const float4*)(ln1b + seg);
        #pragma unroll
        for (int j4 = 0; j4 < 4; ++j4) {
            float4 gv = gp[j4], bv = bp[j4];
            float* gf = (float*)&gv; float* bf = (float*)&bv;
            #pragma unroll
            for (int jj = 0; jj < 4; ++jj) {
                int j = j4 * 4 + jj;
                h1r[j] = (z[j] - mu) * rs * gf[jj] + bf[jj];
            }
        }
        // store fp16 h1 to LDS for the FF1 fragments
        #pragma unroll
        for (int j = 0; j < 8; ++j) {
            *(uint*)(h1sh + rloc * 136 + seg + 2 * j) = __builtin_bit_cast(uint,
                __builtin_amdgcn_cvt_pkrtz(h1r[2 * j], h1r[2 * j + 1]));
        }
    }
    __syncthreads();

    // ---- phase 2: FF1 + GELU -> gsh (4 waves, each a 32x32 tile, K=128) ----
    int wave = tid >> 6, lane = tid & 63;
    int m32  = lane & 31, khalf = lane >> 5;
    int col0 = wave * 32;
    {
        f32x16 acc;
        #pragma unroll
        for (int i = 0; i < 16; ++i) acc[i] = 0.f;
        const _Float16* ap = h1sh + m32 * 136 + khalf * 8;
        const _Float16* wp = W1h + (col0 + m32) * 128 + khalf * 8;
        #pragma unroll
        for (int k0 = 0; k0 < 128; k0 += 16) {
            f16x8 aa = __builtin_bit_cast(f16x8, *(const uint4*)(ap + k0));
            f16x8 wa = __builtin_bit_cast(f16x8, *(const uint4*)(wp + k0));
            acc = __builtin_amdgcn_mfma_f32_32x32x16_f16(aa, wa, acc, 0, 0, 0);
        }
        int   c  = col0 + m32;
        float bi = b1[c];
        #pragma unroll
        for (int reg = 0; reg < 16; ++reg) {
            int row2 = (reg & 3) + 8 * (reg >> 2) + 4 * khalf;
            float v = acc[reg] + bi;
            v = 0.5f * v * (1.0f + erff(v * 0.70710678118654752f));  // exact GELU
            gsh[row2 * 136 + c] = (_Float16)v;
        }
    }
    __syncthreads();

    // ---- phase 3: FF2 -> Cs ----
    {
        f32x16 acc;
        #pragma unroll
        for (int i = 0; i < 16; ++i) acc[i] = 0.f;
        const _Float16* ap = gsh + m32 * 136 + khalf * 8;
        const _Float16* wp = W2h + (col0 + m32) * 128 + khalf * 8;
        #pragma unroll
        for (int k0 = 0; k0 < 128; k0 += 16) {
            f16x8 aa = __builtin_bit_cast(f16x8, *(const uint4*)(ap + k0));
            f16x8 wa = __builtin_bit_cast(f16x8, *(const uint4*)(wp + k0));
            acc = __builtin_amdgcn_mfma_f32_32x32x16_f16(aa, wa, acc, 0, 0, 0);
        }
        #pragma unroll
        for (int reg = 0; reg < 16; ++reg) {
            int row2 = (reg & 3) + 8 * (reg >> 2) + 4 * khalf;
            Cs[row2 * 132 + col0 + m32] = acc[reg];
        }
    }
    __syncthreads();

    // ---- phase 4: residual (from regs) + LN2 + write ----
    float z2[16];
    float t1 = 0.f, t2 = 0.f;
    #pragma unroll
    for (int j4 = 0; j4 < 4; ++j4) {
        float4 cv = *(const float4*)(Cs + rloc * 132 + seg + j4 * 4);
        float4 bv = *(const float4*)(b2 + seg + j4 * 4);
        float* cf = (float*)&cv; float* bf = (float*)&bv;
        #pragma unroll
        for (int jj = 0; jj < 4; ++jj) {
            int j = j4 * 4 + jj;
            z2[j] = cf[jj] + bf[jj] + h1r[j];
            t1 += z2[j]; t2 += z2[j] * z2[j];
        }
    }
    #pragma unroll
    for (int off = 4; off > 0; off >>= 1) {
        t1 += __shfl_xor(t1, off);
        t2 += __shfl_xor(t2, off);
    }
    float mu2  = t1 * (1.0f / 128.0f);
    float var2 = t2 * (1.0f / 128.0f) - mu2 * mu2;
    float rs2  = rsqrtf(var2 + 1e-5f);
    #pragma unroll
    for (int j4 = 0; j4 < 4; ++j4) {
        float4 gv = *(const float4*)(ln2g + seg + j4 * 4);
        float4 bv = *(const float4*)(ln2b + seg + j4 * 4);
        float* gf = (float*)&gv; float* bf = (float*)&bv;
        float4 ov;
        float* of = (float*)&ov;
        #pragma unroll
        for (int jj = 0; jj < 4; ++jj) {
            int j = j4 * 4 + jj;
            of[jj] = (z2[j] - mu2) * rs2 * gf[jj] + bf[jj];
        }
        *(float4*)(outp + r * 128 + seg + j4 * 4) = ov;
    }
}

// ---------------------------------------------------------------------------
extern "C" void kernel_launch(void* const* d_in, const int* in_sizes, int n_in,
                              void* d_out, int out_size, void* d_ws, size_t ws_size,
                              hipStream_t stream)
{
    const float* x     = (const float*)d_in[0];
    const float* te    = (const float*)d_in[1];
    const float* Wqkv  = (const float*)d_in[2];
    const float* Wtk   = (const float*)d_in[3];
    const float* Wtv   = (const float*)d_in[4];
    const float* emb   = (const float*)d_in[5];
    const float* Wbeta = (const float*)d_in[6];
    const float* ln1g  = (const float*)d_in[7];
    const float* ln1b  = (const float*)d_in[8];
    const float* ln2g  = (const float*)d_in[9];
    const float* ln2b  = (const float*)d_in[10];
    const float* W1    = (const float*)d_in[11];
    const float* b1    = (const float*)d_in[12];
    const float* W2    = (const float*)d_in[13];
    const float* b2    = (const float*)d_in[14];
    float* outp = (float*)d_out;

    float* ws = (float*)d_ws;
    float* tk = ws;                        // 51200
    float* tv = ws + 51200;                // 51200
    float* qb_region = ws + 102400;        // SBUF floats
    float* kb_region = qb_region + SBUF;   // SBUF floats
    float* vb_region = kb_region + SBUF;   // SBUF floats
    float* yb        = vb_region + SBUF;   // SBUF floats

    _Float16* qnat = (_Float16*)qb_region;                   // natural (r,c) fp16
    _Float16* knat = (_Float16*)kb_region;                   // natural (r,c) fp16
    _Float16* vnat = (_Float16*)vb_region;                   // natural (r,c) fp16
    _Float16* embh = (_Float16*)(qb_region + SBUF / 2);      // spare half of q region
    _Float16* yh   = (_Float16*)yb;                          // y fp16 (f,n,c), lower half
    _Float16* xh   = (_Float16*)(kb_region + SBUF / 2);      // x fp16 packed
    _Float16* Wqh  = (_Float16*)(yb + SBUF / 2);             // W_qkv fp16 (yb upper)
    _Float16* W1h  = (_Float16*)(yb + SBUF / 2 + 32768);     // W1 fp16 (16384 halves)
    _Float16* W2h  = (_Float16*)(yb + SBUF / 2 + 49152);     // W2 fp16 (16384 halves)

    prep_pack<<<6842, 256, 0, stream>>>(x, Wqkv, emb, te, Wtk, Wtv, W1, W2,
                                        xh, Wqh, embh, tk, tv, W1h, W2h);
    qkv_gemm<<<9600, 256, 0, stream>>>(xh, Wqh, tk, tv, qnat, knat, vnat);
    attn_kernel<<<3200, 512, 0, stream>>>(qnat, knat, vnat, embh, yh);
    ffn_fused<<<3200, 256, 0, stream>>>(x, yh, Wbeta, ln1g, ln1b,
                                        W1h, b1, W2h, b2, ln2g, ln2b, outp);
}